// Round 6
// baseline (512.050 us; speedup 1.0000x reference)
//
#include <hip/hip_runtime.h>
#include <hip/hip_bf16.h>

typedef __hip_bfloat16 bf16;
typedef __attribute__((ext_vector_type(8))) short v8s;
typedef __attribute__((ext_vector_type(4))) float v4f;

__device__ __forceinline__ float b2f(bf16 v){ return __bfloat162float(v); }
__device__ __forceinline__ bf16  f2b(float v){ return __float2bfloat16(v); }

// Inputs may be bf16 OR f32 — runtime-detected flag (1 => f32). Output dtype follows.
__device__ __forceinline__ float ldin(const void* p, int i, bool f32in){
  return f32in ? ((const float*)p)[i] : b2f(((const bf16*)p)[i]);
}

// stage 4 consecutive source elems (f32-or-bf16) into dst as bf16 (8B write)
__device__ __forceinline__ void stage4(const void* src, size_t off, bool f32in, bf16* dst){
  union { bf16 h[4]; ushort4 u; } tmp;
  if (f32in){
    float4 f = *(const float4*)((const float*)src + off);
    tmp.h[0] = f2b(f.x); tmp.h[1] = f2b(f.y); tmp.h[2] = f2b(f.z); tmp.h[3] = f2b(f.w);
  } else {
    tmp.u = *(const ushort4*)((const ushort*)src + off);
  }
  *(ushort4*)dst = tmp.u;
}
__device__ __forceinline__ void stage4b(const bf16* src, bf16* dst){
  *(ushort4*)dst = *(const ushort4*)src;
}

// async global->LDS, 16B per lane. LDS dest must be wave-uniform base (HW adds lane*16).
__device__ __forceinline__ void async_cp16(const bf16* g, bf16* l){
  __builtin_amdgcn_global_load_lds(
      (const __attribute__((address_space(1))) unsigned int*)g,
      (__attribute__((address_space(3))) unsigned int*)l, 16, 0, 0);
}

// Problem: B=2, C=512, T=16, H=W=24, heads=8, ch=64
// ws: flag | A (S) | A2 (S) | Bq (3S) | Cx 9,437,184 | [Cx2 9,437,184 if room]
// R1: proj_s epilogue request-bound -> LDS-transpose epilogue (WIN, -58us).
// R2: qkv GEMMs -> unified 128x128 global_load_lds GEMM (linear LDS caused
//     16-way bank conflict 1.06e7).
// R3: XOR-swizzle via pre-swizzled global source + swizzled ds_read (conflict fix).
// R4: attn_s latency-bound (MfmaUtil 10.7, VALU 39, HBM 7, 81.5us):
//     reg-prefetch K/V (T14 async-stage), exp2-domain softmax, defer-max (T13),
//     setprio around MFMA (T5).
// R5: broker timeout, no measurement — resubmitted unchanged.

// ---------------------------------------------------------------- detect input dtype
__global__ void k_detect(const void* x, int* flag){
  int tid = threadIdx.x;
  const bf16* p = (const bf16*)x;
  int cnt = 0;
  for (int i = tid; i < 512; i += 64){
    float v = b2f(p[i]);
    if (!(fabsf(v) <= 64.f)) cnt++;
  }
  #pragma unroll
  for (int off = 32; off; off >>= 1) cnt += __shfl_down(cnt, off, 64);
  if (tid == 0) flag[0] = (cnt > 16) ? 1 : 0;
}

// ---------------------------------------------------------------- weight convert -> bf16 scratch
__global__ __launch_bounds__(256) void k_cvtw(const void* __restrict__ W,
        bf16* __restrict__ out, int n4, const int* __restrict__ flag){
  const bool f32in = flag[0] != 0;
  int i = blockIdx.x*256 + threadIdx.x;
  if (i < n4) stage4(W, (size_t)i*4, f32in, out + (size_t)i*4);
}

// ---------------------------------------------------------------- K1: spatial groupnorm -> xnT [l][c]
__global__ __launch_bounds__(256) void k_gn_s(const void* __restrict__ x,
        const void* __restrict__ gw, const void* __restrict__ gb,
        bf16* __restrict__ xnT, const int* __restrict__ flag, int n0){
  const bool f32in = flag[0] != 0;
  const int g = blockIdx.x;
  const int nl = blockIdx.y;
  const int n = n0 + nl;
  const int b = n >> 4, t = n & 15;
  const int tid = threadIdx.x;
  __shared__ float xs[576*17];     // [l][cg] padded
  __shared__ float red[4][2];
  __shared__ float stats[2];
  float s = 0.f, q = 0.f;
  for (int i = tid; i < 9216; i += 256){
    int cg = i / 576, l = i - cg*576;
    int c = g*16 + cg;
    float v = ldin(x, ((b*512 + c)*16 + t)*576 + l, f32in);
    xs[l*17 + cg] = v; s += v; q += v*v;
  }
  #pragma unroll
  for (int off = 32; off; off >>= 1){ s += __shfl_down(s, off, 64); q += __shfl_down(q, off, 64); }
  int wid = tid >> 6;
  if ((tid & 63) == 0){ red[wid][0] = s; red[wid][1] = q; }
  __syncthreads();
  if (tid == 0){
    float S = red[0][0]+red[1][0]+red[2][0]+red[3][0];
    float Q = red[0][1]+red[1][1]+red[2][1]+red[3][1];
    float mean = S * (1.f/9216.f);
    float var  = Q * (1.f/9216.f) - mean*mean;
    stats[0] = mean; stats[1] = rsqrtf(fmaxf(var, 0.f) + 1e-5f);
  }
  __syncthreads();
  float mean = stats[0], rstd = stats[1];
  for (int i = tid; i < 9216; i += 256){
    int l = i >> 4, cg = i & 15;
    int c = g*16 + cg;
    xnT[(size_t)(nl*576 + l)*512 + c] =
        f2b((xs[l*17 + cg] - mean)*rstd*ldin(gw, c, f32in) + ldin(gb, c, f32in));
  }
}

// ---------------------------------------------------------------- K2/K6: unified qkv GEMM
// Xf: flat [R][512] bf16. Wb: [1536][512] bf16. 128x128 tile, BK=64,
// global_load_lds staging into linear LDS; slot^=(row&7) XOR swizzle applied
// via pre-swizzled global source + swizzled ds_read (T2 / rule #21).
// mode 0: spatial epilogue (Q/K [l][512] + V [c][576] per nl); mode 1: temporal [m][o][t].
__global__ __launch_bounds__(256) void k_gemm_qkv(const bf16* __restrict__ Xf,
        const bf16* __restrict__ Wb, const void* __restrict__ Bv,
        bf16* __restrict__ Y, const int* __restrict__ flag,
        size_t kOff, size_t vOff, int mode){
  const bool f32in = flag[0] != 0;
  const int nwg = gridDim.x;
  const int bid = blockIdx.x;
  const int g = (bid & 7)*(nwg >> 3) + (bid >> 3);   // chunked XCD swizzle (nwg%8==0)
  const int mt = g / 12, nt = g - mt*12;
  const int r0 = mt*128, o0 = nt*128;
  const int tid = threadIdx.x, lane = tid & 63, w = tid >> 6;
  const int wm = w & 1, wn = w >> 1;
  const int r15 = lane & 15, quad = lane >> 4;
  const int rsw = r15 & 7;                 // read-side swizzle key (row&7 == r15&7)
  __shared__ bf16 As[128*64];
  __shared__ bf16 Bs[128*64];
  v4f acc[4][4];
  #pragma unroll
  for (int i = 0; i < 4; ++i)
    #pragma unroll
    for (int j = 0; j < 4; ++j) acc[i][j] = (v4f){0.f,0.f,0.f,0.f};
  for (int kc = 0; kc < 512; kc += 64){
    __syncthreads();
    #pragma unroll
    for (int r = 0; r < 4; ++r){
      int d = (tid + 256*r)*8;             // linear LDS elem offset this lane fills
      int row = d >> 6;
      int slot = (d >> 3) & 7;             // 16B slot within the 128B row
      int col = ((slot ^ (row & 7)) * 8);  // inverse-swizzled source column
      async_cp16(&Xf[(size_t)(r0 + row)*512 + kc + col], As + r*2048 + w*512);
      async_cp16(&Wb[(size_t)(o0 + row)*512 + kc + col], Bs + r*2048 + w*512);
    }
    __syncthreads();                        // compiler drains vmcnt(0) before barrier
    #pragma unroll
    for (int ks = 0; ks < 2; ++ks){
      v8s a[4], b[4];
      #pragma unroll
      for (int mi = 0; mi < 4; ++mi)
        a[mi] = *(const v8s*)&As[(wm*64 + mi*16 + r15)*64 + (((ks*4 + quad) ^ rsw)*8)];
      #pragma unroll
      for (int ni = 0; ni < 4; ++ni)
        b[ni] = *(const v8s*)&Bs[(wn*64 + ni*16 + r15)*64 + (((ks*4 + quad) ^ rsw)*8)];
      #pragma unroll
      for (int mi = 0; mi < 4; ++mi)
        #pragma unroll
        for (int ni = 0; ni < 4; ++ni)
          acc[mi][ni] = __builtin_amdgcn_mfma_f32_16x16x32_bf16(a[mi], b[ni], acc[mi][ni], 0, 0, 0);
    }
  }
  if (mode == 0){
    #pragma unroll
    for (int ni = 0; ni < 4; ++ni){
      int o = o0 + wn*64 + ni*16 + r15;
      int seg = o >> 9, oseg = o & 511;
      size_t segb = (seg==0) ? 0 : (seg==1) ? kOff : vOff;
      float bia = ldin(Bv, o, f32in);
      #pragma unroll
      for (int mi = 0; mi < 4; ++mi)
        #pragma unroll
        for (int rg = 0; rg < 4; ++rg){
          int rr = r0 + wm*64 + mi*16 + quad*4 + rg;
          int nl = rr / 576, l = rr - nl*576;
          size_t dst = segb + (size_t)nl*294912 +
                       ((seg==2) ? ((size_t)oseg*576 + l) : ((size_t)l*512 + oseg));
          Y[dst] = f2b(acc[mi][ni][rg] + bia);
        }
    }
  } else {
    #pragma unroll
    for (int ni = 0; ni < 4; ++ni){
      int o = o0 + wn*64 + ni*16 + r15;
      float bia = ldin(Bv, o, f32in);
      #pragma unroll
      for (int mi = 0; mi < 4; ++mi)
        #pragma unroll
        for (int rg = 0; rg < 4; ++rg){
          int rr = r0 + wm*64 + mi*16 + quad*4 + rg;
          int m = rr >> 4, t = rr & 15;
          Y[((size_t)m*1536 + o)*16 + t] = f2b(acc[mi][ni][rg] + bia);
        }
    }
  }
}

// ---------------------------------------------------------------- K3: spatial attention (flash MFMA) -> attT [l][c]
// R4: reg-prefetch K/V next-tile during compute (T14); exp2-domain softmax;
// defer-max THR=8 (T13); setprio around MFMA (T5).
__global__ __launch_bounds__(256, 4) void k_attn_s_mfma(const bf16* __restrict__ qkv,
        bf16* __restrict__ attT, size_t kOff, size_t vOff){
  const int bid = blockIdx.x;
  const int xcd = bid & 7, slot = bid >> 3;
  const int nl = xcd + 8*(slot/72);
  const int idx = slot - 72*(slot/72);
  const int head = idx/9, t0 = idx - 9*head;
  const int tid = threadIdx.x, lane = tid & 63, w = tid >> 6;
  const int r15 = lane & 15, quad = lane >> 4;
  __shared__ bf16 Ks[64*72];
  __shared__ bf16 Vs[64*72];
  __shared__ bf16 Ps[4][16*72];
  const bf16* QT = qkv + (size_t)nl*294912;
  const bf16* KT = qkv + kOff + (size_t)nl*294912;
  const bf16* Vp = qkv + vOff + (size_t)nl*294912;
  const int c0 = head*64;
  v8s aq0, aq1;
  {
    const bf16* qrow = QT + (size_t)(t0*64 + w*16 + r15)*512 + c0;
    aq0 = *(const v8s*)(qrow + quad*8);
    aq1 = *(const v8s*)(qrow + 32 + quad*8);
  }
  // staging geometry (same lanes->elems map as before, now via reg prefetch)
  int srow[4], scol[4];
  #pragma unroll
  for (int r = 0; r < 4; ++r){
    int e4 = (tid + 256*r)*4;
    srow[r] = e4 >> 6; scol[r] = e4 & 63;
  }
  ushort4 kreg[4], vreg[4];
  #pragma unroll
  for (int r = 0; r < 4; ++r){
    kreg[r] = *(const ushort4*)&KT[(size_t)srow[r]*512 + c0 + scol[r]];
    vreg[r] = *(const ushort4*)&Vp[(size_t)(c0 + srow[r])*576 + scol[r]];
  }
  v4f oc[4];
  #pragma unroll
  for (int ni = 0; ni < 4; ++ni) oc[ni] = (v4f){0.f,0.f,0.f,0.f};
  float m_run[4] = {-1e30f,-1e30f,-1e30f,-1e30f};
  float l_run[4] = {0.f,0.f,0.f,0.f};
  const float SC = 0.180336880f;            // 0.125 * log2(e): exp2 domain
  for (int sc = 0; sc < 9; ++sc){
    __syncthreads();
    #pragma unroll
    for (int r = 0; r < 4; ++r){
      *(ushort4*)&Ks[srow[r]*72 + scol[r]] = kreg[r];
      *(ushort4*)&Vs[srow[r]*72 + scol[r]] = vreg[r];
    }
    __syncthreads();
    if (sc < 8){                            // prefetch next tile; latency hides under compute
      #pragma unroll
      for (int r = 0; r < 4; ++r){
        kreg[r] = *(const ushort4*)&KT[(size_t)((sc+1)*64 + srow[r])*512 + c0 + scol[r]];
        vreg[r] = *(const ushort4*)&Vp[(size_t)(c0 + srow[r])*576 + (sc+1)*64 + scol[r]];
      }
    }
    v4f sa[4];
    #pragma unroll
    for (int sj = 0; sj < 4; ++sj) sa[sj] = (v4f){0.f,0.f,0.f,0.f};
    __builtin_amdgcn_s_setprio(1);
    #pragma unroll
    for (int sj = 0; sj < 4; ++sj){
      v8s b0 = *(const v8s*)&Ks[(sj*16 + r15)*72 + quad*8];
      v8s b1 = *(const v8s*)&Ks[(sj*16 + r15)*72 + 32 + quad*8];
      sa[sj] = __builtin_amdgcn_mfma_f32_16x16x32_bf16(aq0, b0, sa[sj], 0, 0, 0);
      sa[sj] = __builtin_amdgcn_mfma_f32_16x16x32_bf16(aq1, b1, sa[sj], 0, 0, 0);
    }
    __builtin_amdgcn_s_setprio(0);
    float cmx[4] = {-1e30f,-1e30f,-1e30f,-1e30f};
    #pragma unroll
    for (int sj = 0; sj < 4; ++sj)
      #pragma unroll
      for (int rg = 0; rg < 4; ++rg){
        float v = sa[sj][rg]*SC;
        sa[sj][rg] = v;
        cmx[rg] = fmaxf(cmx[rg], v);
      }
    #pragma unroll
    for (int off = 1; off < 16; off <<= 1)
      #pragma unroll
      for (int rg = 0; rg < 4; ++rg) cmx[rg] = fmaxf(cmx[rg], __shfl_xor(cmx[rg], off, 64));
    float grow = fmaxf(fmaxf(cmx[0]-m_run[0], cmx[1]-m_run[1]),
                       fmaxf(cmx[2]-m_run[2], cmx[3]-m_run[3]));
    if (__any(grow > 8.f)){                 // defer-max: rescale only on real growth
      #pragma unroll
      for (int rg = 0; rg < 4; ++rg){
        float mnew = fmaxf(m_run[rg], cmx[rg]);
        float al = exp2f(m_run[rg] - mnew);
        m_run[rg] = mnew;
        l_run[rg] *= al;
        #pragma unroll
        for (int ni = 0; ni < 4; ++ni) oc[ni][rg] *= al;
      }
    }
    float psum[4] = {0.f,0.f,0.f,0.f};
    #pragma unroll
    for (int sj = 0; sj < 4; ++sj)
      #pragma unroll
      for (int rg = 0; rg < 4; ++rg){
        float e = exp2f(sa[sj][rg] - m_run[rg]);
        sa[sj][rg] = e; psum[rg] += e;
      }
    #pragma unroll
    for (int off = 1; off < 16; off <<= 1)
      #pragma unroll
      for (int rg = 0; rg < 4; ++rg) psum[rg] += __shfl_xor(psum[rg], off, 64);
    #pragma unroll
    for (int rg = 0; rg < 4; ++rg) l_run[rg] += psum[rg];
    #pragma unroll
    for (int sj = 0; sj < 4; ++sj)
      #pragma unroll
      for (int rg = 0; rg < 4; ++rg)
        Ps[w][(quad*4 + rg)*72 + sj*16 + r15] = f2b(sa[sj][rg]);
    __builtin_amdgcn_s_setprio(1);
    #pragma unroll
    for (int ks = 0; ks < 2; ++ks){
      v8s a = *(const v8s*)&Ps[w][r15*72 + ks*32 + quad*8];
      #pragma unroll
      for (int ni = 0; ni < 4; ++ni){
        v8s b = *(const v8s*)&Vs[(ni*16 + r15)*72 + ks*32 + quad*8];
        oc[ni] = __builtin_amdgcn_mfma_f32_16x16x32_bf16(a, b, oc[ni], 0, 0, 0);
      }
    }
    __builtin_amdgcn_s_setprio(0);
  }
  float inv[4];
  #pragma unroll
  for (int rg = 0; rg < 4; ++rg) inv[rg] = 1.f / l_run[rg];
  #pragma unroll
  for (int ni = 0; ni < 4; ++ni)
    #pragma unroll
    for (int rg = 0; rg < 4; ++rg){
      int t = t0*64 + w*16 + quad*4 + rg;
      attT[(size_t)(nl*576 + t)*512 + c0 + ni*16 + r15] = f2b(oc[ni][rg]*inv[rg]);
    }
}

// ---------------------------------------------------------------- K4: spatial proj + residual (MFMA)
// R1: LDS-transpose epilogue with coalesced 16B stores (x2 and x2T).
__global__ __launch_bounds__(256) void k_proj_s_mfma(const bf16* __restrict__ AT,
        const bf16* __restrict__ Wb, const void* __restrict__ Bv,
        const void* __restrict__ xin, bf16* __restrict__ x2,
        bf16* __restrict__ x2T, int doT,
        const int* __restrict__ flag, int n0){
  const bool f32in = flag[0] != 0;
  const int o0 = blockIdx.x * 128;
  const int l0 = blockIdx.y * 64;
  const int nl = blockIdx.z;
  const int n = n0 + nl;
  const int b = n >> 4, t = n & 15;
  const int tid = threadIdx.x, lane = tid & 63;
  const int wm = (tid >> 6) & 1, wn = tid >> 7;
  const int r15 = lane & 15, quad = lane >> 4;
  __shared__ bf16 As[128*72];
  __shared__ bf16 Bs[64*72];
  v4f acc[4][2];
  #pragma unroll
  for (int i = 0; i < 4; ++i)
    #pragma unroll
    for (int j = 0; j < 2; ++j) acc[i][j] = (v4f){0.f,0.f,0.f,0.f};
  for (int kc = 0; kc < 512; kc += 64){
    __syncthreads();
    #pragma unroll
    for (int r = 0; r < 8; ++r){
      int e4 = (tid + 256*r)*4;
      int row = e4 >> 6, k = e4 & 63;
      stage4b(&Wb[(size_t)(o0+row)*512 + kc + k], &As[row*72 + k]);
    }
    #pragma unroll
    for (int r = 0; r < 4; ++r){
      int e4 = (tid + 256*r)*4;
      int row = e4 >> 6, k = e4 & 63;
      stage4b(&AT[(size_t)(nl*576 + l0 + row)*512 + kc + k], &Bs[row*72 + k]);
    }
    __syncthreads();
    #pragma unroll
    for (int ks = 0; ks < 2; ++ks){
      v8s a[4], b[2];
      #pragma unroll
      for (int mi = 0; mi < 4; ++mi)
        a[mi] = *(const v8s*)&As[(wm*64 + mi*16 + r15)*72 + ks*32 + quad*8];
      #pragma unroll
      for (int ni = 0; ni < 2; ++ni)
        b[ni] = *(const v8s*)&Bs[(wn*32 + ni*16 + r15)*72 + ks*32 + quad*8];
      #pragma unroll
      for (int mi = 0; mi < 4; ++mi)
        #pragma unroll
        for (int ni = 0; ni < 2; ++ni)
          acc[mi][ni] = __builtin_amdgcn_mfma_f32_16x16x32_bf16(a[mi], b[ni], acc[mi][ni], 0, 0, 0);
    }
  }
  // -------- epilogue: stage acc+bias into As as [o_rel][l_rel] (stride 72)
  __syncthreads();
  #pragma unroll
  for (int mi = 0; mi < 4; ++mi){
    int orel = wm*64 + mi*16 + quad*4;
    #pragma unroll
    for (int rg = 0; rg < 4; ++rg){
      float bia = ldin(Bv, o0 + orel + rg, f32in);
      #pragma unroll
      for (int ni = 0; ni < 2; ++ni)
        As[(orel + rg)*72 + wn*32 + ni*16 + r15] = f2b(acc[mi][ni][rg] + bia);
    }
  }
  __syncthreads();
  // phase 1: residual add + coalesced x2 write (+writeback for phase 2)
  const size_t xrow = ((size_t)(b*512 + o0)*16 + t)*576 + l0;
  for (int it = 0; it < 4; ++it){
    int idx = tid + it*256;             // 1024 chunks of 8 elems
    int o = idx >> 3, lc = (idx & 7)*8;
    union { bf16 h[8]; v8s v; } val;
    val.v = *(const v8s*)&As[o*72 + lc];
    size_t ga = xrow + (size_t)o*9216 + lc;
    if (f32in){
      const float* xp = (const float*)xin + ga;
      float4 f0 = *(const float4*)xp;
      float4 f1 = *(const float4*)(xp + 4);
      val.h[0] = f2b(b2f(val.h[0]) + f0.x);
      val.h[1] = f2b(b2f(val.h[1]) + f0.y);
      val.h[2] = f2b(b2f(val.h[2]) + f0.z);
      val.h[3] = f2b(b2f(val.h[3]) + f0.w);
      val.h[4] = f2b(b2f(val.h[4]) + f1.x);
      val.h[5] = f2b(b2f(val.h[5]) + f1.y);
      val.h[6] = f2b(b2f(val.h[6]) + f1.z);
      val.h[7] = f2b(b2f(val.h[7]) + f1.w);
    } else {
      union { bf16 h[8]; v8s v; } xv;
      xv.v = *(const v8s*)((const bf16*)xin + ga);
      #pragma unroll
      for (int j = 0; j < 8; ++j) val.h[j] = f2b(b2f(val.h[j]) + b2f(xv.h[j]));
    }
    *(v8s*)&x2[ga] = val.v;
    if (doT) *(v8s*)&As[o*72 + lc] = val.v;
  }
  if (doT){
    __syncthreads();
    // phase 2: x2T [m][t][c]: per chunk, 8 consecutive o at fixed l
    const size_t tbase = ((size_t)b*576 + l0)*8192 + (size_t)t*512 + o0;
    for (int it = 0; it < 4; ++it){
      int l = (tid & 15) + it*16;
      int ocg = (tid >> 4)*8;
      union { bf16 h[8]; v8s v; } val;
      #pragma unroll
      for (int j = 0; j < 8; ++j) val.h[j] = As[(ocg + j)*72 + l];
      *(v8s*)&x2T[tbase + (size_t)l*8192 + ocg] = val.v;
    }
  }
}

// ---------------------------------------------------------------- K5a: temporal groupnorm (scattered x2) -> xnT [m][t][c]
__global__ __launch_bounds__(256) void k_gn_t(const bf16* __restrict__ x2,
        const void* __restrict__ gw, const void* __restrict__ gb,
        bf16* __restrict__ xnT, const int* __restrict__ flag, int m0){
  const bool f32in = flag[0] != 0;
  const int ml = blockIdx.x;
  const int m = m0 + ml;
  const int b = m / 576, l = m - b*576;
  const int tid = threadIdx.x;
  __shared__ float xs[8192];
  __shared__ float mg[32], rg[32];
  for (int i = tid; i < 8192; i += 256){
    int t = i >> 9, c = i & 511;
    xs[i] = b2f(x2[((b*512 + c)*16 + t)*576 + l]);
  }
  __syncthreads();
  {
    int g = tid >> 3, ii = tid & 7;
    float s = 0.f, q = 0.f;
    for (int idx = ii; idx < 256; idx += 8){
      int t = idx >> 4, cg = idx & 15;
      float v = xs[t*512 + g*16 + cg]; s += v; q += v*v;
    }
    #pragma unroll
    for (int off = 1; off < 8; off <<= 1){ s += __shfl_xor(s, off, 64); q += __shfl_xor(q, off, 64); }
    if (ii == 0){
      float mean = s*(1.f/256.f);
      float var  = q*(1.f/256.f) - mean*mean;
      mg[g] = mean; rg[g] = rsqrtf(fmaxf(var, 0.f) + 1e-5f);
    }
  }
  __syncthreads();
  for (int i = tid; i < 8192; i += 256){
    int c = i & 511, g = c >> 4;
    xnT[(size_t)ml*8192 + i] = f2b((xs[i] - mg[g])*rg[g]*ldin(gw, c, f32in) + ldin(gb, c, f32in));
  }
}

// ---------------------------------------------------------------- K5b: temporal groupnorm (coalesced x2T)
__global__ __launch_bounds__(256) void k_gn_t2(const bf16* __restrict__ x2T,
        const void* __restrict__ gw, const void* __restrict__ gb,
        bf16* __restrict__ xnT, const int* __restrict__ flag, int m0){
  const bool f32in = flag[0] != 0;
  const int ml = blockIdx.x;
  const int m = m0 + ml;
  const int tid = threadIdx.x;
  __shared__ float xs[8192];
  __shared__ float mg[32], rg[32];
  for (int i = tid; i < 8192; i += 256)
    xs[i] = b2f(x2T[(size_t)m*8192 + i]);     // [t][c] order, fully coalesced
  __syncthreads();
  {
    int g = tid >> 3, ii = tid & 7;
    float s = 0.f, q = 0.f;
    for (int idx = ii; idx < 256; idx += 8){
      int t = idx >> 4, cg = idx & 15;
      float v = xs[t*512 + g*16 + cg]; s += v; q += v*v;
    }
    #pragma unroll
    for (int off = 1; off < 8; off <<= 1){ s += __shfl_xor(s, off, 64); q += __shfl_xor(q, off, 64); }
    if (ii == 0){
      float mean = s*(1.f/256.f);
      float var  = q*(1.f/256.f) - mean*mean;
      mg[g] = mean; rg[g] = rsqrtf(fmaxf(var, 0.f) + 1e-5f);
    }
  }
  __syncthreads();
  for (int i = tid; i < 8192; i += 256){
    int c = i & 511, g = c >> 4;
    xnT[(size_t)ml*8192 + i] = f2b((xs[i] - mg[g])*rg[g]*ldin(gw, c, f32in) + ldin(gb, c, f32in));
  }
}

// ---------------------------------------------------------------- K7: temporal attention -> attT [m][t][c]
__global__ __launch_bounds__(256) void k_attn_t(const bf16* __restrict__ qkv,
        const void* __restrict__ tbk, const void* __restrict__ tbv,
        bf16* __restrict__ attT, const int* __restrict__ flag){
  const bool f32in = flag[0] != 0;
  const int head = blockIdx.x;
  const int ml = blockIdx.y;
  const int tid = threadIdx.x;
  __shared__ float qsT[16*68], ksT[16*68], vsT[16*68];  // [t][c], stride 68 (16B-aligned rows)
  __shared__ float tks[33*68], tvs[33*68];              // [d][c]
  __shared__ float ps[16*17];
  const int base = (ml*1536 + head*64)*16;
  for (int i = tid; i < 1024; i += 256){
    int c = i >> 4, t = i & 15;
    qsT[t*68 + c] = b2f(qkv[base + i]);
    ksT[t*68 + c] = b2f(qkv[base + 8192 + i]);
    vsT[t*68 + c] = b2f(qkv[base + 16384 + i]);
  }
  for (int i = tid; i < 33*64; i += 256){
    int d = i >> 6, c = i & 63;
    tks[d*68 + c] = ldin(tbk, i, f32in);
    tvs[d*68 + c] = ldin(tbv, i, f32in);
  }
  __syncthreads();
  {
    const int t = tid >> 4, s = tid & 15;
    const float4* qt = (const float4*)&qsT[t*68];
    const float4* kr = (const float4*)&ksT[s*68];
    const float4* q2 = (const float4*)&qsT[s*68];
    const float4* tr = (const float4*)&tks[(t - s + 16)*68];
    float qk = 0.f, rp = 0.f;
    #pragma unroll
    for (int c4 = 0; c4 < 16; ++c4){
      float4 a = qt[c4], b = kr[c4];
      qk += a.x*b.x + a.y*b.y + a.z*b.z + a.w*b.w;
      float4 a2 = q2[c4], tb = tr[c4];
      rp += a2.x*tb.x + a2.y*tb.y + a2.z*tb.z + a2.w*tb.w;
    }
    float logit = 0.125f*qk + 0.35355339059327373f*rp;
    if (s > t) logit = -1e8f;
    float mx = logit;
    #pragma unroll
    for (int off = 8; off; off >>= 1) mx = fmaxf(mx, __shfl_xor(mx, off, 16));
    float e = __expf(logit - mx);
    float tot = e;
    #pragma unroll
    for (int off = 8; off; off >>= 1) tot += __shfl_xor(tot, off, 16);
    ps[t*17 + s] = e / tot;
  }
  __syncthreads();
  {
    const int c4 = tid & 15, t = tid >> 4;
    float4 acc = {0.f,0.f,0.f,0.f};
    #pragma unroll
    for (int s = 0; s < 16; ++s){
      float p = ps[t*17 + s];
      float4 v4 = *(const float4*)&vsT[s*68 + c4*4];
      float4 t4 = *(const float4*)&tvs[(s - t + 16)*68 + c4*4];
      acc.x += p*(v4.x + t4.x); acc.y += p*(v4.y + t4.y);
      acc.z += p*(v4.z + t4.z); acc.w += p*(v4.w + t4.w);
    }
    union { bf16 h[4]; ushort4 u; } o;
    o.h[0] = f2b(acc.x); o.h[1] = f2b(acc.y); o.h[2] = f2b(acc.z); o.h[3] = f2b(acc.w);
    *(ushort4*)&attT[(size_t)ml*8192 + t*512 + head*64 + c4*4] = o.u;
  }
}

// ---------------------------------------------------------------- K8: temporal proj + residual -> out (MFMA, coalesced)
__global__ __launch_bounds__(256) void k_proj_t_mfma(const bf16* __restrict__ AT,
        const bf16* __restrict__ Wb, const void* __restrict__ Bv,
        const bf16* __restrict__ x2, void* __restrict__ out,
        const int* __restrict__ flag, int m0){
  const bool f32in = flag[0] != 0;
  const int o0 = blockIdx.x * 128;
  const int tp = blockIdx.y;            // t-pair
  const int mg0 = blockIdx.z * 32;      // m base (32 | 576)
  const int tid = threadIdx.x, lane = tid & 63;
  const int wm = (tid >> 6) & 1, wn = tid >> 7;
  const int r15 = lane & 15, quad = lane >> 4;
  __shared__ bf16 As[128*72];
  __shared__ bf16 Bs[64*72];
  v4f acc[4][2];
  #pragma unroll
  for (int i = 0; i < 4; ++i)
    #pragma unroll
    for (int j = 0; j < 2; ++j) acc[i][j] = (v4f){0.f,0.f,0.f,0.f};
  for (int kc = 0; kc < 512; kc += 64){
    __syncthreads();
    #pragma unroll
    for (int r = 0; r < 8; ++r){
      int e4 = (tid + 256*r)*4;
      int row = e4 >> 6, k = e4 & 63;
      stage4b(&Wb[(size_t)(o0+row)*512 + kc + k], &As[row*72 + k]);
    }
    #pragma unroll
    for (int r = 0; r < 4; ++r){
      int e4 = (tid + 256*r)*4;
      int row = e4 >> 6, k = e4 & 63;
      stage4b(&AT[(size_t)(mg0 + (row & 31))*8192 + (tp*2 + (row >> 5))*512 + kc + k],
              &Bs[row*72 + k]);
    }
    __syncthreads();
    #pragma unroll
    for (int ks = 0; ks < 2; ++ks){
      v8s a[4], b[2];
      #pragma unroll
      for (int mi = 0; mi < 4; ++mi)
        a[mi] = *(const v8s*)&As[(wm*64 + mi*16 + r15)*72 + ks*32 + quad*8];
      #pragma unroll
      for (int ni = 0; ni < 2; ++ni)
        b[ni] = *(const v8s*)&Bs[(wn*32 + ni*16 + r15)*72 + ks*32 + quad*8];
      #pragma unroll
      for (int mi = 0; mi < 4; ++mi)
        #pragma unroll
        for (int ni = 0; ni < 2; ++ni)
          acc[mi][ni] = __builtin_amdgcn_mfma_f32_16x16x32_bf16(a[mi], b[ni], acc[mi][ni], 0, 0, 0);
    }
  }
  const int tt = tp*2 + wn;
  #pragma unroll
  for (int mi = 0; mi < 4; ++mi)
    #pragma unroll
    for (int rg = 0; rg < 4; ++rg){
      int o = o0 + wm*64 + mi*16 + quad*4 + rg;
      float bia = ldin(Bv, o, f32in);
      #pragma unroll
      for (int ni = 0; ni < 2; ++ni){
        int m = m0 + mg0 + ni*16 + r15;
        int b = m / 576, l = m - b*576;
        size_t addr = ((size_t)(b*512 + o)*16 + tt)*576 + l;
        float val = acc[mi][ni][rg] + bia + b2f(x2[addr]);
        if (f32in) ((float*)out)[addr] = val;
        else       ((bf16*)out)[addr] = f2b(val);
      }
    }
}

// ----------------------------------------------------------------
extern "C" void kernel_launch(void* const* d_in, const int* in_sizes, int n_in,
                              void* d_out, int out_size, void* d_ws, size_t ws_size,
                              hipStream_t stream){
  const void* x   = d_in[0];
  const void* nsw = d_in[1];
  const void* nsb = d_in[2];
  const void* qsw = d_in[3];
  const void* qsb = d_in[4];
  const void* psw = d_in[5];
  const void* psb = d_in[6];
  const void* ntw = d_in[7];
  const void* ntb = d_in[8];
  const void* qtw = d_in[9];
  const void* qtb = d_in[10];
  const void* ptw = d_in[11];
  const void* ptb = d_in[12];
  const void* rpk = d_in[13];
  const void* rpv = d_in[14];

  // Chunking and x2T gate from ws_size (constant across calls -> graph-safe).
  const size_t S_full = (size_t)32*294912;
  const size_t need_full = 256 + (S_full*5 + 9437184)*2;
  const size_t need_T    = 256 + (S_full*5 + (size_t)2*9437184)*2;  // +18.9 MB for x2T
  const int NCH = (ws_size >= need_full) ? 32 : 8;
  const int MCH = (NCH == 32) ? 1152 : 288;
  const size_t S = (size_t)NCH*294912;
  const int useT = (NCH == 32 && ws_size >= need_T) ? 1 : 0;

  int*  flag = (int*)d_ws;
  bf16* A  = (bf16*)((char*)d_ws + 256);   // S: xnT_s / xnT_t
  bf16* A2 = A  + S;                        // S: attT_s / attT_t (+ transient W copy)
  bf16* Bq = A2 + S;                        // 3S: qkv (+ transient W copies)
  bf16* Cx = Bq + 3*S;                      // 9,437,184: x2 residual
  bf16* Cx2 = Cx + 9437184;                 // 9,437,184: x2T [m][t][c] (if useT)
  const size_t kOff = S, vOff = 2*S;
  bf16* Wcv  = A2;
  bf16* Wcv2 = Bq;

  k_detect<<<1, 64, 0, stream>>>(x, flag);

  for (int n0 = 0; n0 < 32; n0 += NCH){
    k_gn_s       <<<dim3(32, NCH),   256, 0, stream>>>(x, nsw, nsb, A, flag, n0);
    k_cvtw       <<<dim3(768),       256, 0, stream>>>(qsw, Wcv, 196608, flag);
    k_gemm_qkv   <<<dim3(NCH*54),    256, 0, stream>>>(A, Wcv, qsb, Bq, flag, kOff, vOff, 0);
    k_attn_s_mfma<<<dim3(72*NCH),    256, 0, stream>>>(Bq, A2, kOff, vOff);
    // proj_s weight pre-convert into Bq (qkv dead after attn_s)
    k_cvtw       <<<dim3(256),       256, 0, stream>>>(psw, Bq, 65536, flag);
    k_proj_s_mfma<<<dim3(4, 9, NCH), 256, 0, stream>>>(A2, Bq, psb, x, Cx, Cx2, useT, flag, n0);
  }
  for (int m0 = 0; m0 < 1152; m0 += MCH){
    if (useT) k_gn_t2<<<dim3(MCH),   256, 0, stream>>>(Cx2, ntw, ntb, A, flag, m0);
    else      k_gn_t <<<dim3(MCH),   256, 0, stream>>>(Cx,  ntw, ntb, A, flag, m0);
    k_cvtw       <<<dim3(768),       256, 0, stream>>>(qtw, Wcv, 196608, flag);
    k_gemm_qkv   <<<dim3((MCH/2)*3), 256, 0, stream>>>(A, Wcv, qtb, Bq, flag, 0, 0, 1);
    k_attn_t     <<<dim3(8, MCH),    256, 0, stream>>>(Bq, rpk, rpv, A2, flag);
    k_cvtw       <<<dim3(256),       256, 0, stream>>>(ptw, Wcv2, 65536, flag);
    k_proj_t_mfma<<<dim3(4, 8, MCH/32), 256, 0, stream>>>(A2, Wcv2, ptb, Cx, d_out, flag, m0);
  }
}

// Round 8
// 492.852 us; speedup vs baseline: 1.0390x; 1.0390x over previous
//
#include <hip/hip_runtime.h>
#include <hip/hip_bf16.h>

typedef __hip_bfloat16 bf16;
typedef __attribute__((ext_vector_type(8))) short v8s;
typedef __attribute__((ext_vector_type(4))) float v4f;

__device__ __forceinline__ float b2f(bf16 v){ return __bfloat162float(v); }
__device__ __forceinline__ bf16  f2b(float v){ return __float2bfloat16(v); }

// Inputs may be bf16 OR f32 — runtime-detected flag (1 => f32). Output dtype follows.
__device__ __forceinline__ float ldin(const void* p, int i, bool f32in){
  return f32in ? ((const float*)p)[i] : b2f(((const bf16*)p)[i]);
}

// stage 4 consecutive source elems (f32-or-bf16) into dst as bf16 (8B write)
__device__ __forceinline__ void stage4(const void* src, size_t off, bool f32in, bf16* dst){
  union { bf16 h[4]; ushort4 u; } tmp;
  if (f32in){
    float4 f = *(const float4*)((const float*)src + off);
    tmp.h[0] = f2b(f.x); tmp.h[1] = f2b(f.y); tmp.h[2] = f2b(f.z); tmp.h[3] = f2b(f.w);
  } else {
    tmp.u = *(const ushort4*)((const ushort*)src + off);
  }
  *(ushort4*)dst = tmp.u;
}
__device__ __forceinline__ void stage4b(const bf16* src, bf16* dst){
  *(ushort4*)dst = *(const ushort4*)src;
}

// async global->LDS, 16B per lane. LDS dest must be wave-uniform base (HW adds lane*16).
__device__ __forceinline__ void async_cp16(const bf16* g, bf16* l){
  __builtin_amdgcn_global_load_lds(
      (const __attribute__((address_space(1))) unsigned int*)g,
      (__attribute__((address_space(3))) unsigned int*)l, 16, 0, 0);
}

// Problem: B=2, C=512, T=16, H=W=24, heads=8, ch=64
// ws: flag | A (S) | A2 (S) | Bq (3S) | Cx 9,437,184 | [Cx2 9,437,184 if room]
// R1: proj_s epilogue request-bound -> LDS-transpose epilogue (WIN, -58us).
// R2: qkv GEMMs -> unified 128x128 global_load_lds GEMM.
// R3: XOR-swizzle via pre-swizzled global source + swizzled ds_read (conflict fix).
// R4: attn_s reg-prefetch + exp2 + defer-max + setprio: FAILED (+3.5us) —
//     VALUBusy rose 39->47; cost is softmax cross-lane ops, not load latency;
//     setprio is null/negative on lockstep 4-wave blocks (m190).
// R6: attn_s: drop setprio; conditional max-reduce (shfl-max only when a lane
//     partial exceeds m+8); row-sum via ones-MFMA into 5th accumulator
//     (removes psum shfl reduce).
// R7: container infra failure, no measurement — resubmitted unchanged.

// ---------------------------------------------------------------- detect input dtype
__global__ void k_detect(const void* x, int* flag){
  int tid = threadIdx.x;
  const bf16* p = (const bf16*)x;
  int cnt = 0;
  for (int i = tid; i < 512; i += 64){
    float v = b2f(p[i]);
    if (!(fabsf(v) <= 64.f)) cnt++;
  }
  #pragma unroll
  for (int off = 32; off; off >>= 1) cnt += __shfl_down(cnt, off, 64);
  if (tid == 0) flag[0] = (cnt > 16) ? 1 : 0;
}

// ---------------------------------------------------------------- weight convert -> bf16 scratch
__global__ __launch_bounds__(256) void k_cvtw(const void* __restrict__ W,
        bf16* __restrict__ out, int n4, const int* __restrict__ flag){
  const bool f32in = flag[0] != 0;
  int i = blockIdx.x*256 + threadIdx.x;
  if (i < n4) stage4(W, (size_t)i*4, f32in, out + (size_t)i*4);
}

// ---------------------------------------------------------------- K1: spatial groupnorm -> xnT [l][c]
__global__ __launch_bounds__(256) void k_gn_s(const void* __restrict__ x,
        const void* __restrict__ gw, const void* __restrict__ gb,
        bf16* __restrict__ xnT, const int* __restrict__ flag, int n0){
  const bool f32in = flag[0] != 0;
  const int g = blockIdx.x;
  const int nl = blockIdx.y;
  const int n = n0 + nl;
  const int b = n >> 4, t = n & 15;
  const int tid = threadIdx.x;
  __shared__ float xs[576*17];     // [l][cg] padded
  __shared__ float red[4][2];
  __shared__ float stats[2];
  float s = 0.f, q = 0.f;
  for (int i = tid; i < 9216; i += 256){
    int cg = i / 576, l = i - cg*576;
    int c = g*16 + cg;
    float v = ldin(x, ((b*512 + c)*16 + t)*576 + l, f32in);
    xs[l*17 + cg] = v; s += v; q += v*v;
  }
  #pragma unroll
  for (int off = 32; off; off >>= 1){ s += __shfl_down(s, off, 64); q += __shfl_down(q, off, 64); }
  int wid = tid >> 6;
  if ((tid & 63) == 0){ red[wid][0] = s; red[wid][1] = q; }
  __syncthreads();
  if (tid == 0){
    float S = red[0][0]+red[1][0]+red[2][0]+red[3][0];
    float Q = red[0][1]+red[1][1]+red[2][1]+red[3][1];
    float mean = S * (1.f/9216.f);
    float var  = Q * (1.f/9216.f) - mean*mean;
    stats[0] = mean; stats[1] = rsqrtf(fmaxf(var, 0.f) + 1e-5f);
  }
  __syncthreads();
  float mean = stats[0], rstd = stats[1];
  for (int i = tid; i < 9216; i += 256){
    int l = i >> 4, cg = i & 15;
    int c = g*16 + cg;
    xnT[(size_t)(nl*576 + l)*512 + c] =
        f2b((xs[l*17 + cg] - mean)*rstd*ldin(gw, c, f32in) + ldin(gb, c, f32in));
  }
}

// ---------------------------------------------------------------- K2/K6: unified qkv GEMM
// Xf: flat [R][512] bf16. Wb: [1536][512] bf16. 128x128 tile, BK=64,
// global_load_lds staging into linear LDS; slot^=(row&7) XOR swizzle applied
// via pre-swizzled global source + swizzled ds_read (T2 / rule #21).
// mode 0: spatial epilogue (Q/K [l][512] + V [c][576] per nl); mode 1: temporal [m][o][t].
__global__ __launch_bounds__(256) void k_gemm_qkv(const bf16* __restrict__ Xf,
        const bf16* __restrict__ Wb, const void* __restrict__ Bv,
        bf16* __restrict__ Y, const int* __restrict__ flag,
        size_t kOff, size_t vOff, int mode){
  const bool f32in = flag[0] != 0;
  const int nwg = gridDim.x;
  const int bid = blockIdx.x;
  const int g = (bid & 7)*(nwg >> 3) + (bid >> 3);   // chunked XCD swizzle (nwg%8==0)
  const int mt = g / 12, nt = g - mt*12;
  const int r0 = mt*128, o0 = nt*128;
  const int tid = threadIdx.x, lane = tid & 63, w = tid >> 6;
  const int wm = w & 1, wn = w >> 1;
  const int r15 = lane & 15, quad = lane >> 4;
  const int rsw = r15 & 7;                 // read-side swizzle key (row&7 == r15&7)
  __shared__ bf16 As[128*64];
  __shared__ bf16 Bs[128*64];
  v4f acc[4][4];
  #pragma unroll
  for (int i = 0; i < 4; ++i)
    #pragma unroll
    for (int j = 0; j < 4; ++j) acc[i][j] = (v4f){0.f,0.f,0.f,0.f};
  for (int kc = 0; kc < 512; kc += 64){
    __syncthreads();
    #pragma unroll
    for (int r = 0; r < 4; ++r){
      int d = (tid + 256*r)*8;             // linear LDS elem offset this lane fills
      int row = d >> 6;
      int slot = (d >> 3) & 7;             // 16B slot within the 128B row
      int col = ((slot ^ (row & 7)) * 8);  // inverse-swizzled source column
      async_cp16(&Xf[(size_t)(r0 + row)*512 + kc + col], As + r*2048 + w*512);
      async_cp16(&Wb[(size_t)(o0 + row)*512 + kc + col], Bs + r*2048 + w*512);
    }
    __syncthreads();                        // compiler drains vmcnt(0) before barrier
    #pragma unroll
    for (int ks = 0; ks < 2; ++ks){
      v8s a[4], b[4];
      #pragma unroll
      for (int mi = 0; mi < 4; ++mi)
        a[mi] = *(const v8s*)&As[(wm*64 + mi*16 + r15)*64 + (((ks*4 + quad) ^ rsw)*8)];
      #pragma unroll
      for (int ni = 0; ni < 4; ++ni)
        b[ni] = *(const v8s*)&Bs[(wn*64 + ni*16 + r15)*64 + (((ks*4 + quad) ^ rsw)*8)];
      #pragma unroll
      for (int mi = 0; mi < 4; ++mi)
        #pragma unroll
        for (int ni = 0; ni < 4; ++ni)
          acc[mi][ni] = __builtin_amdgcn_mfma_f32_16x16x32_bf16(a[mi], b[ni], acc[mi][ni], 0, 0, 0);
    }
  }
  if (mode == 0){
    #pragma unroll
    for (int ni = 0; ni < 4; ++ni){
      int o = o0 + wn*64 + ni*16 + r15;
      int seg = o >> 9, oseg = o & 511;
      size_t segb = (seg==0) ? 0 : (seg==1) ? kOff : vOff;
      float bia = ldin(Bv, o, f32in);
      #pragma unroll
      for (int mi = 0; mi < 4; ++mi)
        #pragma unroll
        for (int rg = 0; rg < 4; ++rg){
          int rr = r0 + wm*64 + mi*16 + quad*4 + rg;
          int nl = rr / 576, l = rr - nl*576;
          size_t dst = segb + (size_t)nl*294912 +
                       ((seg==2) ? ((size_t)oseg*576 + l) : ((size_t)l*512 + oseg));
          Y[dst] = f2b(acc[mi][ni][rg] + bia);
        }
    }
  } else {
    #pragma unroll
    for (int ni = 0; ni < 4; ++ni){
      int o = o0 + wn*64 + ni*16 + r15;
      float bia = ldin(Bv, o, f32in);
      #pragma unroll
      for (int mi = 0; mi < 4; ++mi)
        #pragma unroll
        for (int rg = 0; rg < 4; ++rg){
          int rr = r0 + wm*64 + mi*16 + quad*4 + rg;
          int m = rr >> 4, t = rr & 15;
          Y[((size_t)m*1536 + o)*16 + t] = f2b(acc[mi][ni][rg] + bia);
        }
    }
  }
}

// ---------------------------------------------------------------- K3: spatial attention (flash MFMA) -> attT [l][c]
// R6: conditional max-reduce + ones-MFMA row-sum (no psum shfl); no setprio.
__global__ __launch_bounds__(256, 4) void k_attn_s_mfma(const bf16* __restrict__ qkv,
        bf16* __restrict__ attT, size_t kOff, size_t vOff){
  const int bid = blockIdx.x;
  const int xcd = bid & 7, slot = bid >> 3;
  const int nl = xcd + 8*(slot/72);
  const int idx = slot - 72*(slot/72);
  const int head = idx/9, t0 = idx - 9*head;
  const int tid = threadIdx.x, lane = tid & 63, w = tid >> 6;
  const int r15 = lane & 15, quad = lane >> 4;
  __shared__ bf16 Ks[64*72];
  __shared__ bf16 Vs[64*72];
  __shared__ bf16 Ps[4][16*72];
  const bf16* QT = qkv + (size_t)nl*294912;
  const bf16* KT = qkv + kOff + (size_t)nl*294912;
  const bf16* Vp = qkv + vOff + (size_t)nl*294912;
  const int c0 = head*64;
  v8s aq0, aq1;
  {
    const bf16* qrow = QT + (size_t)(t0*64 + w*16 + r15)*512 + c0;
    aq0 = *(const v8s*)(qrow + quad*8);
    aq1 = *(const v8s*)(qrow + 32 + quad*8);
  }
  // ones B-fragment for row-sum MFMA
  v8s bones;
  {
    union { bf16 h[8]; v8s v; } ob;
    #pragma unroll
    for (int j = 0; j < 8; ++j) ob.h[j] = f2b(1.f);
    bones = ob.v;
  }
  // staging geometry (reg prefetch)
  int srow[4], scol[4];
  #pragma unroll
  for (int r = 0; r < 4; ++r){
    int e4 = (tid + 256*r)*4;
    srow[r] = e4 >> 6; scol[r] = e4 & 63;
  }
  ushort4 kreg[4], vreg[4];
  #pragma unroll
  for (int r = 0; r < 4; ++r){
    kreg[r] = *(const ushort4*)&KT[(size_t)srow[r]*512 + c0 + scol[r]];
    vreg[r] = *(const ushort4*)&Vp[(size_t)(c0 + srow[r])*576 + scol[r]];
  }
  v4f oc[4];
  v4f oc2 = (v4f){0.f,0.f,0.f,0.f};         // row-sum accumulator (l_run)
  #pragma unroll
  for (int ni = 0; ni < 4; ++ni) oc[ni] = (v4f){0.f,0.f,0.f,0.f};
  float m_run[4] = {-1e30f,-1e30f,-1e30f,-1e30f};
  const float SC = 0.180336880f;            // 0.125 * log2(e): exp2 domain
  for (int sc = 0; sc < 9; ++sc){
    __syncthreads();
    #pragma unroll
    for (int r = 0; r < 4; ++r){
      *(ushort4*)&Ks[srow[r]*72 + scol[r]] = kreg[r];
      *(ushort4*)&Vs[srow[r]*72 + scol[r]] = vreg[r];
    }
    __syncthreads();
    if (sc < 8){                            // prefetch next tile under compute
      #pragma unroll
      for (int r = 0; r < 4; ++r){
        kreg[r] = *(const ushort4*)&KT[(size_t)((sc+1)*64 + srow[r])*512 + c0 + scol[r]];
        vreg[r] = *(const ushort4*)&Vp[(size_t)(c0 + srow[r])*576 + (sc+1)*64 + scol[r]];
      }
    }
    v4f sa[4];
    #pragma unroll
    for (int sj = 0; sj < 4; ++sj) sa[sj] = (v4f){0.f,0.f,0.f,0.f};
    #pragma unroll
    for (int sj = 0; sj < 4; ++sj){
      v8s b0 = *(const v8s*)&Ks[(sj*16 + r15)*72 + quad*8];
      v8s b1 = *(const v8s*)&Ks[(sj*16 + r15)*72 + 32 + quad*8];
      sa[sj] = __builtin_amdgcn_mfma_f32_16x16x32_bf16(aq0, b0, sa[sj], 0, 0, 0);
      sa[sj] = __builtin_amdgcn_mfma_f32_16x16x32_bf16(aq1, b1, sa[sj], 0, 0, 0);
    }
    // per-lane partial max per row-group (over this lane's 4 cols)
    float cmx[4] = {-1e30f,-1e30f,-1e30f,-1e30f};
    #pragma unroll
    for (int sj = 0; sj < 4; ++sj)
      #pragma unroll
      for (int rg = 0; rg < 4; ++rg){
        float v = sa[sj][rg]*SC;
        sa[sj][rg] = v;
        cmx[rg] = fmaxf(cmx[rg], v);
      }
    // defer-max: if no lane's PARTIAL exceeds m+8, true rowmax <= m+8 -> P <= 2^8, skip reduce
    float grow = fmaxf(fmaxf(cmx[0]-m_run[0], cmx[1]-m_run[1]),
                       fmaxf(cmx[2]-m_run[2], cmx[3]-m_run[3]));
    if (__any(grow > 8.f)){
      #pragma unroll
      for (int off = 1; off < 16; off <<= 1)
        #pragma unroll
        for (int rg = 0; rg < 4; ++rg) cmx[rg] = fmaxf(cmx[rg], __shfl_xor(cmx[rg], off, 64));
      #pragma unroll
      for (int rg = 0; rg < 4; ++rg){
        float mnew = fmaxf(m_run[rg], cmx[rg]);
        float al = exp2f(m_run[rg] - mnew);
        m_run[rg] = mnew;
        oc2[rg] *= al;
        #pragma unroll
        for (int ni = 0; ni < 4; ++ni) oc[ni][rg] *= al;
      }
    }
    #pragma unroll
    for (int sj = 0; sj < 4; ++sj)
      #pragma unroll
      for (int rg = 0; rg < 4; ++rg)
        Ps[w][(quad*4 + rg)*72 + sj*16 + r15] = f2b(exp2f(sa[sj][rg] - m_run[rg]));
    #pragma unroll
    for (int ks = 0; ks < 2; ++ks){
      v8s a = *(const v8s*)&Ps[w][r15*72 + ks*32 + quad*8];
      #pragma unroll
      for (int ni = 0; ni < 4; ++ni){
        v8s b = *(const v8s*)&Vs[(ni*16 + r15)*72 + ks*32 + quad*8];
        oc[ni] = __builtin_amdgcn_mfma_f32_16x16x32_bf16(a, b, oc[ni], 0, 0, 0);
      }
      oc2 = __builtin_amdgcn_mfma_f32_16x16x32_bf16(a, bones, oc2, 0, 0, 0);  // row-sum
    }
  }
  float inv[4];
  #pragma unroll
  for (int rg = 0; rg < 4; ++rg) inv[rg] = 1.f / oc2[rg];
  #pragma unroll
  for (int ni = 0; ni < 4; ++ni)
    #pragma unroll
    for (int rg = 0; rg < 4; ++rg){
      int t = t0*64 + w*16 + quad*4 + rg;
      attT[(size_t)(nl*576 + t)*512 + c0 + ni*16 + r15] = f2b(oc[ni][rg]*inv[rg]);
    }
}

// ---------------------------------------------------------------- K4: spatial proj + residual (MFMA)
// R1: LDS-transpose epilogue with coalesced 16B stores (x2 and x2T).
__global__ __launch_bounds__(256) void k_proj_s_mfma(const bf16* __restrict__ AT,
        const bf16* __restrict__ Wb, const void* __restrict__ Bv,
        const void* __restrict__ xin, bf16* __restrict__ x2,
        bf16* __restrict__ x2T, int doT,
        const int* __restrict__ flag, int n0){
  const bool f32in = flag[0] != 0;
  const int o0 = blockIdx.x * 128;
  const int l0 = blockIdx.y * 64;
  const int nl = blockIdx.z;
  const int n = n0 + nl;
  const int b = n >> 4, t = n & 15;
  const int tid = threadIdx.x, lane = tid & 63;
  const int wm = (tid >> 6) & 1, wn = tid >> 7;
  const int r15 = lane & 15, quad = lane >> 4;
  __shared__ bf16 As[128*72];
  __shared__ bf16 Bs[64*72];
  v4f acc[4][2];
  #pragma unroll
  for (int i = 0; i < 4; ++i)
    #pragma unroll
    for (int j = 0; j < 2; ++j) acc[i][j] = (v4f){0.f,0.f,0.f,0.f};
  for (int kc = 0; kc < 512; kc += 64){
    __syncthreads();
    #pragma unroll
    for (int r = 0; r < 8; ++r){
      int e4 = (tid + 256*r)*4;
      int row = e4 >> 6, k = e4 & 63;
      stage4b(&Wb[(size_t)(o0+row)*512 + kc + k], &As[row*72 + k]);
    }
    #pragma unroll
    for (int r = 0; r < 4; ++r){
      int e4 = (tid + 256*r)*4;
      int row = e4 >> 6, k = e4 & 63;
      stage4b(&AT[(size_t)(nl*576 + l0 + row)*512 + kc + k], &Bs[row*72 + k]);
    }
    __syncthreads();
    #pragma unroll
    for (int ks = 0; ks < 2; ++ks){
      v8s a[4], b[2];
      #pragma unroll
      for (int mi = 0; mi < 4; ++mi)
        a[mi] = *(const v8s*)&As[(wm*64 + mi*16 + r15)*72 + ks*32 + quad*8];
      #pragma unroll
      for (int ni = 0; ni < 2; ++ni)
        b[ni] = *(const v8s*)&Bs[(wn*32 + ni*16 + r15)*72 + ks*32 + quad*8];
      #pragma unroll
      for (int mi = 0; mi < 4; ++mi)
        #pragma unroll
        for (int ni = 0; ni < 2; ++ni)
          acc[mi][ni] = __builtin_amdgcn_mfma_f32_16x16x32_bf16(a[mi], b[ni], acc[mi][ni], 0, 0, 0);
    }
  }
  // -------- epilogue: stage acc+bias into As as [o_rel][l_rel] (stride 72)
  __syncthreads();
  #pragma unroll
  for (int mi = 0; mi < 4; ++mi){
    int orel = wm*64 + mi*16 + quad*4;
    #pragma unroll
    for (int rg = 0; rg < 4; ++rg){
      float bia = ldin(Bv, o0 + orel + rg, f32in);
      #pragma unroll
      for (int ni = 0; ni < 2; ++ni)
        As[(orel + rg)*72 + wn*32 + ni*16 + r15] = f2b(acc[mi][ni][rg] + bia);
    }
  }
  __syncthreads();
  // phase 1: residual add + coalesced x2 write (+writeback for phase 2)
  const size_t xrow = ((size_t)(b*512 + o0)*16 + t)*576 + l0;
  for (int it = 0; it < 4; ++it){
    int idx = tid + it*256;             // 1024 chunks of 8 elems
    int o = idx >> 3, lc = (idx & 7)*8;
    union { bf16 h[8]; v8s v; } val;
    val.v = *(const v8s*)&As[o*72 + lc];
    size_t ga = xrow + (size_t)o*9216 + lc;
    if (f32in){
      const float* xp = (const float*)xin + ga;
      float4 f0 = *(const float4*)xp;
      float4 f1 = *(const float4*)(xp + 4);
      val.h[0] = f2b(b2f(val.h[0]) + f0.x);
      val.h[1] = f2b(b2f(val.h[1]) + f0.y);
      val.h[2] = f2b(b2f(val.h[2]) + f0.z);
      val.h[3] = f2b(b2f(val.h[3]) + f0.w);
      val.h[4] = f2b(b2f(val.h[4]) + f1.x);
      val.h[5] = f2b(b2f(val.h[5]) + f1.y);
      val.h[6] = f2b(b2f(val.h[6]) + f1.z);
      val.h[7] = f2b(b2f(val.h[7]) + f1.w);
    } else {
      union { bf16 h[8]; v8s v; } xv;
      xv.v = *(const v8s*)((const bf16*)xin + ga);
      #pragma unroll
      for (int j = 0; j < 8; ++j) val.h[j] = f2b(b2f(val.h[j]) + b2f(xv.h[j]));
    }
    *(v8s*)&x2[ga] = val.v;
    if (doT) *(v8s*)&As[o*72 + lc] = val.v;
  }
  if (doT){
    __syncthreads();
    // phase 2: x2T [m][t][c]: per chunk, 8 consecutive o at fixed l
    const size_t tbase = ((size_t)b*576 + l0)*8192 + (size_t)t*512 + o0;
    for (int it = 0; it < 4; ++it){
      int l = (tid & 15) + it*16;
      int ocg = (tid >> 4)*8;
      union { bf16 h[8]; v8s v; } val;
      #pragma unroll
      for (int j = 0; j < 8; ++j) val.h[j] = As[(ocg + j)*72 + l];
      *(v8s*)&x2T[tbase + (size_t)l*8192 + ocg] = val.v;
    }
  }
}

// ---------------------------------------------------------------- K5a: temporal groupnorm (scattered x2) -> xnT [m][t][c]
__global__ __launch_bounds__(256) void k_gn_t(const bf16* __restrict__ x2,
        const void* __restrict__ gw, const void* __restrict__ gb,
        bf16* __restrict__ xnT, const int* __restrict__ flag, int m0){
  const bool f32in = flag[0] != 0;
  const int ml = blockIdx.x;
  const int m = m0 + ml;
  const int b = m / 576, l = m - b*576;
  const int tid = threadIdx.x;
  __shared__ float xs[8192];
  __shared__ float mg[32], rg[32];
  for (int i = tid; i < 8192; i += 256){
    int t = i >> 9, c = i & 511;
    xs[i] = b2f(x2[((b*512 + c)*16 + t)*576 + l]);
  }
  __syncthreads();
  {
    int g = tid >> 3, ii = tid & 7;
    float s = 0.f, q = 0.f;
    for (int idx = ii; idx < 256; idx += 8){
      int t = idx >> 4, cg = idx & 15;
      float v = xs[t*512 + g*16 + cg]; s += v; q += v*v;
    }
    #pragma unroll
    for (int off = 1; off < 8; off <<= 1){ s += __shfl_xor(s, off, 64); q += __shfl_xor(q, off, 64); }
    if (ii == 0){
      float mean = s*(1.f/256.f);
      float var  = q*(1.f/256.f) - mean*mean;
      mg[g] = mean; rg[g] = rsqrtf(fmaxf(var, 0.f) + 1e-5f);
    }
  }
  __syncthreads();
  for (int i = tid; i < 8192; i += 256){
    int c = i & 511, g = c >> 4;
    xnT[(size_t)ml*8192 + i] = f2b((xs[i] - mg[g])*rg[g]*ldin(gw, c, f32in) + ldin(gb, c, f32in));
  }
}

// ---------------------------------------------------------------- K5b: temporal groupnorm (coalesced x2T)
__global__ __launch_bounds__(256) void k_gn_t2(const bf16* __restrict__ x2T,
        const void* __restrict__ gw, const void* __restrict__ gb,
        bf16* __restrict__ xnT, const int* __restrict__ flag, int m0){
  const bool f32in = flag[0] != 0;
  const int ml = blockIdx.x;
  const int m = m0 + ml;
  const int tid = threadIdx.x;
  __shared__ float xs[8192];
  __shared__ float mg[32], rg[32];
  for (int i = tid; i < 8192; i += 256)
    xs[i] = b2f(x2T[(size_t)m*8192 + i]);     // [t][c] order, fully coalesced
  __syncthreads();
  {
    int g = tid >> 3, ii = tid & 7;
    float s = 0.f, q = 0.f;
    for (int idx = ii; idx < 256; idx += 8){
      int t = idx >> 4, cg = idx & 15;
      float v = xs[t*512 + g*16 + cg]; s += v; q += v*v;
    }
    #pragma unroll
    for (int off = 1; off < 8; off <<= 1){ s += __shfl_xor(s, off, 64); q += __shfl_xor(q, off, 64); }
    if (ii == 0){
      float mean = s*(1.f/256.f);
      float var  = q*(1.f/256.f) - mean*mean;
      mg[g] = mean; rg[g] = rsqrtf(fmaxf(var, 0.f) + 1e-5f);
    }
  }
  __syncthreads();
  for (int i = tid; i < 8192; i += 256){
    int c = i & 511, g = c >> 4;
    xnT[(size_t)ml*8192 + i] = f2b((xs[i] - mg[g])*rg[g]*ldin(gw, c, f32in) + ldin(gb, c, f32in));
  }
}

// ---------------------------------------------------------------- K7: temporal attention -> attT [m][t][c]
__global__ __launch_bounds__(256) void k_attn_t(const bf16* __restrict__ qkv,
        const void* __restrict__ tbk, const void* __restrict__ tbv,
        bf16* __restrict__ attT, const int* __restrict__ flag){
  const bool f32in = flag[0] != 0;
  const int head = blockIdx.x;
  const int ml = blockIdx.y;
  const int tid = threadIdx.x;
  __shared__ float qsT[16*68], ksT[16*68], vsT[16*68];  // [t][c], stride 68 (16B-aligned rows)
  __shared__ float tks[33*68], tvs[33*68];              // [d][c]
  __shared__ float ps[16*17];
  const int base = (ml*1536 + head*64)*16;
  for (int i = tid; i < 1024; i += 256){
    int c = i >> 4, t = i & 15;
    qsT[t*68 + c] = b2f(qkv[base + i]);
    ksT[t*68 + c] = b2f(qkv[base + 8192 + i]);
    vsT[t*68 + c] = b2f(qkv[base + 16384 + i]);
  }
  for (int i = tid; i < 33*64; i += 256){
    int d = i >> 6, c = i & 63;
    tks[d*68 + c] = ldin(tbk, i, f32in);
    tvs[d*68 + c] = ldin(tbv, i, f32in);
  }
  __syncthreads();
  {
    const int t = tid >> 4, s = tid & 15;
    const float4* qt = (const float4*)&qsT[t*68];
    const float4* kr = (const float4*)&ksT[s*68];
    const float4* q2 = (const float4*)&qsT[s*68];
    const float4* tr = (const float4*)&tks[(t - s + 16)*68];
    float qk = 0.f, rp = 0.f;
    #pragma unroll
    for (int c4 = 0; c4 < 16; ++c4){
      float4 a = qt[c4], b = kr[c4];
      qk += a.x*b.x + a.y*b.y + a.z*b.z + a.w*b.w;
      float4 a2 = q2[c4], tb = tr[c4];
      rp += a2.x*tb.x + a2.y*tb.y + a2.z*tb.z + a2.w*tb.w;
    }
    float logit = 0.125f*qk + 0.35355339059327373f*rp;
    if (s > t) logit = -1e8f;
    float mx = logit;
    #pragma unroll
    for (int off = 8; off; off >>= 1) mx = fmaxf(mx, __shfl_xor(mx, off, 16));
    float e = __expf(logit - mx);
    float tot = e;
    #pragma unroll
    for (int off = 8; off; off >>= 1) tot += __shfl_xor(tot, off, 16);
    ps[t*17 + s] = e / tot;
  }
  __syncthreads();
  {
    const int c4 = tid & 15, t = tid >> 4;
    float4 acc = {0.f,0.f,0.f,0.f};
    #pragma unroll
    for (int s = 0; s < 16; ++s){
      float p = ps[t*17 + s];
      float4 v4 = *(const float4*)&vsT[s*68 + c4*4];
      float4 t4 = *(const float4*)&tvs[(s - t + 16)*68 + c4*4];
      acc.x += p*(v4.x + t4.x); acc.y += p*(v4.y + t4.y);
      acc.z += p*(v4.z + t4.z); acc.w += p*(v4.w + t4.w);
    }
    union { bf16 h[4]; ushort4 u; } o;
    o.h[0] = f2b(acc.x); o.h[1] = f2b(acc.y); o.h[2] = f2b(acc.z); o.h[3] = f2b(acc.w);
    *(ushort4*)&attT[(size_t)ml*8192 + t*512 + head*64 + c4*4] = o.u;
  }
}

// ---------------------------------------------------------------- K8: temporal proj + residual -> out (MFMA, coalesced)
__global__ __launch_bounds__(256) void k_proj_t_mfma(const bf16* __restrict__ AT,
        const bf16* __restrict__ Wb, const void* __restrict__ Bv,
        const bf16* __restrict__ x2, void* __restrict__ out,
        const int* __restrict__ flag, int m0){
  const bool f32in = flag[0] != 0;
  const int o0 = blockIdx.x * 128;
  const int tp = blockIdx.y;            // t-pair
  const int mg0 = blockIdx.z * 32;      // m base (32 | 576)
  const int tid = threadIdx.x, lane = tid & 63;
  const int wm = (tid >> 6) & 1, wn = tid >> 7;
  const int r15 = lane & 15, quad = lane >> 4;
  __shared__ bf16 As[128*72];
  __shared__ bf16 Bs[64*72];
  v4f acc[4][2];
  #pragma unroll
  for (int i = 0; i < 4; ++i)
    #pragma unroll
    for (int j = 0; j < 2; ++j) acc[i][j] = (v4f){0.f,0.f,0.f,0.f};
  for (int kc = 0; kc < 512; kc += 64){
    __syncthreads();
    #pragma unroll
    for (int r = 0; r < 8; ++r){
      int e4 = (tid + 256*r)*4;
      int row = e4 >> 6, k = e4 & 63;
      stage4b(&Wb[(size_t)(o0+row)*512 + kc + k], &As[row*72 + k]);
    }
    #pragma unroll
    for (int r = 0; r < 4; ++r){
      int e4 = (tid + 256*r)*4;
      int row = e4 >> 6, k = e4 & 63;
      stage4b(&AT[(size_t)(mg0 + (row & 31))*8192 + (tp*2 + (row >> 5))*512 + kc + k],
              &Bs[row*72 + k]);
    }
    __syncthreads();
    #pragma unroll
    for (int ks = 0; ks < 2; ++ks){
      v8s a[4], b[2];
      #pragma unroll
      for (int mi = 0; mi < 4; ++mi)
        a[mi] = *(const v8s*)&As[(wm*64 + mi*16 + r15)*72 + ks*32 + quad*8];
      #pragma unroll
      for (int ni = 0; ni < 2; ++ni)
        b[ni] = *(const v8s*)&Bs[(wn*32 + ni*16 + r15)*72 + ks*32 + quad*8];
      #pragma unroll
      for (int mi = 0; mi < 4; ++mi)
        #pragma unroll
        for (int ni = 0; ni < 2; ++ni)
          acc[mi][ni] = __builtin_amdgcn_mfma_f32_16x16x32_bf16(a[mi], b[ni], acc[mi][ni], 0, 0, 0);
    }
  }
  const int tt = tp*2 + wn;
  #pragma unroll
  for (int mi = 0; mi < 4; ++mi)
    #pragma unroll
    for (int rg = 0; rg < 4; ++rg){
      int o = o0 + wm*64 + mi*16 + quad*4 + rg;
      float bia = ldin(Bv, o, f32in);
      #pragma unroll
      for (int ni = 0; ni < 2; ++ni){
        int m = m0 + mg0 + ni*16 + r15;
        int b = m / 576, l = m - b*576;
        size_t addr = ((size_t)(b*512 + o)*16 + tt)*576 + l;
        float val = acc[mi][ni][rg] + bia + b2f(x2[addr]);
        if (f32in) ((float*)out)[addr] = val;
        else       ((bf16*)out)[addr] = f2b(val);
      }
    }
}

// ----------------------------------------------------------------
extern "C" void kernel_launch(void* const* d_in, const int* in_sizes, int n_in,
                              void* d_out, int out_size, void* d_ws, size_t ws_size,
                              hipStream_t stream){
  const void* x   = d_in[0];
  const void* nsw = d_in[1];
  const void* nsb = d_in[2];
  const void* qsw = d_in[3];
  const void* qsb = d_in[4];
  const void* psw = d_in[5];
  const void* psb = d_in[6];
  const void* ntw = d_in[7];
  const void* ntb = d_in[8];
  const void* qtw = d_in[9];
  const void* qtb = d_in[10];
  const void* ptw = d_in[11];
  const void* ptb = d_in[12];
  const void* rpk = d_in[13];
  const void* rpv = d_in[14];

  // Chunking and x2T gate from ws_size (constant across calls -> graph-safe).
  const size_t S_full = (size_t)32*294912;
  const size_t need_full = 256 + (S_full*5 + 9437184)*2;
  const size_t need_T    = 256 + (S_full*5 + (size_t)2*9437184)*2;  // +18.9 MB for x2T
  const int NCH = (ws_size >= need_full) ? 32 : 8;
  const int MCH = (NCH == 32) ? 1152 : 288;
  const size_t S = (size_t)NCH*294912;
  const int useT = (NCH == 32 && ws_size >= need_T) ? 1 : 0;

  int*  flag = (int*)d_ws;
  bf16* A  = (bf16*)((char*)d_ws + 256);   // S: xnT_s / xnT_t
  bf16* A2 = A  + S;                        // S: attT_s / attT_t (+ transient W copy)
  bf16* Bq = A2 + S;                        // 3S: qkv (+ transient W copies)
  bf16* Cx = Bq + 3*S;                      // 9,437,184: x2 residual
  bf16* Cx2 = Cx + 9437184;                 // 9,437,184: x2T [m][t][c] (if useT)
  const size_t kOff = S, vOff = 2*S;
  bf16* Wcv  = A2;
  bf16* Wcv2 = Bq;

  k_detect<<<1, 64, 0, stream>>>(x, flag);

  for (int n0 = 0; n0 < 32; n0 += NCH){
    k_gn_s       <<<dim3(32, NCH),   256, 0, stream>>>(x, nsw, nsb, A, flag, n0);
    k_cvtw       <<<dim3(768),       256, 0, stream>>>(qsw, Wcv, 196608, flag);
    k_gemm_qkv   <<<dim3(NCH*54),    256, 0, stream>>>(A, Wcv, qsb, Bq, flag, kOff, vOff, 0);
    k_attn_s_mfma<<<dim3(72*NCH),    256, 0, stream>>>(Bq, A2, kOff, vOff);
    // proj_s weight pre-convert into Bq (qkv dead after attn_s)
    k_cvtw       <<<dim3(256),       256, 0, stream>>>(psw, Bq, 65536, flag);
    k_proj_s_mfma<<<dim3(4, 9, NCH), 256, 0, stream>>>(A2, Bq, psb, x, Cx, Cx2, useT, flag, n0);
  }
  for (int m0 = 0; m0 < 1152; m0 += MCH){
    if (useT) k_gn_t2<<<dim3(MCH),   256, 0, stream>>>(Cx2, ntw, ntb, A, flag, m0);
    else      k_gn_t <<<dim3(MCH),   256, 0, stream>>>(Cx,  ntw, ntb, A, flag, m0);
    k_cvtw       <<<dim3(768),       256, 0, stream>>>(qtw, Wcv, 196608, flag);
    k_gemm_qkv   <<<dim3((MCH/2)*3), 256, 0, stream>>>(A, Wcv, qtb, Bq, flag, 0, 0, 1);
    k_attn_t     <<<dim3(8, MCH),    256, 0, stream>>>(Bq, rpk, rpv, A2, flag);
    k_cvtw       <<<dim3(256),       256, 0, stream>>>(ptw, Wcv2, 65536, flag);
    k_proj_t_mfma<<<dim3(4, 8, MCH/32), 256, 0, stream>>>(A2, Wcv2, ptb, Cx, d_out, flag, m0);
  }
}

// Round 9
// 469.082 us; speedup vs baseline: 1.0916x; 1.0507x over previous
//
#include <hip/hip_runtime.h>
#include <hip/hip_bf16.h>

typedef __hip_bfloat16 bf16;
typedef __attribute__((ext_vector_type(8))) short v8s;
typedef __attribute__((ext_vector_type(4))) float v4f;

__device__ __forceinline__ float b2f(bf16 v){ return __bfloat162float(v); }
__device__ __forceinline__ bf16  f2b(float v){ return __float2bfloat16(v); }

// Inputs may be bf16 OR f32 — runtime-detected flag (1 => f32). Output dtype follows.
__device__ __forceinline__ float ldin(const void* p, int i, bool f32in){
  return f32in ? ((const float*)p)[i] : b2f(((const bf16*)p)[i]);
}

// stage 4 consecutive source elems (f32-or-bf16) into dst as bf16 (8B write)
__device__ __forceinline__ void stage4(const void* src, size_t off, bool f32in, bf16* dst){
  union { bf16 h[4]; ushort4 u; } tmp;
  if (f32in){
    float4 f = *(const float4*)((const float*)src + off);
    tmp.h[0] = f2b(f.x); tmp.h[1] = f2b(f.y); tmp.h[2] = f2b(f.z); tmp.h[3] = f2b(f.w);
  } else {
    tmp.u = *(const ushort4*)((const ushort*)src + off);
  }
  *(ushort4*)dst = tmp.u;
}
__device__ __forceinline__ void stage4b(const bf16* src, bf16* dst){
  *(ushort4*)dst = *(const ushort4*)src;
}

// async global->LDS, 16B per lane. LDS dest must be wave-uniform base (HW adds lane*16).
__device__ __forceinline__ void async_cp16(const bf16* g, bf16* l){
  __builtin_amdgcn_global_load_lds(
      (const __attribute__((address_space(1))) unsigned int*)g,
      (__attribute__((address_space(3))) unsigned int*)l, 16, 0, 0);
}

// Problem: B=2, C=512, T=16, H=W=24, heads=8, ch=64
// ws: flag | A (S) | A2 (S) | Bq (3S) | Cx 9,437,184 | [Cx2 9,437,184 if room]
// R1: proj_s epilogue request-bound -> LDS-transpose epilogue (WIN, -58us).
// R2: qkv GEMMs -> unified 128x128 global_load_lds GEMM.
// R3: XOR-swizzle via pre-swizzled global source + swizzled ds_read (conflict fix).
// R4: attn_s reg-prefetch + exp2 + defer-max + setprio: FAILED (+3.5us) — cost was
//     softmax cross-lane ops; setprio negative on lockstep blocks (m190).
// R6: attn_s conditional max-reduce + ones-MFMA row-sum: WIN (85 -> <77us, total -19).
// R8: attn_t was top (77.6us, MfmaUtil 0, VALU 44%, HBM 7.6%): ~28 scalar global
//     loads/thread (2B qkv + branchy table ldin, 17KB table re-staged by all 9216
//     blocks). Vectorize staging to 16B chunks (qkv v8s, tables float4/v8s).

// ---------------------------------------------------------------- detect input dtype
__global__ void k_detect(const void* x, int* flag){
  int tid = threadIdx.x;
  const bf16* p = (const bf16*)x;
  int cnt = 0;
  for (int i = tid; i < 512; i += 64){
    float v = b2f(p[i]);
    if (!(fabsf(v) <= 64.f)) cnt++;
  }
  #pragma unroll
  for (int off = 32; off; off >>= 1) cnt += __shfl_down(cnt, off, 64);
  if (tid == 0) flag[0] = (cnt > 16) ? 1 : 0;
}

// ---------------------------------------------------------------- weight convert -> bf16 scratch
__global__ __launch_bounds__(256) void k_cvtw(const void* __restrict__ W,
        bf16* __restrict__ out, int n4, const int* __restrict__ flag){
  const bool f32in = flag[0] != 0;
  int i = blockIdx.x*256 + threadIdx.x;
  if (i < n4) stage4(W, (size_t)i*4, f32in, out + (size_t)i*4);
}

// ---------------------------------------------------------------- K1: spatial groupnorm -> xnT [l][c]
__global__ __launch_bounds__(256) void k_gn_s(const void* __restrict__ x,
        const void* __restrict__ gw, const void* __restrict__ gb,
        bf16* __restrict__ xnT, const int* __restrict__ flag, int n0){
  const bool f32in = flag[0] != 0;
  const int g = blockIdx.x;
  const int nl = blockIdx.y;
  const int n = n0 + nl;
  const int b = n >> 4, t = n & 15;
  const int tid = threadIdx.x;
  __shared__ float xs[576*17];     // [l][cg] padded
  __shared__ float red[4][2];
  __shared__ float stats[2];
  float s = 0.f, q = 0.f;
  for (int i = tid; i < 9216; i += 256){
    int cg = i / 576, l = i - cg*576;
    int c = g*16 + cg;
    float v = ldin(x, ((b*512 + c)*16 + t)*576 + l, f32in);
    xs[l*17 + cg] = v; s += v; q += v*v;
  }
  #pragma unroll
  for (int off = 32; off; off >>= 1){ s += __shfl_down(s, off, 64); q += __shfl_down(q, off, 64); }
  int wid = tid >> 6;
  if ((tid & 63) == 0){ red[wid][0] = s; red[wid][1] = q; }
  __syncthreads();
  if (tid == 0){
    float S = red[0][0]+red[1][0]+red[2][0]+red[3][0];
    float Q = red[0][1]+red[1][1]+red[2][1]+red[3][1];
    float mean = S * (1.f/9216.f);
    float var  = Q * (1.f/9216.f) - mean*mean;
    stats[0] = mean; stats[1] = rsqrtf(fmaxf(var, 0.f) + 1e-5f);
  }
  __syncthreads();
  float mean = stats[0], rstd = stats[1];
  for (int i = tid; i < 9216; i += 256){
    int l = i >> 4, cg = i & 15;
    int c = g*16 + cg;
    xnT[(size_t)(nl*576 + l)*512 + c] =
        f2b((xs[l*17 + cg] - mean)*rstd*ldin(gw, c, f32in) + ldin(gb, c, f32in));
  }
}

// ---------------------------------------------------------------- K2/K6: unified qkv GEMM
// Xf: flat [R][512] bf16. Wb: [1536][512] bf16. 128x128 tile, BK=64,
// global_load_lds staging into linear LDS; slot^=(row&7) XOR swizzle applied
// via pre-swizzled global source + swizzled ds_read (T2 / rule #21).
// mode 0: spatial epilogue (Q/K [l][512] + V [c][576] per nl); mode 1: temporal [m][o][t].
__global__ __launch_bounds__(256) void k_gemm_qkv(const bf16* __restrict__ Xf,
        const bf16* __restrict__ Wb, const void* __restrict__ Bv,
        bf16* __restrict__ Y, const int* __restrict__ flag,
        size_t kOff, size_t vOff, int mode){
  const bool f32in = flag[0] != 0;
  const int nwg = gridDim.x;
  const int bid = blockIdx.x;
  const int g = (bid & 7)*(nwg >> 3) + (bid >> 3);   // chunked XCD swizzle (nwg%8==0)
  const int mt = g / 12, nt = g - mt*12;
  const int r0 = mt*128, o0 = nt*128;
  const int tid = threadIdx.x, lane = tid & 63, w = tid >> 6;
  const int wm = w & 1, wn = w >> 1;
  const int r15 = lane & 15, quad = lane >> 4;
  const int rsw = r15 & 7;                 // read-side swizzle key (row&7 == r15&7)
  __shared__ bf16 As[128*64];
  __shared__ bf16 Bs[128*64];
  v4f acc[4][4];
  #pragma unroll
  for (int i = 0; i < 4; ++i)
    #pragma unroll
    for (int j = 0; j < 4; ++j) acc[i][j] = (v4f){0.f,0.f,0.f,0.f};
  for (int kc = 0; kc < 512; kc += 64){
    __syncthreads();
    #pragma unroll
    for (int r = 0; r < 4; ++r){
      int d = (tid + 256*r)*8;             // linear LDS elem offset this lane fills
      int row = d >> 6;
      int slot = (d >> 3) & 7;             // 16B slot within the 128B row
      int col = ((slot ^ (row & 7)) * 8);  // inverse-swizzled source column
      async_cp16(&Xf[(size_t)(r0 + row)*512 + kc + col], As + r*2048 + w*512);
      async_cp16(&Wb[(size_t)(o0 + row)*512 + kc + col], Bs + r*2048 + w*512);
    }
    __syncthreads();                        // compiler drains vmcnt(0) before barrier
    #pragma unroll
    for (int ks = 0; ks < 2; ++ks){
      v8s a[4], b[4];
      #pragma unroll
      for (int mi = 0; mi < 4; ++mi)
        a[mi] = *(const v8s*)&As[(wm*64 + mi*16 + r15)*64 + (((ks*4 + quad) ^ rsw)*8)];
      #pragma unroll
      for (int ni = 0; ni < 4; ++ni)
        b[ni] = *(const v8s*)&Bs[(wn*64 + ni*16 + r15)*64 + (((ks*4 + quad) ^ rsw)*8)];
      #pragma unroll
      for (int mi = 0; mi < 4; ++mi)
        #pragma unroll
        for (int ni = 0; ni < 4; ++ni)
          acc[mi][ni] = __builtin_amdgcn_mfma_f32_16x16x32_bf16(a[mi], b[ni], acc[mi][ni], 0, 0, 0);
    }
  }
  if (mode == 0){
    #pragma unroll
    for (int ni = 0; ni < 4; ++ni){
      int o = o0 + wn*64 + ni*16 + r15;
      int seg = o >> 9, oseg = o & 511;
      size_t segb = (seg==0) ? 0 : (seg==1) ? kOff : vOff;
      float bia = ldin(Bv, o, f32in);
      #pragma unroll
      for (int mi = 0; mi < 4; ++mi)
        #pragma unroll
        for (int rg = 0; rg < 4; ++rg){
          int rr = r0 + wm*64 + mi*16 + quad*4 + rg;
          int nl = rr / 576, l = rr - nl*576;
          size_t dst = segb + (size_t)nl*294912 +
                       ((seg==2) ? ((size_t)oseg*576 + l) : ((size_t)l*512 + oseg));
          Y[dst] = f2b(acc[mi][ni][rg] + bia);
        }
    }
  } else {
    #pragma unroll
    for (int ni = 0; ni < 4; ++ni){
      int o = o0 + wn*64 + ni*16 + r15;
      float bia = ldin(Bv, o, f32in);
      #pragma unroll
      for (int mi = 0; mi < 4; ++mi)
        #pragma unroll
        for (int rg = 0; rg < 4; ++rg){
          int rr = r0 + wm*64 + mi*16 + quad*4 + rg;
          int m = rr >> 4, t = rr & 15;
          Y[((size_t)m*1536 + o)*16 + t] = f2b(acc[mi][ni][rg] + bia);
        }
    }
  }
}

// ---------------------------------------------------------------- K3: spatial attention (flash MFMA) -> attT [l][c]
// R6: conditional max-reduce + ones-MFMA row-sum (no psum shfl); no setprio.
__global__ __launch_bounds__(256, 4) void k_attn_s_mfma(const bf16* __restrict__ qkv,
        bf16* __restrict__ attT, size_t kOff, size_t vOff){
  const int bid = blockIdx.x;
  const int xcd = bid & 7, slot = bid >> 3;
  const int nl = xcd + 8*(slot/72);
  const int idx = slot - 72*(slot/72);
  const int head = idx/9, t0 = idx - 9*head;
  const int tid = threadIdx.x, lane = tid & 63, w = tid >> 6;
  const int r15 = lane & 15, quad = lane >> 4;
  __shared__ bf16 Ks[64*72];
  __shared__ bf16 Vs[64*72];
  __shared__ bf16 Ps[4][16*72];
  const bf16* QT = qkv + (size_t)nl*294912;
  const bf16* KT = qkv + kOff + (size_t)nl*294912;
  const bf16* Vp = qkv + vOff + (size_t)nl*294912;
  const int c0 = head*64;
  v8s aq0, aq1;
  {
    const bf16* qrow = QT + (size_t)(t0*64 + w*16 + r15)*512 + c0;
    aq0 = *(const v8s*)(qrow + quad*8);
    aq1 = *(const v8s*)(qrow + 32 + quad*8);
  }
  // ones B-fragment for row-sum MFMA
  v8s bones;
  {
    union { bf16 h[8]; v8s v; } ob;
    #pragma unroll
    for (int j = 0; j < 8; ++j) ob.h[j] = f2b(1.f);
    bones = ob.v;
  }
  // staging geometry (reg prefetch)
  int srow[4], scol[4];
  #pragma unroll
  for (int r = 0; r < 4; ++r){
    int e4 = (tid + 256*r)*4;
    srow[r] = e4 >> 6; scol[r] = e4 & 63;
  }
  ushort4 kreg[4], vreg[4];
  #pragma unroll
  for (int r = 0; r < 4; ++r){
    kreg[r] = *(const ushort4*)&KT[(size_t)srow[r]*512 + c0 + scol[r]];
    vreg[r] = *(const ushort4*)&Vp[(size_t)(c0 + srow[r])*576 + scol[r]];
  }
  v4f oc[4];
  v4f oc2 = (v4f){0.f,0.f,0.f,0.f};         // row-sum accumulator (l_run)
  #pragma unroll
  for (int ni = 0; ni < 4; ++ni) oc[ni] = (v4f){0.f,0.f,0.f,0.f};
  float m_run[4] = {-1e30f,-1e30f,-1e30f,-1e30f};
  const float SC = 0.180336880f;            // 0.125 * log2(e): exp2 domain
  for (int sc = 0; sc < 9; ++sc){
    __syncthreads();
    #pragma unroll
    for (int r = 0; r < 4; ++r){
      *(ushort4*)&Ks[srow[r]*72 + scol[r]] = kreg[r];
      *(ushort4*)&Vs[srow[r]*72 + scol[r]] = vreg[r];
    }
    __syncthreads();
    if (sc < 8){                            // prefetch next tile under compute
      #pragma unroll
      for (int r = 0; r < 4; ++r){
        kreg[r] = *(const ushort4*)&KT[(size_t)((sc+1)*64 + srow[r])*512 + c0 + scol[r]];
        vreg[r] = *(const ushort4*)&Vp[(size_t)(c0 + srow[r])*576 + (sc+1)*64 + scol[r]];
      }
    }
    v4f sa[4];
    #pragma unroll
    for (int sj = 0; sj < 4; ++sj) sa[sj] = (v4f){0.f,0.f,0.f,0.f};
    #pragma unroll
    for (int sj = 0; sj < 4; ++sj){
      v8s b0 = *(const v8s*)&Ks[(sj*16 + r15)*72 + quad*8];
      v8s b1 = *(const v8s*)&Ks[(sj*16 + r15)*72 + 32 + quad*8];
      sa[sj] = __builtin_amdgcn_mfma_f32_16x16x32_bf16(aq0, b0, sa[sj], 0, 0, 0);
      sa[sj] = __builtin_amdgcn_mfma_f32_16x16x32_bf16(aq1, b1, sa[sj], 0, 0, 0);
    }
    // per-lane partial max per row-group (over this lane's 4 cols)
    float cmx[4] = {-1e30f,-1e30f,-1e30f,-1e30f};
    #pragma unroll
    for (int sj = 0; sj < 4; ++sj)
      #pragma unroll
      for (int rg = 0; rg < 4; ++rg){
        float v = sa[sj][rg]*SC;
        sa[sj][rg] = v;
        cmx[rg] = fmaxf(cmx[rg], v);
      }
    // defer-max: if no lane's PARTIAL exceeds m+8, true rowmax <= m+8 -> P <= 2^8, skip reduce
    float grow = fmaxf(fmaxf(cmx[0]-m_run[0], cmx[1]-m_run[1]),
                       fmaxf(cmx[2]-m_run[2], cmx[3]-m_run[3]));
    if (__any(grow > 8.f)){
      #pragma unroll
      for (int off = 1; off < 16; off <<= 1)
        #pragma unroll
        for (int rg = 0; rg < 4; ++rg) cmx[rg] = fmaxf(cmx[rg], __shfl_xor(cmx[rg], off, 64));
      #pragma unroll
      for (int rg = 0; rg < 4; ++rg){
        float mnew = fmaxf(m_run[rg], cmx[rg]);
        float al = exp2f(m_run[rg] - mnew);
        m_run[rg] = mnew;
        oc2[rg] *= al;
        #pragma unroll
        for (int ni = 0; ni < 4; ++ni) oc[ni][rg] *= al;
      }
    }
    #pragma unroll
    for (int sj = 0; sj < 4; ++sj)
      #pragma unroll
      for (int rg = 0; rg < 4; ++rg)
        Ps[w][(quad*4 + rg)*72 + sj*16 + r15] = f2b(exp2f(sa[sj][rg] - m_run[rg]));
    #pragma unroll
    for (int ks = 0; ks < 2; ++ks){
      v8s a = *(const v8s*)&Ps[w][r15*72 + ks*32 + quad*8];
      #pragma unroll
      for (int ni = 0; ni < 4; ++ni){
        v8s b = *(const v8s*)&Vs[(ni*16 + r15)*72 + ks*32 + quad*8];
        oc[ni] = __builtin_amdgcn_mfma_f32_16x16x32_bf16(a, b, oc[ni], 0, 0, 0);
      }
      oc2 = __builtin_amdgcn_mfma_f32_16x16x32_bf16(a, bones, oc2, 0, 0, 0);  // row-sum
    }
  }
  float inv[4];
  #pragma unroll
  for (int rg = 0; rg < 4; ++rg) inv[rg] = 1.f / oc2[rg];
  #pragma unroll
  for (int ni = 0; ni < 4; ++ni)
    #pragma unroll
    for (int rg = 0; rg < 4; ++rg){
      int t = t0*64 + w*16 + quad*4 + rg;
      attT[(size_t)(nl*576 + t)*512 + c0 + ni*16 + r15] = f2b(oc[ni][rg]*inv[rg]);
    }
}

// ---------------------------------------------------------------- K4: spatial proj + residual (MFMA)
// R1: LDS-transpose epilogue with coalesced 16B stores (x2 and x2T).
__global__ __launch_bounds__(256) void k_proj_s_mfma(const bf16* __restrict__ AT,
        const bf16* __restrict__ Wb, const void* __restrict__ Bv,
        const void* __restrict__ xin, bf16* __restrict__ x2,
        bf16* __restrict__ x2T, int doT,
        const int* __restrict__ flag, int n0){
  const bool f32in = flag[0] != 0;
  const int o0 = blockIdx.x * 128;
  const int l0 = blockIdx.y * 64;
  const int nl = blockIdx.z;
  const int n = n0 + nl;
  const int b = n >> 4, t = n & 15;
  const int tid = threadIdx.x, lane = tid & 63;
  const int wm = (tid >> 6) & 1, wn = tid >> 7;
  const int r15 = lane & 15, quad = lane >> 4;
  __shared__ bf16 As[128*72];
  __shared__ bf16 Bs[64*72];
  v4f acc[4][2];
  #pragma unroll
  for (int i = 0; i < 4; ++i)
    #pragma unroll
    for (int j = 0; j < 2; ++j) acc[i][j] = (v4f){0.f,0.f,0.f,0.f};
  for (int kc = 0; kc < 512; kc += 64){
    __syncthreads();
    #pragma unroll
    for (int r = 0; r < 8; ++r){
      int e4 = (tid + 256*r)*4;
      int row = e4 >> 6, k = e4 & 63;
      stage4b(&Wb[(size_t)(o0+row)*512 + kc + k], &As[row*72 + k]);
    }
    #pragma unroll
    for (int r = 0; r < 4; ++r){
      int e4 = (tid + 256*r)*4;
      int row = e4 >> 6, k = e4 & 63;
      stage4b(&AT[(size_t)(nl*576 + l0 + row)*512 + kc + k], &Bs[row*72 + k]);
    }
    __syncthreads();
    #pragma unroll
    for (int ks = 0; ks < 2; ++ks){
      v8s a[4], b[2];
      #pragma unroll
      for (int mi = 0; mi < 4; ++mi)
        a[mi] = *(const v8s*)&As[(wm*64 + mi*16 + r15)*72 + ks*32 + quad*8];
      #pragma unroll
      for (int ni = 0; ni < 2; ++ni)
        b[ni] = *(const v8s*)&Bs[(wn*32 + ni*16 + r15)*72 + ks*32 + quad*8];
      #pragma unroll
      for (int mi = 0; mi < 4; ++mi)
        #pragma unroll
        for (int ni = 0; ni < 2; ++ni)
          acc[mi][ni] = __builtin_amdgcn_mfma_f32_16x16x32_bf16(a[mi], b[ni], acc[mi][ni], 0, 0, 0);
    }
  }
  // -------- epilogue: stage acc+bias into As as [o_rel][l_rel] (stride 72)
  __syncthreads();
  #pragma unroll
  for (int mi = 0; mi < 4; ++mi){
    int orel = wm*64 + mi*16 + quad*4;
    #pragma unroll
    for (int rg = 0; rg < 4; ++rg){
      float bia = ldin(Bv, o0 + orel + rg, f32in);
      #pragma unroll
      for (int ni = 0; ni < 2; ++ni)
        As[(orel + rg)*72 + wn*32 + ni*16 + r15] = f2b(acc[mi][ni][rg] + bia);
    }
  }
  __syncthreads();
  // phase 1: residual add + coalesced x2 write (+writeback for phase 2)
  const size_t xrow = ((size_t)(b*512 + o0)*16 + t)*576 + l0;
  for (int it = 0; it < 4; ++it){
    int idx = tid + it*256;             // 1024 chunks of 8 elems
    int o = idx >> 3, lc = (idx & 7)*8;
    union { bf16 h[8]; v8s v; } val;
    val.v = *(const v8s*)&As[o*72 + lc];
    size_t ga = xrow + (size_t)o*9216 + lc;
    if (f32in){
      const float* xp = (const float*)xin + ga;
      float4 f0 = *(const float4*)xp;
      float4 f1 = *(const float4*)(xp + 4);
      val.h[0] = f2b(b2f(val.h[0]) + f0.x);
      val.h[1] = f2b(b2f(val.h[1]) + f0.y);
      val.h[2] = f2b(b2f(val.h[2]) + f0.z);
      val.h[3] = f2b(b2f(val.h[3]) + f0.w);
      val.h[4] = f2b(b2f(val.h[4]) + f1.x);
      val.h[5] = f2b(b2f(val.h[5]) + f1.y);
      val.h[6] = f2b(b2f(val.h[6]) + f1.z);
      val.h[7] = f2b(b2f(val.h[7]) + f1.w);
    } else {
      union { bf16 h[8]; v8s v; } xv;
      xv.v = *(const v8s*)((const bf16*)xin + ga);
      #pragma unroll
      for (int j = 0; j < 8; ++j) val.h[j] = f2b(b2f(val.h[j]) + b2f(xv.h[j]));
    }
    *(v8s*)&x2[ga] = val.v;
    if (doT) *(v8s*)&As[o*72 + lc] = val.v;
  }
  if (doT){
    __syncthreads();
    // phase 2: x2T [m][t][c]: per chunk, 8 consecutive o at fixed l
    const size_t tbase = ((size_t)b*576 + l0)*8192 + (size_t)t*512 + o0;
    for (int it = 0; it < 4; ++it){
      int l = (tid & 15) + it*16;
      int ocg = (tid >> 4)*8;
      union { bf16 h[8]; v8s v; } val;
      #pragma unroll
      for (int j = 0; j < 8; ++j) val.h[j] = As[(ocg + j)*72 + l];
      *(v8s*)&x2T[tbase + (size_t)l*8192 + ocg] = val.v;
    }
  }
}

// ---------------------------------------------------------------- K5a: temporal groupnorm (scattered x2) -> xnT [m][t][c]
__global__ __launch_bounds__(256) void k_gn_t(const bf16* __restrict__ x2,
        const void* __restrict__ gw, const void* __restrict__ gb,
        bf16* __restrict__ xnT, const int* __restrict__ flag, int m0){
  const bool f32in = flag[0] != 0;
  const int ml = blockIdx.x;
  const int m = m0 + ml;
  const int b = m / 576, l = m - b*576;
  const int tid = threadIdx.x;
  __shared__ float xs[8192];
  __shared__ float mg[32], rg[32];
  for (int i = tid; i < 8192; i += 256){
    int t = i >> 9, c = i & 511;
    xs[i] = b2f(x2[((b*512 + c)*16 + t)*576 + l]);
  }
  __syncthreads();
  {
    int g = tid >> 3, ii = tid & 7;
    float s = 0.f, q = 0.f;
    for (int idx = ii; idx < 256; idx += 8){
      int t = idx >> 4, cg = idx & 15;
      float v = xs[t*512 + g*16 + cg]; s += v; q += v*v;
    }
    #pragma unroll
    for (int off = 1; off < 8; off <<= 1){ s += __shfl_xor(s, off, 64); q += __shfl_xor(q, off, 64); }
    if (ii == 0){
      float mean = s*(1.f/256.f);
      float var  = q*(1.f/256.f) - mean*mean;
      mg[g] = mean; rg[g] = rsqrtf(fmaxf(var, 0.f) + 1e-5f);
    }
  }
  __syncthreads();
  for (int i = tid; i < 8192; i += 256){
    int c = i & 511, g = c >> 4;
    xnT[(size_t)ml*8192 + i] = f2b((xs[i] - mg[g])*rg[g]*ldin(gw, c, f32in) + ldin(gb, c, f32in));
  }
}

// ---------------------------------------------------------------- K5b: temporal groupnorm (coalesced x2T)
__global__ __launch_bounds__(256) void k_gn_t2(const bf16* __restrict__ x2T,
        const void* __restrict__ gw, const void* __restrict__ gb,
        bf16* __restrict__ xnT, const int* __restrict__ flag, int m0){
  const bool f32in = flag[0] != 0;
  const int ml = blockIdx.x;
  const int m = m0 + ml;
  const int tid = threadIdx.x;
  __shared__ float xs[8192];
  __shared__ float mg[32], rg[32];
  for (int i = tid; i < 8192; i += 256)
    xs[i] = b2f(x2T[(size_t)m*8192 + i]);     // [t][c] order, fully coalesced
  __syncthreads();
  {
    int g = tid >> 3, ii = tid & 7;
    float s = 0.f, q = 0.f;
    for (int idx = ii; idx < 256; idx += 8){
      int t = idx >> 4, cg = idx & 15;
      float v = xs[t*512 + g*16 + cg]; s += v; q += v*v;
    }
    #pragma unroll
    for (int off = 1; off < 8; off <<= 1){ s += __shfl_xor(s, off, 64); q += __shfl_xor(q, off, 64); }
    if (ii == 0){
      float mean = s*(1.f/256.f);
      float var  = q*(1.f/256.f) - mean*mean;
      mg[g] = mean; rg[g] = rsqrtf(fmaxf(var, 0.f) + 1e-5f);
    }
  }
  __syncthreads();
  for (int i = tid; i < 8192; i += 256){
    int c = i & 511, g = c >> 4;
    xnT[(size_t)ml*8192 + i] = f2b((xs[i] - mg[g])*rg[g]*ldin(gw, c, f32in) + ldin(gb, c, f32in));
  }
}

// ---------------------------------------------------------------- K7: temporal attention -> attT [m][t][c]
// R8: vectorized staging — qkv via v8s (8 consecutive t, one c), tables via
// float4 (f32) / v8s+cvt (bf16) with contiguous float4 LDS writes.
__global__ __launch_bounds__(256) void k_attn_t(const bf16* __restrict__ qkv,
        const void* __restrict__ tbk, const void* __restrict__ tbv,
        bf16* __restrict__ attT, const int* __restrict__ flag){
  const bool f32in = flag[0] != 0;
  const int head = blockIdx.x;
  const int ml = blockIdx.y;
  const int tid = threadIdx.x;
  __shared__ float qsT[16*68], ksT[16*68], vsT[16*68];  // [t][c], stride 68 (16B-aligned rows)
  __shared__ float tks[33*68], tvs[33*68];              // [d][c]
  __shared__ float ps[16*17];
  const int base = (ml*1536 + head*64)*16;
  // ---- qkv staging: 3 arrays x 128 v8s-chunks (chunk = 8 consecutive t, one c)
  for (int j = tid; j < 384; j += 256){
    int arr = j >> 7, cj = j & 127;
    int c = cj >> 1, t0 = (cj & 1)*8;
    union { bf16 h[8]; v8s v; } u;
    u.v = *(const v8s*)(qkv + base + arr*8192 + c*16 + t0);
    float* dst = (arr == 0) ? qsT : (arr == 1) ? ksT : vsT;
    #pragma unroll
    for (int e = 0; e < 8; ++e) dst[(t0 + e)*68 + c] = b2f(u.h[e]);
  }
  // ---- table staging: 33x64 each; contiguous-in-c chunks -> float4 LDS writes
  if (f32in){
    for (int j = tid; j < 1056; j += 256){
      int tb = (j >= 528) ? 1 : 0;
      int cj = j - tb*528;
      int d = cj >> 4, c = (cj & 15)*4;
      float4 v = *(const float4*)((const float*)(tb ? tbv : tbk) + d*64 + c);
      *(float4*)&((tb ? tvs : tks)[d*68 + c]) = v;
    }
  } else {
    for (int j = tid; j < 528; j += 256){
      int tb = (j >= 264) ? 1 : 0;
      int cj = j - tb*264;
      int d = cj >> 3, c = (cj & 7)*8;
      union { bf16 h[8]; v8s v; } u;
      u.v = *(const v8s*)((const bf16*)(tb ? tbv : tbk) + d*64 + c);
      float* dst = (tb ? tvs : tks) + d*68 + c;
      float4 f0 = {b2f(u.h[0]), b2f(u.h[1]), b2f(u.h[2]), b2f(u.h[3])};
      float4 f1 = {b2f(u.h[4]), b2f(u.h[5]), b2f(u.h[6]), b2f(u.h[7])};
      *(float4*)dst = f0;
      *(float4*)(dst + 4) = f1;
    }
  }
  __syncthreads();
  {
    const int t = tid >> 4, s = tid & 15;
    const float4* qt = (const float4*)&qsT[t*68];
    const float4* kr = (const float4*)&ksT[s*68];
    const float4* q2 = (const float4*)&qsT[s*68];
    const float4* tr = (const float4*)&tks[(t - s + 16)*68];
    float qk = 0.f, rp = 0.f;
    #pragma unroll
    for (int c4 = 0; c4 < 16; ++c4){
      float4 a = qt[c4], b = kr[c4];
      qk += a.x*b.x + a.y*b.y + a.z*b.z + a.w*b.w;
      float4 a2 = q2[c4], tb = tr[c4];
      rp += a2.x*tb.x + a2.y*tb.y + a2.z*tb.z + a2.w*tb.w;
    }
    float logit = 0.125f*qk + 0.35355339059327373f*rp;
    if (s > t) logit = -1e8f;
    float mx = logit;
    #pragma unroll
    for (int off = 8; off; off >>= 1) mx = fmaxf(mx, __shfl_xor(mx, off, 16));
    float e = __expf(logit - mx);
    float tot = e;
    #pragma unroll
    for (int off = 8; off; off >>= 1) tot += __shfl_xor(tot, off, 16);
    ps[t*17 + s] = e / tot;
  }
  __syncthreads();
  {
    const int c4 = tid & 15, t = tid >> 4;
    float4 acc = {0.f,0.f,0.f,0.f};
    #pragma unroll
    for (int s = 0; s < 16; ++s){
      float p = ps[t*17 + s];
      float4 v4 = *(const float4*)&vsT[s*68 + c4*4];
      float4 t4 = *(const float4*)&tvs[(s - t + 16)*68 + c4*4];
      acc.x += p*(v4.x + t4.x); acc.y += p*(v4.y + t4.y);
      acc.z += p*(v4.z + t4.z); acc.w += p*(v4.w + t4.w);
    }
    union { bf16 h[4]; ushort4 u; } o;
    o.h[0] = f2b(acc.x); o.h[1] = f2b(acc.y); o.h[2] = f2b(acc.z); o.h[3] = f2b(acc.w);
    *(ushort4*)&attT[(size_t)ml*8192 + t*512 + head*64 + c4*4] = o.u;
  }
}

// ---------------------------------------------------------------- K8: temporal proj + residual -> out (MFMA, coalesced)
__global__ __launch_bounds__(256) void k_proj_t_mfma(const bf16* __restrict__ AT,
        const bf16* __restrict__ Wb, const void* __restrict__ Bv,
        const bf16* __restrict__ x2, void* __restrict__ out,
        const int* __restrict__ flag, int m0){
  const bool f32in = flag[0] != 0;
  const int o0 = blockIdx.x * 128;
  const int tp = blockIdx.y;            // t-pair
  const int mg0 = blockIdx.z * 32;      // m base (32 | 576)
  const int tid = threadIdx.x, lane = tid & 63;
  const int wm = (tid >> 6) & 1, wn = tid >> 7;
  const int r15 = lane & 15, quad = lane >> 4;
  __shared__ bf16 As[128*72];
  __shared__ bf16 Bs[64*72];
  v4f acc[4][2];
  #pragma unroll
  for (int i = 0; i < 4; ++i)
    #pragma unroll
    for (int j = 0; j < 2; ++j) acc[i][j] = (v4f){0.f,0.f,0.f,0.f};
  for (int kc = 0; kc < 512; kc += 64){
    __syncthreads();
    #pragma unroll
    for (int r = 0; r < 8; ++r){
      int e4 = (tid + 256*r)*4;
      int row = e4 >> 6, k = e4 & 63;
      stage4b(&Wb[(size_t)(o0+row)*512 + kc + k], &As[row*72 + k]);
    }
    #pragma unroll
    for (int r = 0; r < 4; ++r){
      int e4 = (tid + 256*r)*4;
      int row = e4 >> 6, k = e4 & 63;
      stage4b(&AT[(size_t)(mg0 + (row & 31))*8192 + (tp*2 + (row >> 5))*512 + kc + k],
              &Bs[row*72 + k]);
    }
    __syncthreads();
    #pragma unroll
    for (int ks = 0; ks < 2; ++ks){
      v8s a[4], b[2];
      #pragma unroll
      for (int mi = 0; mi < 4; ++mi)
        a[mi] = *(const v8s*)&As[(wm*64 + mi*16 + r15)*72 + ks*32 + quad*8];
      #pragma unroll
      for (int ni = 0; ni < 2; ++ni)
        b[ni] = *(const v8s*)&Bs[(wn*32 + ni*16 + r15)*72 + ks*32 + quad*8];
      #pragma unroll
      for (int mi = 0; mi < 4; ++mi)
        #pragma unroll
        for (int ni = 0; ni < 2; ++ni)
          acc[mi][ni] = __builtin_amdgcn_mfma_f32_16x16x32_bf16(a[mi], b[ni], acc[mi][ni], 0, 0, 0);
    }
  }
  const int tt = tp*2 + wn;
  #pragma unroll
  for (int mi = 0; mi < 4; ++mi)
    #pragma unroll
    for (int rg = 0; rg < 4; ++rg){
      int o = o0 + wm*64 + mi*16 + quad*4 + rg;
      float bia = ldin(Bv, o, f32in);
      #pragma unroll
      for (int ni = 0; ni < 2; ++ni){
        int m = m0 + mg0 + ni*16 + r15;
        int b = m / 576, l = m - b*576;
        size_t addr = ((size_t)(b*512 + o)*16 + tt)*576 + l;
        float val = acc[mi][ni][rg] + bia + b2f(x2[addr]);
        if (f32in) ((float*)out)[addr] = val;
        else       ((bf16*)out)[addr] = f2b(val);
      }
    }
}

// ----------------------------------------------------------------
extern "C" void kernel_launch(void* const* d_in, const int* in_sizes, int n_in,
                              void* d_out, int out_size, void* d_ws, size_t ws_size,
                              hipStream_t stream){
  const void* x   = d_in[0];
  const void* nsw = d_in[1];
  const void* nsb = d_in[2];
  const void* qsw = d_in[3];
  const void* qsb = d_in[4];
  const void* psw = d_in[5];
  const void* psb = d_in[6];
  const void* ntw = d_in[7];
  const void* ntb = d_in[8];
  const void* qtw = d_in[9];
  const void* qtb = d_in[10];
  const void* ptw = d_in[11];
  const void* ptb = d_in[12];
  const void* rpk = d_in[13];
  const void* rpv = d_in[14];

  // Chunking and x2T gate from ws_size (constant across calls -> graph-safe).
  const size_t S_full = (size_t)32*294912;
  const size_t need_full = 256 + (S_full*5 + 9437184)*2;
  const size_t need_T    = 256 + (S_full*5 + (size_t)2*9437184)*2;  // +18.9 MB for x2T
  const int NCH = (ws_size >= need_full) ? 32 : 8;
  const int MCH = (NCH == 32) ? 1152 : 288;
  const size_t S = (size_t)NCH*294912;
  const int useT = (NCH == 32 && ws_size >= need_T) ? 1 : 0;

  int*  flag = (int*)d_ws;
  bf16* A  = (bf16*)((char*)d_ws + 256);   // S: xnT_s / xnT_t
  bf16* A2 = A  + S;                        // S: attT_s / attT_t (+ transient W copy)
  bf16* Bq = A2 + S;                        // 3S: qkv (+ transient W copies)
  bf16* Cx = Bq + 3*S;                      // 9,437,184: x2 residual
  bf16* Cx2 = Cx + 9437184;                 // 9,437,184: x2T [m][t][c] (if useT)
  const size_t kOff = S, vOff = 2*S;
  bf16* Wcv  = A2;
  bf16* Wcv2 = Bq;

  k_detect<<<1, 64, 0, stream>>>(x, flag);

  for (int n0 = 0; n0 < 32; n0 += NCH){
    k_gn_s       <<<dim3(32, NCH),   256, 0, stream>>>(x, nsw, nsb, A, flag, n0);
    k_cvtw       <<<dim3(768),       256, 0, stream>>>(qsw, Wcv, 196608, flag);
    k_gemm_qkv   <<<dim3(NCH*54),    256, 0, stream>>>(A, Wcv, qsb, Bq, flag, kOff, vOff, 0);
    k_attn_s_mfma<<<dim3(72*NCH),    256, 0, stream>>>(Bq, A2, kOff, vOff);
    // proj_s weight pre-convert into Bq (qkv dead after attn_s)
    k_cvtw       <<<dim3(256),       256, 0, stream>>>(psw, Bq, 65536, flag);
    k_proj_s_mfma<<<dim3(4, 9, NCH), 256, 0, stream>>>(A2, Bq, psb, x, Cx, Cx2, useT, flag, n0);
  }
  for (int m0 = 0; m0 < 1152; m0 += MCH){
    if (useT) k_gn_t2<<<dim3(MCH),   256, 0, stream>>>(Cx2, ntw, ntb, A, flag, m0);
    else      k_gn_t <<<dim3(MCH),   256, 0, stream>>>(Cx,  ntw, ntb, A, flag, m0);
    k_cvtw       <<<dim3(768),       256, 0, stream>>>(qtw, Wcv, 196608, flag);
    k_gemm_qkv   <<<dim3((MCH/2)*3), 256, 0, stream>>>(A, Wcv, qtb, Bq, flag, 0, 0, 1);
    k_attn_t     <<<dim3(8, MCH),    256, 0, stream>>>(Bq, rpk, rpv, A2, flag);
    k_cvtw       <<<dim3(256),       256, 0, stream>>>(ptw, Wcv2, 65536, flag);
    k_proj_t_mfma<<<dim3(4, 8, MCH/32), 256, 0, stream>>>(A2, Wcv2, ptb, Cx, d_out, flag, m0);
  }
}

// Round 12
// 458.762 us; speedup vs baseline: 1.1162x; 1.0225x over previous
//
#include <hip/hip_runtime.h>
#include <hip/hip_bf16.h>

typedef __hip_bfloat16 bf16;
typedef __attribute__((ext_vector_type(8))) short v8s;
typedef __attribute__((ext_vector_type(4))) float v4f;

__device__ __forceinline__ float b2f(bf16 v){ return __bfloat162float(v); }
__device__ __forceinline__ bf16  f2b(float v){ return __float2bfloat16(v); }

// Inputs may be bf16 OR f32 — runtime-detected flag (1 => f32). Output dtype follows.
__device__ __forceinline__ float ldin(const void* p, int i, bool f32in){
  return f32in ? ((const float*)p)[i] : b2f(((const bf16*)p)[i]);
}

// stage 4 consecutive source elems (f32-or-bf16) into dst as bf16 (8B write)
__device__ __forceinline__ void stage4(const void* src, size_t off, bool f32in, bf16* dst){
  union { bf16 h[4]; ushort4 u; } tmp;
  if (f32in){
    float4 f = *(const float4*)((const float*)src + off);
    tmp.h[0] = f2b(f.x); tmp.h[1] = f2b(f.y); tmp.h[2] = f2b(f.z); tmp.h[3] = f2b(f.w);
  } else {
    tmp.u = *(const ushort4*)((const ushort*)src + off);
  }
  *(ushort4*)dst = tmp.u;
}
__device__ __forceinline__ void stage4b(const bf16* src, bf16* dst){
  *(ushort4*)dst = *(const ushort4*)src;
}

// async global->LDS, 16B per lane. LDS dest must be wave-uniform base (HW adds lane*16).
__device__ __forceinline__ void async_cp16(const bf16* g, bf16* l){
  __builtin_amdgcn_global_load_lds(
      (const __attribute__((address_space(1))) unsigned int*)g,
      (__attribute__((address_space(3))) unsigned int*)l, 16, 0, 0);
}

// Problem: B=2, C=512, T=16, H=W=24, heads=8, ch=64
// ws: flag | A (S) | A2 (S) | Bq (3S) | Cx 9,437,184 | [Cx2 9,437,184 if room]
// R1: proj_s epilogue request-bound -> LDS-transpose epilogue (WIN, -58us).
// R2: qkv GEMMs -> unified 128x128 global_load_lds GEMM.
// R3: XOR-swizzle via pre-swizzled global source + swizzled ds_read (conflict=0, R9 PMC).
// R4: attn_s setprio bundle FAILED; R6 conditional max-reduce + ones-MFMA WIN (-19us).
// R8: attn_t staging vectorized (WIN, -24us).
// R9: gemm_qkv 77us, no pipe >27% -> LDS-staged C-tile epilogue + 16B chunk stores.
// R10/R11: infra failures, no measurement — resubmitted unchanged.

// ---------------------------------------------------------------- detect input dtype
__global__ void k_detect(const void* x, int* flag){
  int tid = threadIdx.x;
  const bf16* p = (const bf16*)x;
  int cnt = 0;
  for (int i = tid; i < 512; i += 64){
    float v = b2f(p[i]);
    if (!(fabsf(v) <= 64.f)) cnt++;
  }
  #pragma unroll
  for (int off = 32; off; off >>= 1) cnt += __shfl_down(cnt, off, 64);
  if (tid == 0) flag[0] = (cnt > 16) ? 1 : 0;
}

// ---------------------------------------------------------------- weight convert -> bf16 scratch
__global__ __launch_bounds__(256) void k_cvtw(const void* __restrict__ W,
        bf16* __restrict__ out, int n4, const int* __restrict__ flag){
  const bool f32in = flag[0] != 0;
  int i = blockIdx.x*256 + threadIdx.x;
  if (i < n4) stage4(W, (size_t)i*4, f32in, out + (size_t)i*4);
}

// ---------------------------------------------------------------- K1: spatial groupnorm -> xnT [l][c]
__global__ __launch_bounds__(256) void k_gn_s(const void* __restrict__ x,
        const void* __restrict__ gw, const void* __restrict__ gb,
        bf16* __restrict__ xnT, const int* __restrict__ flag, int n0){
  const bool f32in = flag[0] != 0;
  const int g = blockIdx.x;
  const int nl = blockIdx.y;
  const int n = n0 + nl;
  const int b = n >> 4, t = n & 15;
  const int tid = threadIdx.x;
  __shared__ float xs[576*17];     // [l][cg] padded
  __shared__ float red[4][2];
  __shared__ float stats[2];
  float s = 0.f, q = 0.f;
  for (int i = tid; i < 9216; i += 256){
    int cg = i / 576, l = i - cg*576;
    int c = g*16 + cg;
    float v = ldin(x, ((b*512 + c)*16 + t)*576 + l, f32in);
    xs[l*17 + cg] = v; s += v; q += v*v;
  }
  #pragma unroll
  for (int off = 32; off; off >>= 1){ s += __shfl_down(s, off, 64); q += __shfl_down(q, off, 64); }
  int wid = tid >> 6;
  if ((tid & 63) == 0){ red[wid][0] = s; red[wid][1] = q; }
  __syncthreads();
  if (tid == 0){
    float S = red[0][0]+red[1][0]+red[2][0]+red[3][0];
    float Q = red[0][1]+red[1][1]+red[2][1]+red[3][1];
    float mean = S * (1.f/9216.f);
    float var  = Q * (1.f/9216.f) - mean*mean;
    stats[0] = mean; stats[1] = rsqrtf(fmaxf(var, 0.f) + 1e-5f);
  }
  __syncthreads();
  float mean = stats[0], rstd = stats[1];
  for (int i = tid; i < 9216; i += 256){
    int l = i >> 4, cg = i & 15;
    int c = g*16 + cg;
    xnT[(size_t)(nl*576 + l)*512 + c] =
        f2b((xs[l*17 + cg] - mean)*rstd*ldin(gw, c, f32in) + ldin(gb, c, f32in));
  }
}

// ---------------------------------------------------------------- K2/K6: unified qkv GEMM
// Xf: flat [R][512] bf16. Wb: [1536][512] bf16. 128x128 tile, BK=64,
// global_load_lds staging into linear LDS; slot^=(row&7) XOR swizzle via
// pre-swizzled global source + swizzled ds_read (T2 / rule #21).
// R9: LDS-staged C-tile epilogue with 16B contiguous stores.
// mode 0: spatial (Q/K [l][512] + V [c][576] per nl); mode 1: temporal [m][o][t].
__global__ __launch_bounds__(256) void k_gemm_qkv(const bf16* __restrict__ Xf,
        const bf16* __restrict__ Wb, const void* __restrict__ Bv,
        bf16* __restrict__ Y, const int* __restrict__ flag,
        size_t kOff, size_t vOff, int mode){
  const bool f32in = flag[0] != 0;
  const int nwg = gridDim.x;
  const int bid = blockIdx.x;
  const int g = (bid & 7)*(nwg >> 3) + (bid >> 3);   // chunked XCD swizzle (nwg%8==0)
  const int mt = g / 12, nt = g - mt*12;
  const int r0 = mt*128, o0 = nt*128;
  const int tid = threadIdx.x, lane = tid & 63, w = tid >> 6;
  const int wm = w & 1, wn = w >> 1;
  const int r15 = lane & 15, quad = lane >> 4;
  const int rsw = r15 & 7;                 // read-side swizzle key (row&7 == r15&7)
  __shared__ bf16 LB[16384];               // As=LB[0..8191], Bs=LB[8192..]; C-tile after loop
  bf16* As = LB;
  bf16* Bs = LB + 8192;
  v4f acc[4][4];
  #pragma unroll
  for (int i = 0; i < 4; ++i)
    #pragma unroll
    for (int j = 0; j < 4; ++j) acc[i][j] = (v4f){0.f,0.f,0.f,0.f};
  for (int kc = 0; kc < 512; kc += 64){
    __syncthreads();
    #pragma unroll
    for (int r = 0; r < 4; ++r){
      int d = (tid + 256*r)*8;             // linear LDS elem offset this lane fills
      int row = d >> 6;
      int slot = (d >> 3) & 7;             // 16B slot within the 128B row
      int col = ((slot ^ (row & 7)) * 8);  // inverse-swizzled source column
      async_cp16(&Xf[(size_t)(r0 + row)*512 + kc + col], As + r*2048 + w*512);
      async_cp16(&Wb[(size_t)(o0 + row)*512 + kc + col], Bs + r*2048 + w*512);
    }
    __syncthreads();                        // compiler drains vmcnt(0) before barrier
    #pragma unroll
    for (int ks = 0; ks < 2; ++ks){
      v8s a[4], b[4];
      #pragma unroll
      for (int mi = 0; mi < 4; ++mi)
        a[mi] = *(const v8s*)&As[(wm*64 + mi*16 + r15)*64 + (((ks*4 + quad) ^ rsw)*8)];
      #pragma unroll
      for (int ni = 0; ni < 4; ++ni)
        b[ni] = *(const v8s*)&Bs[(wn*64 + ni*16 + r15)*64 + (((ks*4 + quad) ^ rsw)*8)];
      #pragma unroll
      for (int mi = 0; mi < 4; ++mi)
        #pragma unroll
        for (int ni = 0; ni < 4; ++ni)
          acc[mi][ni] = __builtin_amdgcn_mfma_f32_16x16x32_bf16(a[mi], b[ni], acc[mi][ni], 0, 0, 0);
    }
  }
  // ---- R9 epilogue: stage acc+bias into LB as [r=128][c=128], then 16B stores
  __syncthreads();
  #pragma unroll
  for (int ni = 0; ni < 4; ++ni){
    int crel = wn*64 + ni*16 + r15;
    float bia = ldin(Bv, o0 + crel, f32in);
    #pragma unroll
    for (int mi = 0; mi < 4; ++mi){
      int rb = wm*64 + mi*16 + quad*4;
      #pragma unroll
      for (int rg = 0; rg < 4; ++rg)
        LB[(rb + rg)*128 + crel] = f2b(acc[mi][ni][rg] + bia);
    }
  }
  __syncthreads();
  if (mode == 0){
    const int seg = o0 >> 9, ob = o0 & 511;
    const size_t segb = (seg==0) ? 0 : (seg==1) ? kOff : vOff;
    if (seg < 2){
      // Q/K [l][512]: chunk = 8 consecutive oseg at fixed row
      for (int i = tid; i < 2048; i += 256){
        int r = i >> 4, c8 = (i & 15)*8;
        v8s v = *(const v8s*)&LB[r*128 + c8];
        int rr = r0 + r;
        int nl = rr / 576, l = rr - nl*576;
        *(v8s*)&Y[segb + (size_t)nl*294912 + (size_t)l*512 + ob + c8] = v;
      }
    } else {
      // V [c][576]: chunk = 8 consecutive rows (l) at fixed col; lanes c-major
      for (int i = tid; i < 2048; i += 256){
        int c = i & 127, rb = (i >> 7)*8;   // rows rb..rb+7 (576%8==0 -> no nl split)
        union { bf16 h[8]; v8s v; } u;
        #pragma unroll
        for (int e = 0; e < 8; ++e) u.h[e] = LB[(rb + e)*128 + c];
        int rr = r0 + rb;
        int nl = rr / 576, l = rr - nl*576;
        *(v8s*)&Y[segb + (size_t)nl*294912 + (size_t)(ob + c)*576 + l] = u.v;
      }
    }
  } else {
    // temporal [m][o][t]: chunk = 8 consecutive t at fixed (m, o); lanes c-major
    const int m0b = r0 >> 4;
    for (int i = tid; i < 2048; i += 256){
      int c = i & 127, rh = i >> 7;
      int mloc = rh >> 1, t0 = (rh & 1)*8;
      union { bf16 h[8]; v8s v; } u;
      #pragma unroll
      for (int e = 0; e < 8; ++e) u.h[e] = LB[(mloc*16 + t0 + e)*128 + c];
      *(v8s*)&Y[((size_t)(m0b + mloc)*1536 + o0 + c)*16 + t0] = u.v;
    }
  }
}

// ---------------------------------------------------------------- K3: spatial attention (flash MFMA) -> attT [l][c]
// R6: conditional max-reduce + ones-MFMA row-sum (no psum shfl); no setprio.
__global__ __launch_bounds__(256, 4) void k_attn_s_mfma(const bf16* __restrict__ qkv,
        bf16* __restrict__ attT, size_t kOff, size_t vOff){
  const int bid = blockIdx.x;
  const int xcd = bid & 7, slot = bid >> 3;
  const int nl = xcd + 8*(slot/72);
  const int idx = slot - 72*(slot/72);
  const int head = idx/9, t0 = idx - 9*head;
  const int tid = threadIdx.x, lane = tid & 63, w = tid >> 6;
  const int r15 = lane & 15, quad = lane >> 4;
  __shared__ bf16 Ks[64*72];
  __shared__ bf16 Vs[64*72];
  __shared__ bf16 Ps[4][16*72];
  const bf16* QT = qkv + (size_t)nl*294912;
  const bf16* KT = qkv + kOff + (size_t)nl*294912;
  const bf16* Vp = qkv + vOff + (size_t)nl*294912;
  const int c0 = head*64;
  v8s aq0, aq1;
  {
    const bf16* qrow = QT + (size_t)(t0*64 + w*16 + r15)*512 + c0;
    aq0 = *(const v8s*)(qrow + quad*8);
    aq1 = *(const v8s*)(qrow + 32 + quad*8);
  }
  // ones B-fragment for row-sum MFMA
  v8s bones;
  {
    union { bf16 h[8]; v8s v; } ob;
    #pragma unroll
    for (int j = 0; j < 8; ++j) ob.h[j] = f2b(1.f);
    bones = ob.v;
  }
  // staging geometry (reg prefetch)
  int srow[4], scol[4];
  #pragma unroll
  for (int r = 0; r < 4; ++r){
    int e4 = (tid + 256*r)*4;
    srow[r] = e4 >> 6; scol[r] = e4 & 63;
  }
  ushort4 kreg[4], vreg[4];
  #pragma unroll
  for (int r = 0; r < 4; ++r){
    kreg[r] = *(const ushort4*)&KT[(size_t)srow[r]*512 + c0 + scol[r]];
    vreg[r] = *(const ushort4*)&Vp[(size_t)(c0 + srow[r])*576 + scol[r]];
  }
  v4f oc[4];
  v4f oc2 = (v4f){0.f,0.f,0.f,0.f};         // row-sum accumulator (l_run)
  #pragma unroll
  for (int ni = 0; ni < 4; ++ni) oc[ni] = (v4f){0.f,0.f,0.f,0.f};
  float m_run[4] = {-1e30f,-1e30f,-1e30f,-1e30f};
  const float SC = 0.180336880f;            // 0.125 * log2(e): exp2 domain
  for (int sc = 0; sc < 9; ++sc){
    __syncthreads();
    #pragma unroll
    for (int r = 0; r < 4; ++r){
      *(ushort4*)&Ks[srow[r]*72 + scol[r]] = kreg[r];
      *(ushort4*)&Vs[srow[r]*72 + scol[r]] = vreg[r];
    }
    __syncthreads();
    if (sc < 8){                            // prefetch next tile under compute
      #pragma unroll
      for (int r = 0; r < 4; ++r){
        kreg[r] = *(const ushort4*)&KT[(size_t)((sc+1)*64 + srow[r])*512 + c0 + scol[r]];
        vreg[r] = *(const ushort4*)&Vp[(size_t)(c0 + srow[r])*576 + (sc+1)*64 + scol[r]];
      }
    }
    v4f sa[4];
    #pragma unroll
    for (int sj = 0; sj < 4; ++sj) sa[sj] = (v4f){0.f,0.f,0.f,0.f};
    #pragma unroll
    for (int sj = 0; sj < 4; ++sj){
      v8s b0 = *(const v8s*)&Ks[(sj*16 + r15)*72 + quad*8];
      v8s b1 = *(const v8s*)&Ks[(sj*16 + r15)*72 + 32 + quad*8];
      sa[sj] = __builtin_amdgcn_mfma_f32_16x16x32_bf16(aq0, b0, sa[sj], 0, 0, 0);
      sa[sj] = __builtin_amdgcn_mfma_f32_16x16x32_bf16(aq1, b1, sa[sj], 0, 0, 0);
    }
    // per-lane partial max per row-group (over this lane's 4 cols)
    float cmx[4] = {-1e30f,-1e30f,-1e30f,-1e30f};
    #pragma unroll
    for (int sj = 0; sj < 4; ++sj)
      #pragma unroll
      for (int rg = 0; rg < 4; ++rg){
        float v = sa[sj][rg]*SC;
        sa[sj][rg] = v;
        cmx[rg] = fmaxf(cmx[rg], v);
      }
    // defer-max: if no lane's PARTIAL exceeds m+8, true rowmax <= m+8 -> P <= 2^8, skip reduce
    float grow = fmaxf(fmaxf(cmx[0]-m_run[0], cmx[1]-m_run[1]),
                       fmaxf(cmx[2]-m_run[2], cmx[3]-m_run[3]));
    if (__any(grow > 8.f)){
      #pragma unroll
      for (int off = 1; off < 16; off <<= 1)
        #pragma unroll
        for (int rg = 0; rg < 4; ++rg) cmx[rg] = fmaxf(cmx[rg], __shfl_xor(cmx[rg], off, 64));
      #pragma unroll
      for (int rg = 0; rg < 4; ++rg){
        float mnew = fmaxf(m_run[rg], cmx[rg]);
        float al = exp2f(m_run[rg] - mnew);
        m_run[rg] = mnew;
        oc2[rg] *= al;
        #pragma unroll
        for (int ni = 0; ni < 4; ++ni) oc[ni][rg] *= al;
      }
    }
    #pragma unroll
    for (int sj = 0; sj < 4; ++sj)
      #pragma unroll
      for (int rg = 0; rg < 4; ++rg)
        Ps[w][(quad*4 + rg)*72 + sj*16 + r15] = f2b(exp2f(sa[sj][rg] - m_run[rg]));
    #pragma unroll
    for (int ks = 0; ks < 2; ++ks){
      v8s a = *(const v8s*)&Ps[w][r15*72 + ks*32 + quad*8];
      #pragma unroll
      for (int ni = 0; ni < 4; ++ni){
        v8s b = *(const v8s*)&Vs[(ni*16 + r15)*72 + ks*32 + quad*8];
        oc[ni] = __builtin_amdgcn_mfma_f32_16x16x32_bf16(a, b, oc[ni], 0, 0, 0);
      }
      oc2 = __builtin_amdgcn_mfma_f32_16x16x32_bf16(a, bones, oc2, 0, 0, 0);  // row-sum
    }
  }
  float inv[4];
  #pragma unroll
  for (int rg = 0; rg < 4; ++rg) inv[rg] = 1.f / oc2[rg];
  #pragma unroll
  for (int ni = 0; ni < 4; ++ni)
    #pragma unroll
    for (int rg = 0; rg < 4; ++rg){
      int t = t0*64 + w*16 + quad*4 + rg;
      attT[(size_t)(nl*576 + t)*512 + c0 + ni*16 + r15] = f2b(oc[ni][rg]*inv[rg]);
    }
}

// ---------------------------------------------------------------- K4: spatial proj + residual (MFMA)
// R1: LDS-transpose epilogue with coalesced 16B stores (x2 and x2T).
__global__ __launch_bounds__(256) void k_proj_s_mfma(const bf16* __restrict__ AT,
        const bf16* __restrict__ Wb, const void* __restrict__ Bv,
        const void* __restrict__ xin, bf16* __restrict__ x2,
        bf16* __restrict__ x2T, int doT,
        const int* __restrict__ flag, int n0){
  const bool f32in = flag[0] != 0;
  const int o0 = blockIdx.x * 128;
  const int l0 = blockIdx.y * 64;
  const int nl = blockIdx.z;
  const int n = n0 + nl;
  const int b = n >> 4, t = n & 15;
  const int tid = threadIdx.x, lane = tid & 63;
  const int wm = (tid >> 6) & 1, wn = tid >> 7;
  const int r15 = lane & 15, quad = lane >> 4;
  __shared__ bf16 As[128*72];
  __shared__ bf16 Bs[64*72];
  v4f acc[4][2];
  #pragma unroll
  for (int i = 0; i < 4; ++i)
    #pragma unroll
    for (int j = 0; j < 2; ++j) acc[i][j] = (v4f){0.f,0.f,0.f,0.f};
  for (int kc = 0; kc < 512; kc += 64){
    __syncthreads();
    #pragma unroll
    for (int r = 0; r < 8; ++r){
      int e4 = (tid + 256*r)*4;
      int row = e4 >> 6, k = e4 & 63;
      stage4b(&Wb[(size_t)(o0+row)*512 + kc + k], &As[row*72 + k]);
    }
    #pragma unroll
    for (int r = 0; r < 4; ++r){
      int e4 = (tid + 256*r)*4;
      int row = e4 >> 6, k = e4 & 63;
      stage4b(&AT[(size_t)(nl*576 + l0 + row)*512 + kc + k], &Bs[row*72 + k]);
    }
    __syncthreads();
    #pragma unroll
    for (int ks = 0; ks < 2; ++ks){
      v8s a[4], b[2];
      #pragma unroll
      for (int mi = 0; mi < 4; ++mi)
        a[mi] = *(const v8s*)&As[(wm*64 + mi*16 + r15)*72 + ks*32 + quad*8];
      #pragma unroll
      for (int ni = 0; ni < 2; ++ni)
        b[ni] = *(const v8s*)&Bs[(wn*32 + ni*16 + r15)*72 + ks*32 + quad*8];
      #pragma unroll
      for (int mi = 0; mi < 4; ++mi)
        #pragma unroll
        for (int ni = 0; ni < 2; ++ni)
          acc[mi][ni] = __builtin_amdgcn_mfma_f32_16x16x32_bf16(a[mi], b[ni], acc[mi][ni], 0, 0, 0);
    }
  }
  // -------- epilogue: stage acc+bias into As as [o_rel][l_rel] (stride 72)
  __syncthreads();
  #pragma unroll
  for (int mi = 0; mi < 4; ++mi){
    int orel = wm*64 + mi*16 + quad*4;
    #pragma unroll
    for (int rg = 0; rg < 4; ++rg){
      float bia = ldin(Bv, o0 + orel + rg, f32in);
      #pragma unroll
      for (int ni = 0; ni < 2; ++ni)
        As[(orel + rg)*72 + wn*32 + ni*16 + r15] = f2b(acc[mi][ni][rg] + bia);
    }
  }
  __syncthreads();
  // phase 1: residual add + coalesced x2 write (+writeback for phase 2)
  const size_t xrow = ((size_t)(b*512 + o0)*16 + t)*576 + l0;
  for (int it = 0; it < 4; ++it){
    int idx = tid + it*256;             // 1024 chunks of 8 elems
    int o = idx >> 3, lc = (idx & 7)*8;
    union { bf16 h[8]; v8s v; } val;
    val.v = *(const v8s*)&As[o*72 + lc];
    size_t ga = xrow + (size_t)o*9216 + lc;
    if (f32in){
      const float* xp = (const float*)xin + ga;
      float4 f0 = *(const float4*)xp;
      float4 f1 = *(const float4*)(xp + 4);
      val.h[0] = f2b(b2f(val.h[0]) + f0.x);
      val.h[1] = f2b(b2f(val.h[1]) + f0.y);
      val.h[2] = f2b(b2f(val.h[2]) + f0.z);
      val.h[3] = f2b(b2f(val.h[3]) + f0.w);
      val.h[4] = f2b(b2f(val.h[4]) + f1.x);
      val.h[5] = f2b(b2f(val.h[5]) + f1.y);
      val.h[6] = f2b(b2f(val.h[6]) + f1.z);
      val.h[7] = f2b(b2f(val.h[7]) + f1.w);
    } else {
      union { bf16 h[8]; v8s v; } xv;
      xv.v = *(const v8s*)((const bf16*)xin + ga);
      #pragma unroll
      for (int j = 0; j < 8; ++j) val.h[j] = f2b(b2f(val.h[j]) + b2f(xv.h[j]));
    }
    *(v8s*)&x2[ga] = val.v;
    if (doT) *(v8s*)&As[o*72 + lc] = val.v;
  }
  if (doT){
    __syncthreads();
    // phase 2: x2T [m][t][c]: per chunk, 8 consecutive o at fixed l
    const size_t tbase = ((size_t)b*576 + l0)*8192 + (size_t)t*512 + o0;
    for (int it = 0; it < 4; ++it){
      int l = (tid & 15) + it*16;
      int ocg = (tid >> 4)*8;
      union { bf16 h[8]; v8s v; } val;
      #pragma unroll
      for (int j = 0; j < 8; ++j) val.h[j] = As[(ocg + j)*72 + l];
      *(v8s*)&x2T[tbase + (size_t)l*8192 + ocg] = val.v;
    }
  }
}

// ---------------------------------------------------------------- K5a: temporal groupnorm (scattered x2) -> xnT [m][t][c]
__global__ __launch_bounds__(256) void k_gn_t(const bf16* __restrict__ x2,
        const void* __restrict__ gw, const void* __restrict__ gb,
        bf16* __restrict__ xnT, const int* __restrict__ flag, int m0){
  const bool f32in = flag[0] != 0;
  const int ml = blockIdx.x;
  const int m = m0 + ml;
  const int b = m / 576, l = m - b*576;
  const int tid = threadIdx.x;
  __shared__ float xs[8192];
  __shared__ float mg[32], rg[32];
  for (int i = tid; i < 8192; i += 256){
    int t = i >> 9, c = i & 511;
    xs[i] = b2f(x2[((b*512 + c)*16 + t)*576 + l]);
  }
  __syncthreads();
  {
    int g = tid >> 3, ii = tid & 7;
    float s = 0.f, q = 0.f;
    for (int idx = ii; idx < 256; idx += 8){
      int t = idx >> 4, cg = idx & 15;
      float v = xs[t*512 + g*16 + cg]; s += v; q += v*v;
    }
    #pragma unroll
    for (int off = 1; off < 8; off <<= 1){ s += __shfl_xor(s, off, 64); q += __shfl_xor(q, off, 64); }
    if (ii == 0){
      float mean = s*(1.f/256.f);
      float var  = q*(1.f/256.f) - mean*mean;
      mg[g] = mean; rg[g] = rsqrtf(fmaxf(var, 0.f) + 1e-5f);
    }
  }
  __syncthreads();
  for (int i = tid; i < 8192; i += 256){
    int c = i & 511, g = c >> 4;
    xnT[(size_t)ml*8192 + i] = f2b((xs[i] - mg[g])*rg[g]*ldin(gw, c, f32in) + ldin(gb, c, f32in));
  }
}

// ---------------------------------------------------------------- K5b: temporal groupnorm (coalesced x2T)
__global__ __launch_bounds__(256) void k_gn_t2(const bf16* __restrict__ x2T,
        const void* __restrict__ gw, const void* __restrict__ gb,
        bf16* __restrict__ xnT, const int* __restrict__ flag, int m0){
  const bool f32in = flag[0] != 0;
  const int ml = blockIdx.x;
  const int m = m0 + ml;
  const int tid = threadIdx.x;
  __shared__ float xs[8192];
  __shared__ float mg[32], rg[32];
  for (int i = tid; i < 8192; i += 256)
    xs[i] = b2f(x2T[(size_t)m*8192 + i]);     // [t][c] order, fully coalesced
  __syncthreads();
  {
    int g = tid >> 3, ii = tid & 7;
    float s = 0.f, q = 0.f;
    for (int idx = ii; idx < 256; idx += 8){
      int t = idx >> 4, cg = idx & 15;
      float v = xs[t*512 + g*16 + cg]; s += v; q += v*v;
    }
    #pragma unroll
    for (int off = 1; off < 8; off <<= 1){ s += __shfl_xor(s, off, 64); q += __shfl_xor(q, off, 64); }
    if (ii == 0){
      float mean = s*(1.f/256.f);
      float var  = q*(1.f/256.f) - mean*mean;
      mg[g] = mean; rg[g] = rsqrtf(fmaxf(var, 0.f) + 1e-5f);
    }
  }
  __syncthreads();
  for (int i = tid; i < 8192; i += 256){
    int c = i & 511, g = c >> 4;
    xnT[(size_t)ml*8192 + i] = f2b((xs[i] - mg[g])*rg[g]*ldin(gw, c, f32in) + ldin(gb, c, f32in));
  }
}

// ---------------------------------------------------------------- K7: temporal attention -> attT [m][t][c]
// R8: vectorized staging — qkv via v8s (8 consecutive t, one c), tables via
// float4 (f32) / v8s+cvt (bf16) with contiguous float4 LDS writes.
__global__ __launch_bounds__(256) void k_attn_t(const bf16* __restrict__ qkv,
        const void* __restrict__ tbk, const void* __restrict__ tbv,
        bf16* __restrict__ attT, const int* __restrict__ flag){
  const bool f32in = flag[0] != 0;
  const int head = blockIdx.x;
  const int ml = blockIdx.y;
  const int tid = threadIdx.x;
  __shared__ float qsT[16*68], ksT[16*68], vsT[16*68];  // [t][c], stride 68 (16B-aligned rows)
  __shared__ float tks[33*68], tvs[33*68];              // [d][c]
  __shared__ float ps[16*17];
  const int base = (ml*1536 + head*64)*16;
  // ---- qkv staging: 3 arrays x 128 v8s-chunks (chunk = 8 consecutive t, one c)
  for (int j = tid; j < 384; j += 256){
    int arr = j >> 7, cj = j & 127;
    int c = cj >> 1, t0 = (cj & 1)*8;
    union { bf16 h[8]; v8s v; } u;
    u.v = *(const v8s*)(qkv + base + arr*8192 + c*16 + t0);
    float* dst = (arr == 0) ? qsT : (arr == 1) ? ksT : vsT;
    #pragma unroll
    for (int e = 0; e < 8; ++e) dst[(t0 + e)*68 + c] = b2f(u.h[e]);
  }
  // ---- table staging: 33x64 each; contiguous-in-c chunks -> float4 LDS writes
  if (f32in){
    for (int j = tid; j < 1056; j += 256){
      int tb = (j >= 528) ? 1 : 0;
      int cj = j - tb*528;
      int d = cj >> 4, c = (cj & 15)*4;
      float4 v = *(const float4*)((const float*)(tb ? tbv : tbk) + d*64 + c);
      *(float4*)&((tb ? tvs : tks)[d*68 + c]) = v;
    }
  } else {
    for (int j = tid; j < 528; j += 256){
      int tb = (j >= 264) ? 1 : 0;
      int cj = j - tb*264;
      int d = cj >> 3, c = (cj & 7)*8;
      union { bf16 h[8]; v8s v; } u;
      u.v = *(const v8s*)((const bf16*)(tb ? tbv : tbk) + d*64 + c);
      float* dst = (tb ? tvs : tks) + d*68 + c;
      float4 f0 = {b2f(u.h[0]), b2f(u.h[1]), b2f(u.h[2]), b2f(u.h[3])};
      float4 f1 = {b2f(u.h[4]), b2f(u.h[5]), b2f(u.h[6]), b2f(u.h[7])};
      *(float4*)dst = f0;
      *(float4*)(dst + 4) = f1;
    }
  }
  __syncthreads();
  {
    const int t = tid >> 4, s = tid & 15;
    const float4* qt = (const float4*)&qsT[t*68];
    const float4* kr = (const float4*)&ksT[s*68];
    const float4* q2 = (const float4*)&qsT[s*68];
    const float4* tr = (const float4*)&tks[(t - s + 16)*68];
    float qk = 0.f, rp = 0.f;
    #pragma unroll
    for (int c4 = 0; c4 < 16; ++c4){
      float4 a = qt[c4], b = kr[c4];
      qk += a.x*b.x + a.y*b.y + a.z*b.z + a.w*b.w;
      float4 a2 = q2[c4], tb = tr[c4];
      rp += a2.x*tb.x + a2.y*tb.y + a2.z*tb.z + a2.w*tb.w;
    }
    float logit = 0.125f*qk + 0.35355339059327373f*rp;
    if (s > t) logit = -1e8f;
    float mx = logit;
    #pragma unroll
    for (int off = 8; off; off >>= 1) mx = fmaxf(mx, __shfl_xor(mx, off, 16));
    float e = __expf(logit - mx);
    float tot = e;
    #pragma unroll
    for (int off = 8; off; off >>= 1) tot += __shfl_xor(tot, off, 16);
    ps[t*17 + s] = e / tot;
  }
  __syncthreads();
  {
    const int c4 = tid & 15, t = tid >> 4;
    float4 acc = {0.f,0.f,0.f,0.f};
    #pragma unroll
    for (int s = 0; s < 16; ++s){
      float p = ps[t*17 + s];
      float4 v4 = *(const float4*)&vsT[s*68 + c4*4];
      float4 t4 = *(const float4*)&tvs[(s - t + 16)*68 + c4*4];
      acc.x += p*(v4.x + t4.x); acc.y += p*(v4.y + t4.y);
      acc.z += p*(v4.z + t4.z); acc.w += p*(v4.w + t4.w);
    }
    union { bf16 h[4]; ushort4 u; } o;
    o.h[0] = f2b(acc.x); o.h[1] = f2b(acc.y); o.h[2] = f2b(acc.z); o.h[3] = f2b(acc.w);
    *(ushort4*)&attT[(size_t)ml*8192 + t*512 + head*64 + c4*4] = o.u;
  }
}

// ---------------------------------------------------------------- K8: temporal proj + residual -> out (MFMA, coalesced)
__global__ __launch_bounds__(256) void k_proj_t_mfma(const bf16* __restrict__ AT,
        const bf16* __restrict__ Wb, const void* __restrict__ Bv,
        const bf16* __restrict__ x2, void* __restrict__ out,
        const int* __restrict__ flag, int m0){
  const bool f32in = flag[0] != 0;
  const int o0 = blockIdx.x * 128;
  const int tp = blockIdx.y;            // t-pair
  const int mg0 = blockIdx.z * 32;      // m base (32 | 576)
  const int tid = threadIdx.x, lane = tid & 63;
  const int wm = (tid >> 6) & 1, wn = tid >> 7;
  const int r15 = lane & 15, quad = lane >> 4;
  __shared__ bf16 As[128*72];
  __shared__ bf16 Bs[64*72];
  v4f acc[4][2];
  #pragma unroll
  for (int i = 0; i < 4; ++i)
    #pragma unroll
    for (int j = 0; j < 2; ++j) acc[i][j] = (v4f){0.f,0.f,0.f,0.f};
  for (int kc = 0; kc < 512; kc += 64){
    __syncthreads();
    #pragma unroll
    for (int r = 0; r < 8; ++r){
      int e4 = (tid + 256*r)*4;
      int row = e4 >> 6, k = e4 & 63;
      stage4b(&Wb[(size_t)(o0+row)*512 + kc + k], &As[row*72 + k]);
    }
    #pragma unroll
    for (int r = 0; r < 4; ++r){
      int e4 = (tid + 256*r)*4;
      int row = e4 >> 6, k = e4 & 63;
      stage4b(&AT[(size_t)(mg0 + (row & 31))*8192 + (tp*2 + (row >> 5))*512 + kc + k],
              &Bs[row*72 + k]);
    }
    __syncthreads();
    #pragma unroll
    for (int ks = 0; ks < 2; ++ks){
      v8s a[4], b[2];
      #pragma unroll
      for (int mi = 0; mi < 4; ++mi)
        a[mi] = *(const v8s*)&As[(wm*64 + mi*16 + r15)*72 + ks*32 + quad*8];
      #pragma unroll
      for (int ni = 0; ni < 2; ++ni)
        b[ni] = *(const v8s*)&Bs[(wn*32 + ni*16 + r15)*72 + ks*32 + quad*8];
      #pragma unroll
      for (int mi = 0; mi < 4; ++mi)
        #pragma unroll
        for (int ni = 0; ni < 2; ++ni)
          acc[mi][ni] = __builtin_amdgcn_mfma_f32_16x16x32_bf16(a[mi], b[ni], acc[mi][ni], 0, 0, 0);
    }
  }
  const int tt = tp*2 + wn;
  #pragma unroll
  for (int mi = 0; mi < 4; ++mi)
    #pragma unroll
    for (int rg = 0; rg < 4; ++rg){
      int o = o0 + wm*64 + mi*16 + quad*4 + rg;
      float bia = ldin(Bv, o, f32in);
      #pragma unroll
      for (int ni = 0; ni < 2; ++ni){
        int m = m0 + mg0 + ni*16 + r15;
        int b = m / 576, l = m - b*576;
        size_t addr = ((size_t)(b*512 + o)*16 + tt)*576 + l;
        float val = acc[mi][ni][rg] + bia + b2f(x2[addr]);
        if (f32in) ((float*)out)[addr] = val;
        else       ((bf16*)out)[addr] = f2b(val);
      }
    }
}

// ----------------------------------------------------------------
extern "C" void kernel_launch(void* const* d_in, const int* in_sizes, int n_in,
                              void* d_out, int out_size, void* d_ws, size_t ws_size,
                              hipStream_t stream){
  const void* x   = d_in[0];
  const void* nsw = d_in[1];
  const void* nsb = d_in[2];
  const void* qsw = d_in[3];
  const void* qsb = d_in[4];
  const void* psw = d_in[5];
  const void* psb = d_in[6];
  const void* ntw = d_in[7];
  const void* ntb = d_in[8];
  const void* qtw = d_in[9];
  const void* qtb = d_in[10];
  const void* ptw = d_in[11];
  const void* ptb = d_in[12];
  const void* rpk = d_in[13];
  const void* rpv = d_in[14];

  // Chunking and x2T gate from ws_size (constant across calls -> graph-safe).
  const size_t S_full = (size_t)32*294912;
  const size_t need_full = 256 + (S_full*5 + 9437184)*2;
  const size_t need_T    = 256 + (S_full*5 + (size_t)2*9437184)*2;  // +18.9 MB for x2T
  const int NCH = (ws_size >= need_full) ? 32 : 8;
  const int MCH = (NCH == 32) ? 1152 : 288;
  const size_t S = (size_t)NCH*294912;
  const int useT = (NCH == 32 && ws_size >= need_T) ? 1 : 0;

  int*  flag = (int*)d_ws;
  bf16* A  = (bf16*)((char*)d_ws + 256);   // S: xnT_s / xnT_t
  bf16* A2 = A  + S;                        // S: attT_s / attT_t (+ transient W copy)
  bf16* Bq = A2 + S;                        // 3S: qkv (+ transient W copies)
  bf16* Cx = Bq + 3*S;                      // 9,437,184: x2 residual
  bf16* Cx2 = Cx + 9437184;                 // 9,437,184: x2T [m][t][c] (if useT)
  const size_t kOff = S, vOff = 2*S;
  bf16* Wcv  = A2;
  bf16* Wcv2 = Bq;

  k_detect<<<1, 64, 0, stream>>>(x, flag);

  for (int n0 = 0; n0 < 32; n0 += NCH){
    k_gn_s       <<<dim3(32, NCH),   256, 0, stream>>>(x, nsw, nsb, A, flag, n0);
    k_cvtw       <<<dim3(768),       256, 0, stream>>>(qsw, Wcv, 196608, flag);
    k_gemm_qkv   <<<dim3(NCH*54),    256, 0, stream>>>(A, Wcv, qsb, Bq, flag, kOff, vOff, 0);
    k_attn_s_mfma<<<dim3(72*NCH),    256, 0, stream>>>(Bq, A2, kOff, vOff);
    // proj_s weight pre-convert into Bq (qkv dead after attn_s)
    k_cvtw       <<<dim3(256),       256, 0, stream>>>(psw, Bq, 65536, flag);
    k_proj_s_mfma<<<dim3(4, 9, NCH), 256, 0, stream>>>(A2, Bq, psb, x, Cx, Cx2, useT, flag, n0);
  }
  for (int m0 = 0; m0 < 1152; m0 += MCH){
    if (useT) k_gn_t2<<<dim3(MCH),   256, 0, stream>>>(Cx2, ntw, ntb, A, flag, m0);
    else      k_gn_t <<<dim3(MCH),   256, 0, stream>>>(Cx,  ntw, ntb, A, flag, m0);
    k_cvtw       <<<dim3(768),       256, 0, stream>>>(qtw, Wcv, 196608, flag);
    k_gemm_qkv   <<<dim3((MCH/2)*3), 256, 0, stream>>>(A, Wcv, qtb, Bq, flag, 0, 0, 1);
    k_attn_t     <<<dim3(8, MCH),    256, 0, stream>>>(Bq, rpk, rpv, A2, flag);
    k_cvtw       <<<dim3(256),       256, 0, stream>>>(ptw, Wcv2, 65536, flag);
    k_proj_t_mfma<<<dim3(4, 8, MCH/32), 256, 0, stream>>>(A2, Wcv2, ptb, Cx, d_out, flag, m0);
  }
}

// Round 13
// 429.938 us; speedup vs baseline: 1.1910x; 1.0670x over previous
//
#include <hip/hip_runtime.h>
#include <hip/hip_bf16.h>

typedef __hip_bfloat16 bf16;
typedef __attribute__((ext_vector_type(8))) short v8s;
typedef __attribute__((ext_vector_type(4))) float v4f;

__device__ __forceinline__ float b2f(bf16 v){ return __bfloat162float(v); }
__device__ __forceinline__ bf16  f2b(float v){ return __float2bfloat16(v); }

// Inputs may be bf16 OR f32 — runtime-detected flag (1 => f32). Output dtype follows.
__device__ __forceinline__ float ldin(const void* p, int i, bool f32in){
  return f32in ? ((const float*)p)[i] : b2f(((const bf16*)p)[i]);
}

// stage 4 consecutive source elems (f32-or-bf16) into dst as bf16 (8B write)
__device__ __forceinline__ void stage4(const void* src, size_t off, bool f32in, bf16* dst){
  union { bf16 h[4]; ushort4 u; } tmp;
  if (f32in){
    float4 f = *(const float4*)((const float*)src + off);
    tmp.h[0] = f2b(f.x); tmp.h[1] = f2b(f.y); tmp.h[2] = f2b(f.z); tmp.h[3] = f2b(f.w);
  } else {
    tmp.u = *(const ushort4*)((const ushort*)src + off);
  }
  *(ushort4*)dst = tmp.u;
}
__device__ __forceinline__ void stage4b(const bf16* src, bf16* dst){
  *(ushort4*)dst = *(const ushort4*)src;
}

// async global->LDS, 16B per lane. LDS dest must be wave-uniform base (HW adds lane*16).
__device__ __forceinline__ void async_cp16(const bf16* g, bf16* l){
  __builtin_amdgcn_global_load_lds(
      (const __attribute__((address_space(1))) unsigned int*)g,
      (__attribute__((address_space(3))) unsigned int*)l, 16, 0, 0);
}

// Problem: B=2, C=512, T=16, H=W=24, heads=8, ch=64
// ws: flag | A (S) | A2 (S) | Bq (3S) | Cx 9,437,184 | [Cx2 9,437,184 if room]
// R1: proj_s epilogue request-bound -> LDS-transpose epilogue (WIN, -58us).
// R2: qkv GEMMs -> unified 128x128 global_load_lds GEMM.
// R3: XOR-swizzle via pre-swizzled global source + swizzled ds_read (conflict=0).
// R4: attn_s setprio bundle FAILED; R6 conditional max-reduce + ones-MFMA WIN (-19us).
// R8: attn_t staging vectorized (WIN, -24us).
// R9: gemm_qkv LDS-staged C-tile epilogue + 16B stores (WIN, -10us; left top-5).
// R12: profile flat, attn_s top (60.7us, VALU 55% — VALU-bound). Apply proven
//      patterns to siblings: proj_t gets R1-style LDS epilogue (was 32 scalar
//      2B stores + 32 scalar x2 loads/thread); gn_s gets vectorized loads,
//      [cg][577] LDS layout (float4 conflict-free writes), gw/gb preload,
//      v8s output stores.

// ---------------------------------------------------------------- detect input dtype
__global__ void k_detect(const void* x, int* flag){
  int tid = threadIdx.x;
  const bf16* p = (const bf16*)x;
  int cnt = 0;
  for (int i = tid; i < 512; i += 64){
    float v = b2f(p[i]);
    if (!(fabsf(v) <= 64.f)) cnt++;
  }
  #pragma unroll
  for (int off = 32; off; off >>= 1) cnt += __shfl_down(cnt, off, 64);
  if (tid == 0) flag[0] = (cnt > 16) ? 1 : 0;
}

// ---------------------------------------------------------------- weight convert -> bf16 scratch
__global__ __launch_bounds__(256) void k_cvtw(const void* __restrict__ W,
        bf16* __restrict__ out, int n4, const int* __restrict__ flag){
  const bool f32in = flag[0] != 0;
  int i = blockIdx.x*256 + threadIdx.x;
  if (i < n4) stage4(W, (size_t)i*4, f32in, out + (size_t)i*4);
}

// ---------------------------------------------------------------- K1: spatial groupnorm -> xnT [l][c]
// R12: vectorized loads, xs[cg][577] (float4 LDS writes conflict-free),
// gw/gb preload, v8s output stores.
__global__ __launch_bounds__(256) void k_gn_s(const void* __restrict__ x,
        const void* __restrict__ gw, const void* __restrict__ gb,
        bf16* __restrict__ xnT, const int* __restrict__ flag, int n0){
  const bool f32in = flag[0] != 0;
  const int g = blockIdx.x;
  const int nl = blockIdx.y;
  const int n = n0 + nl;
  const int b = n >> 4, t = n & 15;
  const int tid = threadIdx.x;
  __shared__ float xs[16*577];     // [cg][l] padded
  __shared__ float red[4][2];
  __shared__ float stats[2];
  __shared__ float sgw[16], sgb[16];
  if (tid < 16){
    sgw[tid] = ldin(gw, g*16 + tid, f32in);
    sgb[tid] = ldin(gb, g*16 + tid, f32in);
  }
  float s = 0.f, q = 0.f;
  #pragma unroll
  for (int p = 0; p < 9; ++p){
    int j = tid + p*256;                 // 2304 chunks of 4 along l
    int cg = j / 144, lc = (j - cg*144)*4;
    int c = g*16 + cg;
    size_t base = ((size_t)(b*512 + c)*16 + t)*576 + lc;
    float4 f;
    if (f32in){
      f = *(const float4*)((const float*)x + base);
    } else {
      union { bf16 h[4]; ushort4 u; } uu;
      uu.u = *(const ushort4*)((const bf16*)x + base);
      f.x = b2f(uu.h[0]); f.y = b2f(uu.h[1]); f.z = b2f(uu.h[2]); f.w = b2f(uu.h[3]);
    }
    *(float4*)&xs[cg*577 + lc] = f;
    s += f.x + f.y + f.z + f.w;
    q += f.x*f.x + f.y*f.y + f.z*f.z + f.w*f.w;
  }
  #pragma unroll
  for (int off = 32; off; off >>= 1){ s += __shfl_down(s, off, 64); q += __shfl_down(q, off, 64); }
  int wid = tid >> 6;
  if ((tid & 63) == 0){ red[wid][0] = s; red[wid][1] = q; }
  __syncthreads();
  if (tid == 0){
    float S = red[0][0]+red[1][0]+red[2][0]+red[3][0];
    float Q = red[0][1]+red[1][1]+red[2][1]+red[3][1];
    float mean = S * (1.f/9216.f);
    float var  = Q * (1.f/9216.f) - mean*mean;
    stats[0] = mean; stats[1] = rsqrtf(fmaxf(var, 0.f) + 1e-5f);
  }
  __syncthreads();
  float mean = stats[0], rstd = stats[1];
  // output: 1152 chunks of 8 consecutive c at fixed l -> 16B stores
  for (int j = tid; j < 1152; j += 256){
    int l = j >> 1, c8 = (j & 1)*8;
    union { bf16 h[8]; v8s v; } o;
    #pragma unroll
    for (int e = 0; e < 8; ++e){
      int cg = c8 + e;
      o.h[e] = f2b((xs[cg*577 + l] - mean)*rstd*sgw[cg] + sgb[cg]);
    }
    *(v8s*)&xnT[(size_t)(nl*576 + l)*512 + g*16 + c8] = o.v;
  }
}

// ---------------------------------------------------------------- K2/K6: unified qkv GEMM
// Xf: flat [R][512] bf16. Wb: [1536][512] bf16. 128x128 tile, BK=64,
// global_load_lds staging into linear LDS; slot^=(row&7) XOR swizzle via
// pre-swizzled global source + swizzled ds_read (T2 / rule #21).
// R9: LDS-staged C-tile epilogue with 16B contiguous stores.
// mode 0: spatial (Q/K [l][512] + V [c][576] per nl); mode 1: temporal [m][o][t].
__global__ __launch_bounds__(256) void k_gemm_qkv(const bf16* __restrict__ Xf,
        const bf16* __restrict__ Wb, const void* __restrict__ Bv,
        bf16* __restrict__ Y, const int* __restrict__ flag,
        size_t kOff, size_t vOff, int mode){
  const bool f32in = flag[0] != 0;
  const int nwg = gridDim.x;
  const int bid = blockIdx.x;
  const int g = (bid & 7)*(nwg >> 3) + (bid >> 3);   // chunked XCD swizzle (nwg%8==0)
  const int mt = g / 12, nt = g - mt*12;
  const int r0 = mt*128, o0 = nt*128;
  const int tid = threadIdx.x, lane = tid & 63, w = tid >> 6;
  const int wm = w & 1, wn = w >> 1;
  const int r15 = lane & 15, quad = lane >> 4;
  const int rsw = r15 & 7;                 // read-side swizzle key (row&7 == r15&7)
  __shared__ bf16 LB[16384];               // As=LB[0..8191], Bs=LB[8192..]; C-tile after loop
  bf16* As = LB;
  bf16* Bs = LB + 8192;
  v4f acc[4][4];
  #pragma unroll
  for (int i = 0; i < 4; ++i)
    #pragma unroll
    for (int j = 0; j < 4; ++j) acc[i][j] = (v4f){0.f,0.f,0.f,0.f};
  for (int kc = 0; kc < 512; kc += 64){
    __syncthreads();
    #pragma unroll
    for (int r = 0; r < 4; ++r){
      int d = (tid + 256*r)*8;             // linear LDS elem offset this lane fills
      int row = d >> 6;
      int slot = (d >> 3) & 7;             // 16B slot within the 128B row
      int col = ((slot ^ (row & 7)) * 8);  // inverse-swizzled source column
      async_cp16(&Xf[(size_t)(r0 + row)*512 + kc + col], As + r*2048 + w*512);
      async_cp16(&Wb[(size_t)(o0 + row)*512 + kc + col], Bs + r*2048 + w*512);
    }
    __syncthreads();                        // compiler drains vmcnt(0) before barrier
    #pragma unroll
    for (int ks = 0; ks < 2; ++ks){
      v8s a[4], b[4];
      #pragma unroll
      for (int mi = 0; mi < 4; ++mi)
        a[mi] = *(const v8s*)&As[(wm*64 + mi*16 + r15)*64 + (((ks*4 + quad) ^ rsw)*8)];
      #pragma unroll
      for (int ni = 0; ni < 4; ++ni)
        b[ni] = *(const v8s*)&Bs[(wn*64 + ni*16 + r15)*64 + (((ks*4 + quad) ^ rsw)*8)];
      #pragma unroll
      for (int mi = 0; mi < 4; ++mi)
        #pragma unroll
        for (int ni = 0; ni < 4; ++ni)
          acc[mi][ni] = __builtin_amdgcn_mfma_f32_16x16x32_bf16(a[mi], b[ni], acc[mi][ni], 0, 0, 0);
    }
  }
  // ---- R9 epilogue: stage acc+bias into LB as [r=128][c=128], then 16B stores
  __syncthreads();
  #pragma unroll
  for (int ni = 0; ni < 4; ++ni){
    int crel = wn*64 + ni*16 + r15;
    float bia = ldin(Bv, o0 + crel, f32in);
    #pragma unroll
    for (int mi = 0; mi < 4; ++mi){
      int rb = wm*64 + mi*16 + quad*4;
      #pragma unroll
      for (int rg = 0; rg < 4; ++rg)
        LB[(rb + rg)*128 + crel] = f2b(acc[mi][ni][rg] + bia);
    }
  }
  __syncthreads();
  if (mode == 0){
    const int seg = o0 >> 9, ob = o0 & 511;
    const size_t segb = (seg==0) ? 0 : (seg==1) ? kOff : vOff;
    if (seg < 2){
      // Q/K [l][512]: chunk = 8 consecutive oseg at fixed row
      for (int i = tid; i < 2048; i += 256){
        int r = i >> 4, c8 = (i & 15)*8;
        v8s v = *(const v8s*)&LB[r*128 + c8];
        int rr = r0 + r;
        int nl = rr / 576, l = rr - nl*576;
        *(v8s*)&Y[segb + (size_t)nl*294912 + (size_t)l*512 + ob + c8] = v;
      }
    } else {
      // V [c][576]: chunk = 8 consecutive rows (l) at fixed col; lanes c-major
      for (int i = tid; i < 2048; i += 256){
        int c = i & 127, rb = (i >> 7)*8;   // rows rb..rb+7 (576%8==0 -> no nl split)
        union { bf16 h[8]; v8s v; } u;
        #pragma unroll
        for (int e = 0; e < 8; ++e) u.h[e] = LB[(rb + e)*128 + c];
        int rr = r0 + rb;
        int nl = rr / 576, l = rr - nl*576;
        *(v8s*)&Y[segb + (size_t)nl*294912 + (size_t)(ob + c)*576 + l] = u.v;
      }
    }
  } else {
    // temporal [m][o][t]: chunk = 8 consecutive t at fixed (m, o); lanes c-major
    const int m0b = r0 >> 4;
    for (int i = tid; i < 2048; i += 256){
      int c = i & 127, rh = i >> 7;
      int mloc = rh >> 1, t0 = (rh & 1)*8;
      union { bf16 h[8]; v8s v; } u;
      #pragma unroll
      for (int e = 0; e < 8; ++e) u.h[e] = LB[(mloc*16 + t0 + e)*128 + c];
      *(v8s*)&Y[((size_t)(m0b + mloc)*1536 + o0 + c)*16 + t0] = u.v;
    }
  }
}

// ---------------------------------------------------------------- K3: spatial attention (flash MFMA) -> attT [l][c]
// R6: conditional max-reduce + ones-MFMA row-sum (no psum shfl); no setprio.
__global__ __launch_bounds__(256, 4) void k_attn_s_mfma(const bf16* __restrict__ qkv,
        bf16* __restrict__ attT, size_t kOff, size_t vOff){
  const int bid = blockIdx.x;
  const int xcd = bid & 7, slot = bid >> 3;
  const int nl = xcd + 8*(slot/72);
  const int idx = slot - 72*(slot/72);
  const int head = idx/9, t0 = idx - 9*head;
  const int tid = threadIdx.x, lane = tid & 63, w = tid >> 6;
  const int r15 = lane & 15, quad = lane >> 4;
  __shared__ bf16 Ks[64*72];
  __shared__ bf16 Vs[64*72];
  __shared__ bf16 Ps[4][16*72];
  const bf16* QT = qkv + (size_t)nl*294912;
  const bf16* KT = qkv + kOff + (size_t)nl*294912;
  const bf16* Vp = qkv + vOff + (size_t)nl*294912;
  const int c0 = head*64;
  v8s aq0, aq1;
  {
    const bf16* qrow = QT + (size_t)(t0*64 + w*16 + r15)*512 + c0;
    aq0 = *(const v8s*)(qrow + quad*8);
    aq1 = *(const v8s*)(qrow + 32 + quad*8);
  }
  // ones B-fragment for row-sum MFMA
  v8s bones;
  {
    union { bf16 h[8]; v8s v; } ob;
    #pragma unroll
    for (int j = 0; j < 8; ++j) ob.h[j] = f2b(1.f);
    bones = ob.v;
  }
  // staging geometry (reg prefetch)
  int srow[4], scol[4];
  #pragma unroll
  for (int r = 0; r < 4; ++r){
    int e4 = (tid + 256*r)*4;
    srow[r] = e4 >> 6; scol[r] = e4 & 63;
  }
  ushort4 kreg[4], vreg[4];
  #pragma unroll
  for (int r = 0; r < 4; ++r){
    kreg[r] = *(const ushort4*)&KT[(size_t)srow[r]*512 + c0 + scol[r]];
    vreg[r] = *(const ushort4*)&Vp[(size_t)(c0 + srow[r])*576 + scol[r]];
  }
  v4f oc[4];
  v4f oc2 = (v4f){0.f,0.f,0.f,0.f};         // row-sum accumulator (l_run)
  #pragma unroll
  for (int ni = 0; ni < 4; ++ni) oc[ni] = (v4f){0.f,0.f,0.f,0.f};
  float m_run[4] = {-1e30f,-1e30f,-1e30f,-1e30f};
  const float SC = 0.180336880f;            // 0.125 * log2(e): exp2 domain
  for (int sc = 0; sc < 9; ++sc){
    __syncthreads();
    #pragma unroll
    for (int r = 0; r < 4; ++r){
      *(ushort4*)&Ks[srow[r]*72 + scol[r]] = kreg[r];
      *(ushort4*)&Vs[srow[r]*72 + scol[r]] = vreg[r];
    }
    __syncthreads();
    if (sc < 8){                            // prefetch next tile under compute
      #pragma unroll
      for (int r = 0; r < 4; ++r){
        kreg[r] = *(const ushort4*)&KT[(size_t)((sc+1)*64 + srow[r])*512 + c0 + scol[r]];
        vreg[r] = *(const ushort4*)&Vp[(size_t)(c0 + srow[r])*576 + (sc+1)*64 + scol[r]];
      }
    }
    v4f sa[4];
    #pragma unroll
    for (int sj = 0; sj < 4; ++sj) sa[sj] = (v4f){0.f,0.f,0.f,0.f};
    #pragma unroll
    for (int sj = 0; sj < 4; ++sj){
      v8s b0 = *(const v8s*)&Ks[(sj*16 + r15)*72 + quad*8];
      v8s b1 = *(const v8s*)&Ks[(sj*16 + r15)*72 + 32 + quad*8];
      sa[sj] = __builtin_amdgcn_mfma_f32_16x16x32_bf16(aq0, b0, sa[sj], 0, 0, 0);
      sa[sj] = __builtin_amdgcn_mfma_f32_16x16x32_bf16(aq1, b1, sa[sj], 0, 0, 0);
    }
    // per-lane partial max per row-group (over this lane's 4 cols)
    float cmx[4] = {-1e30f,-1e30f,-1e30f,-1e30f};
    #pragma unroll
    for (int sj = 0; sj < 4; ++sj)
      #pragma unroll
      for (int rg = 0; rg < 4; ++rg){
        float v = sa[sj][rg]*SC;
        sa[sj][rg] = v;
        cmx[rg] = fmaxf(cmx[rg], v);
      }
    // defer-max: if no lane's PARTIAL exceeds m+8, true rowmax <= m+8 -> P <= 2^8, skip reduce
    float grow = fmaxf(fmaxf(cmx[0]-m_run[0], cmx[1]-m_run[1]),
                       fmaxf(cmx[2]-m_run[2], cmx[3]-m_run[3]));
    if (__any(grow > 8.f)){
      #pragma unroll
      for (int off = 1; off < 16; off <<= 1)
        #pragma unroll
        for (int rg = 0; rg < 4; ++rg) cmx[rg] = fmaxf(cmx[rg], __shfl_xor(cmx[rg], off, 64));
      #pragma unroll
      for (int rg = 0; rg < 4; ++rg){
        float mnew = fmaxf(m_run[rg], cmx[rg]);
        float al = exp2f(m_run[rg] - mnew);
        m_run[rg] = mnew;
        oc2[rg] *= al;
        #pragma unroll
        for (int ni = 0; ni < 4; ++ni) oc[ni][rg] *= al;
      }
    }
    #pragma unroll
    for (int sj = 0; sj < 4; ++sj)
      #pragma unroll
      for (int rg = 0; rg < 4; ++rg)
        Ps[w][(quad*4 + rg)*72 + sj*16 + r15] = f2b(exp2f(sa[sj][rg] - m_run[rg]));
    #pragma unroll
    for (int ks = 0; ks < 2; ++ks){
      v8s a = *(const v8s*)&Ps[w][r15*72 + ks*32 + quad*8];
      #pragma unroll
      for (int ni = 0; ni < 4; ++ni){
        v8s b = *(const v8s*)&Vs[(ni*16 + r15)*72 + ks*32 + quad*8];
        oc[ni] = __builtin_amdgcn_mfma_f32_16x16x32_bf16(a, b, oc[ni], 0, 0, 0);
      }
      oc2 = __builtin_amdgcn_mfma_f32_16x16x32_bf16(a, bones, oc2, 0, 0, 0);  // row-sum
    }
  }
  float inv[4];
  #pragma unroll
  for (int rg = 0; rg < 4; ++rg) inv[rg] = 1.f / oc2[rg];
  #pragma unroll
  for (int ni = 0; ni < 4; ++ni)
    #pragma unroll
    for (int rg = 0; rg < 4; ++rg){
      int t = t0*64 + w*16 + quad*4 + rg;
      attT[(size_t)(nl*576 + t)*512 + c0 + ni*16 + r15] = f2b(oc[ni][rg]*inv[rg]);
    }
}

// ---------------------------------------------------------------- K4: spatial proj + residual (MFMA)
// R1: LDS-transpose epilogue with coalesced 16B stores (x2 and x2T).
__global__ __launch_bounds__(256) void k_proj_s_mfma(const bf16* __restrict__ AT,
        const bf16* __restrict__ Wb, const void* __restrict__ Bv,
        const void* __restrict__ xin, bf16* __restrict__ x2,
        bf16* __restrict__ x2T, int doT,
        const int* __restrict__ flag, int n0){
  const bool f32in = flag[0] != 0;
  const int o0 = blockIdx.x * 128;
  const int l0 = blockIdx.y * 64;
  const int nl = blockIdx.z;
  const int n = n0 + nl;
  const int b = n >> 4, t = n & 15;
  const int tid = threadIdx.x, lane = tid & 63;
  const int wm = (tid >> 6) & 1, wn = tid >> 7;
  const int r15 = lane & 15, quad = lane >> 4;
  __shared__ bf16 As[128*72];
  __shared__ bf16 Bs[64*72];
  v4f acc[4][2];
  #pragma unroll
  for (int i = 0; i < 4; ++i)
    #pragma unroll
    for (int j = 0; j < 2; ++j) acc[i][j] = (v4f){0.f,0.f,0.f,0.f};
  for (int kc = 0; kc < 512; kc += 64){
    __syncthreads();
    #pragma unroll
    for (int r = 0; r < 8; ++r){
      int e4 = (tid + 256*r)*4;
      int row = e4 >> 6, k = e4 & 63;
      stage4b(&Wb[(size_t)(o0+row)*512 + kc + k], &As[row*72 + k]);
    }
    #pragma unroll
    for (int r = 0; r < 4; ++r){
      int e4 = (tid + 256*r)*4;
      int row = e4 >> 6, k = e4 & 63;
      stage4b(&AT[(size_t)(nl*576 + l0 + row)*512 + kc + k], &Bs[row*72 + k]);
    }
    __syncthreads();
    #pragma unroll
    for (int ks = 0; ks < 2; ++ks){
      v8s a[4], b[2];
      #pragma unroll
      for (int mi = 0; mi < 4; ++mi)
        a[mi] = *(const v8s*)&As[(wm*64 + mi*16 + r15)*72 + ks*32 + quad*8];
      #pragma unroll
      for (int ni = 0; ni < 2; ++ni)
        b[ni] = *(const v8s*)&Bs[(wn*32 + ni*16 + r15)*72 + ks*32 + quad*8];
      #pragma unroll
      for (int mi = 0; mi < 4; ++mi)
        #pragma unroll
        for (int ni = 0; ni < 2; ++ni)
          acc[mi][ni] = __builtin_amdgcn_mfma_f32_16x16x32_bf16(a[mi], b[ni], acc[mi][ni], 0, 0, 0);
    }
  }
  // -------- epilogue: stage acc+bias into As as [o_rel][l_rel] (stride 72)
  __syncthreads();
  #pragma unroll
  for (int mi = 0; mi < 4; ++mi){
    int orel = wm*64 + mi*16 + quad*4;
    #pragma unroll
    for (int rg = 0; rg < 4; ++rg){
      float bia = ldin(Bv, o0 + orel + rg, f32in);
      #pragma unroll
      for (int ni = 0; ni < 2; ++ni)
        As[(orel + rg)*72 + wn*32 + ni*16 + r15] = f2b(acc[mi][ni][rg] + bia);
    }
  }
  __syncthreads();
  // phase 1: residual add + coalesced x2 write (+writeback for phase 2)
  const size_t xrow = ((size_t)(b*512 + o0)*16 + t)*576 + l0;
  for (int it = 0; it < 4; ++it){
    int idx = tid + it*256;             // 1024 chunks of 8 elems
    int o = idx >> 3, lc = (idx & 7)*8;
    union { bf16 h[8]; v8s v; } val;
    val.v = *(const v8s*)&As[o*72 + lc];
    size_t ga = xrow + (size_t)o*9216 + lc;
    if (f32in){
      const float* xp = (const float*)xin + ga;
      float4 f0 = *(const float4*)xp;
      float4 f1 = *(const float4*)(xp + 4);
      val.h[0] = f2b(b2f(val.h[0]) + f0.x);
      val.h[1] = f2b(b2f(val.h[1]) + f0.y);
      val.h[2] = f2b(b2f(val.h[2]) + f0.z);
      val.h[3] = f2b(b2f(val.h[3]) + f0.w);
      val.h[4] = f2b(b2f(val.h[4]) + f1.x);
      val.h[5] = f2b(b2f(val.h[5]) + f1.y);
      val.h[6] = f2b(b2f(val.h[6]) + f1.z);
      val.h[7] = f2b(b2f(val.h[7]) + f1.w);
    } else {
      union { bf16 h[8]; v8s v; } xv;
      xv.v = *(const v8s*)((const bf16*)xin + ga);
      #pragma unroll
      for (int j = 0; j < 8; ++j) val.h[j] = f2b(b2f(val.h[j]) + b2f(xv.h[j]));
    }
    *(v8s*)&x2[ga] = val.v;
    if (doT) *(v8s*)&As[o*72 + lc] = val.v;
  }
  if (doT){
    __syncthreads();
    // phase 2: x2T [m][t][c]: per chunk, 8 consecutive o at fixed l
    const size_t tbase = ((size_t)b*576 + l0)*8192 + (size_t)t*512 + o0;
    for (int it = 0; it < 4; ++it){
      int l = (tid & 15) + it*16;
      int ocg = (tid >> 4)*8;
      union { bf16 h[8]; v8s v; } val;
      #pragma unroll
      for (int j = 0; j < 8; ++j) val.h[j] = As[(ocg + j)*72 + l];
      *(v8s*)&x2T[tbase + (size_t)l*8192 + ocg] = val.v;
    }
  }
}

// ---------------------------------------------------------------- K5a: temporal groupnorm (scattered x2) -> xnT [m][t][c]
__global__ __launch_bounds__(256) void k_gn_t(const bf16* __restrict__ x2,
        const void* __restrict__ gw, const void* __restrict__ gb,
        bf16* __restrict__ xnT, const int* __restrict__ flag, int m0){
  const bool f32in = flag[0] != 0;
  const int ml = blockIdx.x;
  const int m = m0 + ml;
  const int b = m / 576, l = m - b*576;
  const int tid = threadIdx.x;
  __shared__ float xs[8192];
  __shared__ float mg[32], rg[32];
  for (int i = tid; i < 8192; i += 256){
    int t = i >> 9, c = i & 511;
    xs[i] = b2f(x2[((b*512 + c)*16 + t)*576 + l]);
  }
  __syncthreads();
  {
    int g = tid >> 3, ii = tid & 7;
    float s = 0.f, q = 0.f;
    for (int idx = ii; idx < 256; idx += 8){
      int t = idx >> 4, cg = idx & 15;
      float v = xs[t*512 + g*16 + cg]; s += v; q += v*v;
    }
    #pragma unroll
    for (int off = 1; off < 8; off <<= 1){ s += __shfl_xor(s, off, 64); q += __shfl_xor(q, off, 64); }
    if (ii == 0){
      float mean = s*(1.f/256.f);
      float var  = q*(1.f/256.f) - mean*mean;
      mg[g] = mean; rg[g] = rsqrtf(fmaxf(var, 0.f) + 1e-5f);
    }
  }
  __syncthreads();
  for (int i = tid; i < 8192; i += 256){
    int c = i & 511, g = c >> 4;
    xnT[(size_t)ml*8192 + i] = f2b((xs[i] - mg[g])*rg[g]*ldin(gw, c, f32in) + ldin(gb, c, f32in));
  }
}

// ---------------------------------------------------------------- K5b: temporal groupnorm (coalesced x2T)
__global__ __launch_bounds__(256) void k_gn_t2(const bf16* __restrict__ x2T,
        const void* __restrict__ gw, const void* __restrict__ gb,
        bf16* __restrict__ xnT, const int* __restrict__ flag, int m0){
  const bool f32in = flag[0] != 0;
  const int ml = blockIdx.x;
  const int m = m0 + ml;
  const int tid = threadIdx.x;
  __shared__ float xs[8192];
  __shared__ float mg[32], rg[32];
  for (int i = tid; i < 8192; i += 256)
    xs[i] = b2f(x2T[(size_t)m*8192 + i]);     // [t][c] order, fully coalesced
  __syncthreads();
  {
    int g = tid >> 3, ii = tid & 7;
    float s = 0.f, q = 0.f;
    for (int idx = ii; idx < 256; idx += 8){
      int t = idx >> 4, cg = idx & 15;
      float v = xs[t*512 + g*16 + cg]; s += v; q += v*v;
    }
    #pragma unroll
    for (int off = 1; off < 8; off <<= 1){ s += __shfl_xor(s, off, 64); q += __shfl_xor(q, off, 64); }
    if (ii == 0){
      float mean = s*(1.f/256.f);
      float var  = q*(1.f/256.f) - mean*mean;
      mg[g] = mean; rg[g] = rsqrtf(fmaxf(var, 0.f) + 1e-5f);
    }
  }
  __syncthreads();
  for (int i = tid; i < 8192; i += 256){
    int c = i & 511, g = c >> 4;
    xnT[(size_t)ml*8192 + i] = f2b((xs[i] - mg[g])*rg[g]*ldin(gw, c, f32in) + ldin(gb, c, f32in));
  }
}

// ---------------------------------------------------------------- K7: temporal attention -> attT [m][t][c]
// R8: vectorized staging — qkv via v8s (8 consecutive t, one c), tables via
// float4 (f32) / v8s+cvt (bf16) with contiguous float4 LDS writes.
__global__ __launch_bounds__(256) void k_attn_t(const bf16* __restrict__ qkv,
        const void* __restrict__ tbk, const void* __restrict__ tbv,
        bf16* __restrict__ attT, const int* __restrict__ flag){
  const bool f32in = flag[0] != 0;
  const int head = blockIdx.x;
  const int ml = blockIdx.y;
  const int tid = threadIdx.x;
  __shared__ float qsT[16*68], ksT[16*68], vsT[16*68];  // [t][c], stride 68 (16B-aligned rows)
  __shared__ float tks[33*68], tvs[33*68];              // [d][c]
  __shared__ float ps[16*17];
  const int base = (ml*1536 + head*64)*16;
  // ---- qkv staging: 3 arrays x 128 v8s-chunks (chunk = 8 consecutive t, one c)
  for (int j = tid; j < 384; j += 256){
    int arr = j >> 7, cj = j & 127;
    int c = cj >> 1, t0 = (cj & 1)*8;
    union { bf16 h[8]; v8s v; } u;
    u.v = *(const v8s*)(qkv + base + arr*8192 + c*16 + t0);
    float* dst = (arr == 0) ? qsT : (arr == 1) ? ksT : vsT;
    #pragma unroll
    for (int e = 0; e < 8; ++e) dst[(t0 + e)*68 + c] = b2f(u.h[e]);
  }
  // ---- table staging: 33x64 each; contiguous-in-c chunks -> float4 LDS writes
  if (f32in){
    for (int j = tid; j < 1056; j += 256){
      int tb = (j >= 528) ? 1 : 0;
      int cj = j - tb*528;
      int d = cj >> 4, c = (cj & 15)*4;
      float4 v = *(const float4*)((const float*)(tb ? tbv : tbk) + d*64 + c);
      *(float4*)&((tb ? tvs : tks)[d*68 + c]) = v;
    }
  } else {
    for (int j = tid; j < 528; j += 256){
      int tb = (j >= 264) ? 1 : 0;
      int cj = j - tb*264;
      int d = cj >> 3, c = (cj & 7)*8;
      union { bf16 h[8]; v8s v; } u;
      u.v = *(const v8s*)((const bf16*)(tb ? tbv : tbk) + d*64 + c);
      float* dst = (tb ? tvs : tks) + d*68 + c;
      float4 f0 = {b2f(u.h[0]), b2f(u.h[1]), b2f(u.h[2]), b2f(u.h[3])};
      float4 f1 = {b2f(u.h[4]), b2f(u.h[5]), b2f(u.h[6]), b2f(u.h[7])};
      *(float4*)dst = f0;
      *(float4*)(dst + 4) = f1;
    }
  }
  __syncthreads();
  {
    const int t = tid >> 4, s = tid & 15;
    const float4* qt = (const float4*)&qsT[t*68];
    const float4* kr = (const float4*)&ksT[s*68];
    const float4* q2 = (const float4*)&qsT[s*68];
    const float4* tr = (const float4*)&tks[(t - s + 16)*68];
    float qk = 0.f, rp = 0.f;
    #pragma unroll
    for (int c4 = 0; c4 < 16; ++c4){
      float4 a = qt[c4], b = kr[c4];
      qk += a.x*b.x + a.y*b.y + a.z*b.z + a.w*b.w;
      float4 a2 = q2[c4], tb = tr[c4];
      rp += a2.x*tb.x + a2.y*tb.y + a2.z*tb.z + a2.w*tb.w;
    }
    float logit = 0.125f*qk + 0.35355339059327373f*rp;
    if (s > t) logit = -1e8f;
    float mx = logit;
    #pragma unroll
    for (int off = 8; off; off >>= 1) mx = fmaxf(mx, __shfl_xor(mx, off, 16));
    float e = __expf(logit - mx);
    float tot = e;
    #pragma unroll
    for (int off = 8; off; off >>= 1) tot += __shfl_xor(tot, off, 16);
    ps[t*17 + s] = e / tot;
  }
  __syncthreads();
  {
    const int c4 = tid & 15, t = tid >> 4;
    float4 acc = {0.f,0.f,0.f,0.f};
    #pragma unroll
    for (int s = 0; s < 16; ++s){
      float p = ps[t*17 + s];
      float4 v4 = *(const float4*)&vsT[s*68 + c4*4];
      float4 t4 = *(const float4*)&tvs[(s - t + 16)*68 + c4*4];
      acc.x += p*(v4.x + t4.x); acc.y += p*(v4.y + t4.y);
      acc.z += p*(v4.z + t4.z); acc.w += p*(v4.w + t4.w);
    }
    union { bf16 h[4]; ushort4 u; } o;
    o.h[0] = f2b(acc.x); o.h[1] = f2b(acc.y); o.h[2] = f2b(acc.z); o.h[3] = f2b(acc.w);
    *(ushort4*)&attT[(size_t)ml*8192 + t*512 + head*64 + c4*4] = o.u;
  }
}

// ---------------------------------------------------------------- K8: temporal proj + residual -> out (MFMA)
// R12: LDS-staged epilogue (R1 pattern): Cs[t][o][l] in As, then 8-elem chunks
// with v8s x2 loads + contiguous 16/32B stores (was 32 scalar 2B stores/thread).
__global__ __launch_bounds__(256) void k_proj_t_mfma(const bf16* __restrict__ AT,
        const bf16* __restrict__ Wb, const void* __restrict__ Bv,
        const bf16* __restrict__ x2, void* __restrict__ out,
        const int* __restrict__ flag, int m0){
  const bool f32in = flag[0] != 0;
  const int o0 = blockIdx.x * 128;
  const int tp = blockIdx.y;            // t-pair
  const int mg0 = blockIdx.z * 32;      // m base (32 | 576)
  const int tid = threadIdx.x, lane = tid & 63;
  const int wm = (tid >> 6) & 1, wn = tid >> 7;
  const int r15 = lane & 15, quad = lane >> 4;
  __shared__ bf16 As[128*72];           // W staging; Cs[2][128][36] after loop (9216 elems)
  __shared__ bf16 Bs[64*72];
  v4f acc[4][2];
  #pragma unroll
  for (int i = 0; i < 4; ++i)
    #pragma unroll
    for (int j = 0; j < 2; ++j) acc[i][j] = (v4f){0.f,0.f,0.f,0.f};
  for (int kc = 0; kc < 512; kc += 64){
    __syncthreads();
    #pragma unroll
    for (int r = 0; r < 8; ++r){
      int e4 = (tid + 256*r)*4;
      int row = e4 >> 6, k = e4 & 63;
      stage4b(&Wb[(size_t)(o0+row)*512 + kc + k], &As[row*72 + k]);
    }
    #pragma unroll
    for (int r = 0; r < 4; ++r){
      int e4 = (tid + 256*r)*4;
      int row = e4 >> 6, k = e4 & 63;
      stage4b(&AT[(size_t)(mg0 + (row & 31))*8192 + (tp*2 + (row >> 5))*512 + kc + k],
              &Bs[row*72 + k]);
    }
    __syncthreads();
    #pragma unroll
    for (int ks = 0; ks < 2; ++ks){
      v8s a[4], b[2];
      #pragma unroll
      for (int mi = 0; mi < 4; ++mi)
        a[mi] = *(const v8s*)&As[(wm*64 + mi*16 + r15)*72 + ks*32 + quad*8];
      #pragma unroll
      for (int ni = 0; ni < 2; ++ni)
        b[ni] = *(const v8s*)&Bs[(wn*32 + ni*16 + r15)*72 + ks*32 + quad*8];
      #pragma unroll
      for (int mi = 0; mi < 4; ++mi)
        #pragma unroll
        for (int ni = 0; ni < 2; ++ni)
          acc[mi][ni] = __builtin_amdgcn_mfma_f32_16x16x32_bf16(a[mi], b[ni], acc[mi][ni], 0, 0, 0);
    }
  }
  // ---- R12 epilogue: stage acc+bias as Cs[t_loc][o_rel][l_loc] (stride 36)
  __syncthreads();
  #pragma unroll
  for (int mi = 0; mi < 4; ++mi){
    int orel = wm*64 + mi*16 + quad*4;
    #pragma unroll
    for (int rg = 0; rg < 4; ++rg){
      float bia = ldin(Bv, o0 + orel + rg, f32in);
      #pragma unroll
      for (int ni = 0; ni < 2; ++ni)
        As[(wn*128 + orel + rg)*36 + ni*16 + r15] = f2b(acc[mi][ni][rg] + bia);
    }
  }
  __syncthreads();
  // store: 8192 elems in 1024 chunks of 8 consecutive l
  const int mb = m0 + mg0;
  const int bb = mb / 576;
  const int l0b = mb - bb*576;          // multiple of 32 (576%32==0)
  for (int it = 0; it < 4; ++it){
    int idx = tid + it*256;             // [0,1024)
    int l8 = (idx & 3)*8;
    int ot = idx >> 2;                  // [0,256)
    int orel = ot & 127, tl = ot >> 7;
    union { bf16 h[8]; v8s v; } cv;
    cv.v = *(const v8s*)&As[(tl*128 + orel)*36 + l8];
    size_t addr = ((size_t)(bb*512 + o0 + orel)*16 + tp*2 + tl)*576 + l0b + l8;
    union { bf16 h[8]; v8s v; } xv;
    xv.v = *(const v8s*)&x2[addr];
    if (f32in){
      float* op = (float*)out + addr;
      float4 f0, f1;
      f0.x = b2f(cv.h[0]) + b2f(xv.h[0]);
      f0.y = b2f(cv.h[1]) + b2f(xv.h[1]);
      f0.z = b2f(cv.h[2]) + b2f(xv.h[2]);
      f0.w = b2f(cv.h[3]) + b2f(xv.h[3]);
      f1.x = b2f(cv.h[4]) + b2f(xv.h[4]);
      f1.y = b2f(cv.h[5]) + b2f(xv.h[5]);
      f1.z = b2f(cv.h[6]) + b2f(xv.h[6]);
      f1.w = b2f(cv.h[7]) + b2f(xv.h[7]);
      *(float4*)op = f0;
      *(float4*)(op + 4) = f1;
    } else {
      union { bf16 h[8]; v8s v; } ov;
      #pragma unroll
      for (int j = 0; j < 8; ++j) ov.h[j] = f2b(b2f(cv.h[j]) + b2f(xv.h[j]));
      *(v8s*)((bf16*)out + addr) = ov.v;
    }
  }
}

// ----------------------------------------------------------------
extern "C" void kernel_launch(void* const* d_in, const int* in_sizes, int n_in,
                              void* d_out, int out_size, void* d_ws, size_t ws_size,
                              hipStream_t stream){
  const void* x   = d_in[0];
  const void* nsw = d_in[1];
  const void* nsb = d_in[2];
  const void* qsw = d_in[3];
  const void* qsb = d_in[4];
  const void* psw = d_in[5];
  const void* psb = d_in[6];
  const void* ntw = d_in[7];
  const void* ntb = d_in[8];
  const void* qtw = d_in[9];
  const void* qtb = d_in[10];
  const void* ptw = d_in[11];
  const void* ptb = d_in[12];
  const void* rpk = d_in[13];
  const void* rpv = d_in[14];

  // Chunking and x2T gate from ws_size (constant across calls -> graph-safe).
  const size_t S_full = (size_t)32*294912;
  const size_t need_full = 256 + (S_full*5 + 9437184)*2;
  const size_t need_T    = 256 + (S_full*5 + (size_t)2*9437184)*2;  // +18.9 MB for x2T
  const int NCH = (ws_size >= need_full) ? 32 : 8;
  const int MCH = (NCH == 32) ? 1152 : 288;
  const size_t S = (size_t)NCH*294912;
  const int useT = (NCH == 32 && ws_size >= need_T) ? 1 : 0;

  int*  flag = (int*)d_ws;
  bf16* A  = (bf16*)((char*)d_ws + 256);   // S: xnT_s / xnT_t
  bf16* A2 = A  + S;                        // S: attT_s / attT_t (+ transient W copy)
  bf16* Bq = A2 + S;                        // 3S: qkv (+ transient W copies)
  bf16* Cx = Bq + 3*S;                      // 9,437,184: x2 residual
  bf16* Cx2 = Cx + 9437184;                 // 9,437,184: x2T [m][t][c] (if useT)
  const size_t kOff = S, vOff = 2*S;
  bf16* Wcv  = A2;
  bf16* Wcv2 = Bq;

  k_detect<<<1, 64, 0, stream>>>(x, flag);

  for (int n0 = 0; n0 < 32; n0 += NCH){
    k_gn_s       <<<dim3(32, NCH),   256, 0, stream>>>(x, nsw, nsb, A, flag, n0);
    k_cvtw       <<<dim3(768),       256, 0, stream>>>(qsw, Wcv, 196608, flag);
    k_gemm_qkv   <<<dim3(NCH*54),    256, 0, stream>>>(A, Wcv, qsb, Bq, flag, kOff, vOff, 0);
    k_attn_s_mfma<<<dim3(72*NCH),    256, 0, stream>>>(Bq, A2, kOff, vOff);
    // proj_s weight pre-convert into Bq (qkv dead after attn_s)
    k_cvtw       <<<dim3(256),       256, 0, stream>>>(psw, Bq, 65536, flag);
    k_proj_s_mfma<<<dim3(4, 9, NCH), 256, 0, stream>>>(A2, Bq, psb, x, Cx, Cx2, useT, flag, n0);
  }
  for (int m0 = 0; m0 < 1152; m0 += MCH){
    if (useT) k_gn_t2<<<dim3(MCH),   256, 0, stream>>>(Cx2, ntw, ntb, A, flag, m0);
    else      k_gn_t <<<dim3(MCH),   256, 0, stream>>>(Cx,  ntw, ntb, A, flag, m0);
    k_cvtw       <<<dim3(768),       256, 0, stream>>>(qtw, Wcv, 196608, flag);
    k_gemm_qkv   <<<dim3((MCH/2)*3), 256, 0, stream>>>(A, Wcv, qtb, Bq, flag, 0, 0, 1);
    k_attn_t     <<<dim3(8, MCH),    256, 0, stream>>>(Bq, rpk, rpv, A2, flag);
    k_cvtw       <<<dim3(256),       256, 0, stream>>>(ptw, Wcv2, 65536, flag);
    k_proj_t_mfma<<<dim3(4, 8, MCH/32), 256, 0, stream>>>(A2, Wcv2, ptb, Cx, d_out, flag, m0);
  }
}

// Round 14
// 429.656 us; speedup vs baseline: 1.1918x; 1.0007x over previous
//
#include <hip/hip_runtime.h>
#include <hip/hip_bf16.h>

typedef __hip_bfloat16 bf16;
typedef __attribute__((ext_vector_type(8))) short v8s;
typedef __attribute__((ext_vector_type(4))) float v4f;

__device__ __forceinline__ float b2f(bf16 v){ return __bfloat162float(v); }
__device__ __forceinline__ bf16  f2b(float v){ return __float2bfloat16(v); }

// Inputs may be bf16 OR f32 — runtime-detected flag (1 => f32). Output dtype follows.
__device__ __forceinline__ float ldin(const void* p, int i, bool f32in){
  return f32in ? ((const float*)p)[i] : b2f(((const bf16*)p)[i]);
}

// stage 4 consecutive source elems (f32-or-bf16) into dst as bf16 (8B write)
__device__ __forceinline__ void stage4(const void* src, size_t off, bool f32in, bf16* dst){
  union { bf16 h[4]; ushort4 u; } tmp;
  if (f32in){
    float4 f = *(const float4*)((const float*)src + off);
    tmp.h[0] = f2b(f.x); tmp.h[1] = f2b(f.y); tmp.h[2] = f2b(f.z); tmp.h[3] = f2b(f.w);
  } else {
    tmp.u = *(const ushort4*)((const ushort*)src + off);
  }
  *(ushort4*)dst = tmp.u;
}
__device__ __forceinline__ void stage4b(const bf16* src, bf16* dst){
  *(ushort4*)dst = *(const ushort4*)src;
}

// async global->LDS, 16B per lane. LDS dest must be wave-uniform base (HW adds lane*16).
__device__ __forceinline__ void async_cp16(const bf16* g, bf16* l){
  __builtin_amdgcn_global_load_lds(
      (const __attribute__((address_space(1))) unsigned int*)g,
      (__attribute__((address_space(3))) unsigned int*)l, 16, 0, 0);
}

// Problem: B=2, C=512, T=16, H=W=24, heads=8, ch=64
// ws: flag | A (S) | A2 (S) | Bq (3S) | Cx 9,437,184 | [Cx2 9,437,184 if room]
// R1: proj_s epilogue request-bound -> LDS-transpose epilogue (WIN, -58us).
// R2: qkv GEMMs -> unified 128x128 global_load_lds GEMM.
// R3: XOR-swizzle via pre-swizzled global source + swizzled ds_read (conflict=0).
// R4: attn_s setprio bundle FAILED; R6 conditional max-reduce + ones-MFMA WIN (-19us).
// R8: attn_t staging vectorized (WIN, -24us).
// R9: gemm_qkv LDS-staged C-tile epilogue + 16B stores (WIN, -10us).
// R12: gn_s vectorized + proj_t LDS epilogue (WIN, -29us).
// R13: attn plateau (both ~65us, VALU 53%, ~47% stalls). Barrier amortization:
//      attn_s K/V double-buffer -> 1 barrier/iter (was 2); attn_t softmax->PV
//      barrier removed (intra-wave dep: ps row t written & read by lanes
//      [16t,16t+16) — same wave64 group).

// ---------------------------------------------------------------- detect input dtype
__global__ void k_detect(const void* x, int* flag){
  int tid = threadIdx.x;
  const bf16* p = (const bf16*)x;
  int cnt = 0;
  for (int i = tid; i < 512; i += 64){
    float v = b2f(p[i]);
    if (!(fabsf(v) <= 64.f)) cnt++;
  }
  #pragma unroll
  for (int off = 32; off; off >>= 1) cnt += __shfl_down(cnt, off, 64);
  if (tid == 0) flag[0] = (cnt > 16) ? 1 : 0;
}

// ---------------------------------------------------------------- weight convert -> bf16 scratch
__global__ __launch_bounds__(256) void k_cvtw(const void* __restrict__ W,
        bf16* __restrict__ out, int n4, const int* __restrict__ flag){
  const bool f32in = flag[0] != 0;
  int i = blockIdx.x*256 + threadIdx.x;
  if (i < n4) stage4(W, (size_t)i*4, f32in, out + (size_t)i*4);
}

// ---------------------------------------------------------------- K1: spatial groupnorm -> xnT [l][c]
// R12: vectorized loads, xs[cg][577] (float4 LDS writes conflict-free),
// gw/gb preload, v8s output stores.
__global__ __launch_bounds__(256) void k_gn_s(const void* __restrict__ x,
        const void* __restrict__ gw, const void* __restrict__ gb,
        bf16* __restrict__ xnT, const int* __restrict__ flag, int n0){
  const bool f32in = flag[0] != 0;
  const int g = blockIdx.x;
  const int nl = blockIdx.y;
  const int n = n0 + nl;
  const int b = n >> 4, t = n & 15;
  const int tid = threadIdx.x;
  __shared__ float xs[16*577];     // [cg][l] padded
  __shared__ float red[4][2];
  __shared__ float stats[2];
  __shared__ float sgw[16], sgb[16];
  if (tid < 16){
    sgw[tid] = ldin(gw, g*16 + tid, f32in);
    sgb[tid] = ldin(gb, g*16 + tid, f32in);
  }
  float s = 0.f, q = 0.f;
  #pragma unroll
  for (int p = 0; p < 9; ++p){
    int j = tid + p*256;                 // 2304 chunks of 4 along l
    int cg = j / 144, lc = (j - cg*144)*4;
    int c = g*16 + cg;
    size_t base = ((size_t)(b*512 + c)*16 + t)*576 + lc;
    float4 f;
    if (f32in){
      f = *(const float4*)((const float*)x + base);
    } else {
      union { bf16 h[4]; ushort4 u; } uu;
      uu.u = *(const ushort4*)((const bf16*)x + base);
      f.x = b2f(uu.h[0]); f.y = b2f(uu.h[1]); f.z = b2f(uu.h[2]); f.w = b2f(uu.h[3]);
    }
    *(float4*)&xs[cg*577 + lc] = f;
    s += f.x + f.y + f.z + f.w;
    q += f.x*f.x + f.y*f.y + f.z*f.z + f.w*f.w;
  }
  #pragma unroll
  for (int off = 32; off; off >>= 1){ s += __shfl_down(s, off, 64); q += __shfl_down(q, off, 64); }
  int wid = tid >> 6;
  if ((tid & 63) == 0){ red[wid][0] = s; red[wid][1] = q; }
  __syncthreads();
  if (tid == 0){
    float S = red[0][0]+red[1][0]+red[2][0]+red[3][0];
    float Q = red[0][1]+red[1][1]+red[2][1]+red[3][1];
    float mean = S * (1.f/9216.f);
    float var  = Q * (1.f/9216.f) - mean*mean;
    stats[0] = mean; stats[1] = rsqrtf(fmaxf(var, 0.f) + 1e-5f);
  }
  __syncthreads();
  float mean = stats[0], rstd = stats[1];
  // output: 1152 chunks of 8 consecutive c at fixed l -> 16B stores
  for (int j = tid; j < 1152; j += 256){
    int l = j >> 1, c8 = (j & 1)*8;
    union { bf16 h[8]; v8s v; } o;
    #pragma unroll
    for (int e = 0; e < 8; ++e){
      int cg = c8 + e;
      o.h[e] = f2b((xs[cg*577 + l] - mean)*rstd*sgw[cg] + sgb[cg]);
    }
    *(v8s*)&xnT[(size_t)(nl*576 + l)*512 + g*16 + c8] = o.v;
  }
}

// ---------------------------------------------------------------- K2/K6: unified qkv GEMM
// Xf: flat [R][512] bf16. Wb: [1536][512] bf16. 128x128 tile, BK=64,
// global_load_lds staging into linear LDS; slot^=(row&7) XOR swizzle via
// pre-swizzled global source + swizzled ds_read (T2 / rule #21).
// R9: LDS-staged C-tile epilogue with 16B contiguous stores.
// mode 0: spatial (Q/K [l][512] + V [c][576] per nl); mode 1: temporal [m][o][t].
__global__ __launch_bounds__(256) void k_gemm_qkv(const bf16* __restrict__ Xf,
        const bf16* __restrict__ Wb, const void* __restrict__ Bv,
        bf16* __restrict__ Y, const int* __restrict__ flag,
        size_t kOff, size_t vOff, int mode){
  const bool f32in = flag[0] != 0;
  const int nwg = gridDim.x;
  const int bid = blockIdx.x;
  const int g = (bid & 7)*(nwg >> 3) + (bid >> 3);   // chunked XCD swizzle (nwg%8==0)
  const int mt = g / 12, nt = g - mt*12;
  const int r0 = mt*128, o0 = nt*128;
  const int tid = threadIdx.x, lane = tid & 63, w = tid >> 6;
  const int wm = w & 1, wn = w >> 1;
  const int r15 = lane & 15, quad = lane >> 4;
  const int rsw = r15 & 7;                 // read-side swizzle key (row&7 == r15&7)
  __shared__ bf16 LB[16384];               // As=LB[0..8191], Bs=LB[8192..]; C-tile after loop
  bf16* As = LB;
  bf16* Bs = LB + 8192;
  v4f acc[4][4];
  #pragma unroll
  for (int i = 0; i < 4; ++i)
    #pragma unroll
    for (int j = 0; j < 4; ++j) acc[i][j] = (v4f){0.f,0.f,0.f,0.f};
  for (int kc = 0; kc < 512; kc += 64){
    __syncthreads();
    #pragma unroll
    for (int r = 0; r < 4; ++r){
      int d = (tid + 256*r)*8;             // linear LDS elem offset this lane fills
      int row = d >> 6;
      int slot = (d >> 3) & 7;             // 16B slot within the 128B row
      int col = ((slot ^ (row & 7)) * 8);  // inverse-swizzled source column
      async_cp16(&Xf[(size_t)(r0 + row)*512 + kc + col], As + r*2048 + w*512);
      async_cp16(&Wb[(size_t)(o0 + row)*512 + kc + col], Bs + r*2048 + w*512);
    }
    __syncthreads();                        // compiler drains vmcnt(0) before barrier
    #pragma unroll
    for (int ks = 0; ks < 2; ++ks){
      v8s a[4], b[4];
      #pragma unroll
      for (int mi = 0; mi < 4; ++mi)
        a[mi] = *(const v8s*)&As[(wm*64 + mi*16 + r15)*64 + (((ks*4 + quad) ^ rsw)*8)];
      #pragma unroll
      for (int ni = 0; ni < 4; ++ni)
        b[ni] = *(const v8s*)&Bs[(wn*64 + ni*16 + r15)*64 + (((ks*4 + quad) ^ rsw)*8)];
      #pragma unroll
      for (int mi = 0; mi < 4; ++mi)
        #pragma unroll
        for (int ni = 0; ni < 4; ++ni)
          acc[mi][ni] = __builtin_amdgcn_mfma_f32_16x16x32_bf16(a[mi], b[ni], acc[mi][ni], 0, 0, 0);
    }
  }
  // ---- R9 epilogue: stage acc+bias into LB as [r=128][c=128], then 16B stores
  __syncthreads();
  #pragma unroll
  for (int ni = 0; ni < 4; ++ni){
    int crel = wn*64 + ni*16 + r15;
    float bia = ldin(Bv, o0 + crel, f32in);
    #pragma unroll
    for (int mi = 0; mi < 4; ++mi){
      int rb = wm*64 + mi*16 + quad*4;
      #pragma unroll
      for (int rg = 0; rg < 4; ++rg)
        LB[(rb + rg)*128 + crel] = f2b(acc[mi][ni][rg] + bia);
    }
  }
  __syncthreads();
  if (mode == 0){
    const int seg = o0 >> 9, ob = o0 & 511;
    const size_t segb = (seg==0) ? 0 : (seg==1) ? kOff : vOff;
    if (seg < 2){
      // Q/K [l][512]: chunk = 8 consecutive oseg at fixed row
      for (int i = tid; i < 2048; i += 256){
        int r = i >> 4, c8 = (i & 15)*8;
        v8s v = *(const v8s*)&LB[r*128 + c8];
        int rr = r0 + r;
        int nl = rr / 576, l = rr - nl*576;
        *(v8s*)&Y[segb + (size_t)nl*294912 + (size_t)l*512 + ob + c8] = v;
      }
    } else {
      // V [c][576]: chunk = 8 consecutive rows (l) at fixed col; lanes c-major
      for (int i = tid; i < 2048; i += 256){
        int c = i & 127, rb = (i >> 7)*8;   // rows rb..rb+7 (576%8==0 -> no nl split)
        union { bf16 h[8]; v8s v; } u;
        #pragma unroll
        for (int e = 0; e < 8; ++e) u.h[e] = LB[(rb + e)*128 + c];
        int rr = r0 + rb;
        int nl = rr / 576, l = rr - nl*576;
        *(v8s*)&Y[segb + (size_t)nl*294912 + (size_t)(ob + c)*576 + l] = u.v;
      }
    }
  } else {
    // temporal [m][o][t]: chunk = 8 consecutive t at fixed (m, o); lanes c-major
    const int m0b = r0 >> 4;
    for (int i = tid; i < 2048; i += 256){
      int c = i & 127, rh = i >> 7;
      int mloc = rh >> 1, t0 = (rh & 1)*8;
      union { bf16 h[8]; v8s v; } u;
      #pragma unroll
      for (int e = 0; e < 8; ++e) u.h[e] = LB[(mloc*16 + t0 + e)*128 + c];
      *(v8s*)&Y[((size_t)(m0b + mloc)*1536 + o0 + c)*16 + t0] = u.v;
    }
  }
}

// ---------------------------------------------------------------- K3: spatial attention (flash MFMA) -> attT [l][c]
// R6: conditional max-reduce + ones-MFMA row-sum; R13: K/V double-buffer,
// single barrier per KV iteration (write -> barrier -> prefetch+compute).
__global__ __launch_bounds__(256, 4) void k_attn_s_mfma(const bf16* __restrict__ qkv,
        bf16* __restrict__ attT, size_t kOff, size_t vOff){
  const int bid = blockIdx.x;
  const int xcd = bid & 7, slot = bid >> 3;
  const int nl = xcd + 8*(slot/72);
  const int idx = slot - 72*(slot/72);
  const int head = idx/9, t0 = idx - 9*head;
  const int tid = threadIdx.x, lane = tid & 63, w = tid >> 6;
  const int r15 = lane & 15, quad = lane >> 4;
  __shared__ bf16 Ks[2][64*72];
  __shared__ bf16 Vs[2][64*72];
  __shared__ bf16 Ps[4][16*72];
  const bf16* QT = qkv + (size_t)nl*294912;
  const bf16* KT = qkv + kOff + (size_t)nl*294912;
  const bf16* Vp = qkv + vOff + (size_t)nl*294912;
  const int c0 = head*64;
  v8s aq0, aq1;
  {
    const bf16* qrow = QT + (size_t)(t0*64 + w*16 + r15)*512 + c0;
    aq0 = *(const v8s*)(qrow + quad*8);
    aq1 = *(const v8s*)(qrow + 32 + quad*8);
  }
  // ones B-fragment for row-sum MFMA
  v8s bones;
  {
    union { bf16 h[8]; v8s v; } ob;
    #pragma unroll
    for (int j = 0; j < 8; ++j) ob.h[j] = f2b(1.f);
    bones = ob.v;
  }
  // staging geometry (reg prefetch)
  int srow[4], scol[4];
  #pragma unroll
  for (int r = 0; r < 4; ++r){
    int e4 = (tid + 256*r)*4;
    srow[r] = e4 >> 6; scol[r] = e4 & 63;
  }
  ushort4 kreg[4], vreg[4];
  #pragma unroll
  for (int r = 0; r < 4; ++r){
    kreg[r] = *(const ushort4*)&KT[(size_t)srow[r]*512 + c0 + scol[r]];
    vreg[r] = *(const ushort4*)&Vp[(size_t)(c0 + srow[r])*576 + scol[r]];
  }
  v4f oc[4];
  v4f oc2 = (v4f){0.f,0.f,0.f,0.f};         // row-sum accumulator (l_run)
  #pragma unroll
  for (int ni = 0; ni < 4; ++ni) oc[ni] = (v4f){0.f,0.f,0.f,0.f};
  float m_run[4] = {-1e30f,-1e30f,-1e30f,-1e30f};
  const float SC = 0.180336880f;            // 0.125 * log2(e): exp2 domain
  for (int sc = 0; sc < 9; ++sc){
    const int cb = sc & 1;
    bf16* Kc = Ks[cb];
    bf16* Vc = Vs[cb];
    #pragma unroll
    for (int r = 0; r < 4; ++r){
      *(ushort4*)&Kc[srow[r]*72 + scol[r]] = kreg[r];
      *(ushort4*)&Vc[srow[r]*72 + scol[r]] = vreg[r];
    }
    __syncthreads();                        // single barrier per iteration (dbuf)
    if (sc < 8){                            // prefetch next tile under compute
      #pragma unroll
      for (int r = 0; r < 4; ++r){
        kreg[r] = *(const ushort4*)&KT[(size_t)((sc+1)*64 + srow[r])*512 + c0 + scol[r]];
        vreg[r] = *(const ushort4*)&Vp[(size_t)(c0 + srow[r])*576 + (sc+1)*64 + scol[r]];
      }
    }
    v4f sa[4];
    #pragma unroll
    for (int sj = 0; sj < 4; ++sj) sa[sj] = (v4f){0.f,0.f,0.f,0.f};
    #pragma unroll
    for (int sj = 0; sj < 4; ++sj){
      v8s b0 = *(const v8s*)&Kc[(sj*16 + r15)*72 + quad*8];
      v8s b1 = *(const v8s*)&Kc[(sj*16 + r15)*72 + 32 + quad*8];
      sa[sj] = __builtin_amdgcn_mfma_f32_16x16x32_bf16(aq0, b0, sa[sj], 0, 0, 0);
      sa[sj] = __builtin_amdgcn_mfma_f32_16x16x32_bf16(aq1, b1, sa[sj], 0, 0, 0);
    }
    // per-lane partial max per row-group (over this lane's 4 cols)
    float cmx[4] = {-1e30f,-1e30f,-1e30f,-1e30f};
    #pragma unroll
    for (int sj = 0; sj < 4; ++sj)
      #pragma unroll
      for (int rg = 0; rg < 4; ++rg){
        float v = sa[sj][rg]*SC;
        sa[sj][rg] = v;
        cmx[rg] = fmaxf(cmx[rg], v);
      }
    // defer-max: if no lane's PARTIAL exceeds m+8, true rowmax <= m+8 -> P <= 2^8, skip reduce
    float grow = fmaxf(fmaxf(cmx[0]-m_run[0], cmx[1]-m_run[1]),
                       fmaxf(cmx[2]-m_run[2], cmx[3]-m_run[3]));
    if (__any(grow > 8.f)){
      #pragma unroll
      for (int off = 1; off < 16; off <<= 1)
        #pragma unroll
        for (int rg = 0; rg < 4; ++rg) cmx[rg] = fmaxf(cmx[rg], __shfl_xor(cmx[rg], off, 64));
      #pragma unroll
      for (int rg = 0; rg < 4; ++rg){
        float mnew = fmaxf(m_run[rg], cmx[rg]);
        float al = exp2f(m_run[rg] - mnew);
        m_run[rg] = mnew;
        oc2[rg] *= al;
        #pragma unroll
        for (int ni = 0; ni < 4; ++ni) oc[ni][rg] *= al;
      }
    }
    #pragma unroll
    for (int sj = 0; sj < 4; ++sj)
      #pragma unroll
      for (int rg = 0; rg < 4; ++rg)
        Ps[w][(quad*4 + rg)*72 + sj*16 + r15] = f2b(exp2f(sa[sj][rg] - m_run[rg]));
    #pragma unroll
    for (int ks = 0; ks < 2; ++ks){
      v8s a = *(const v8s*)&Ps[w][r15*72 + ks*32 + quad*8];
      #pragma unroll
      for (int ni = 0; ni < 4; ++ni){
        v8s b = *(const v8s*)&Vc[(ni*16 + r15)*72 + ks*32 + quad*8];
        oc[ni] = __builtin_amdgcn_mfma_f32_16x16x32_bf16(a, b, oc[ni], 0, 0, 0);
      }
      oc2 = __builtin_amdgcn_mfma_f32_16x16x32_bf16(a, bones, oc2, 0, 0, 0);  // row-sum
    }
  }
  float inv[4];
  #pragma unroll
  for (int rg = 0; rg < 4; ++rg) inv[rg] = 1.f / oc2[rg];
  #pragma unroll
  for (int ni = 0; ni < 4; ++ni)
    #pragma unroll
    for (int rg = 0; rg < 4; ++rg){
      int t = t0*64 + w*16 + quad*4 + rg;
      attT[(size_t)(nl*576 + t)*512 + c0 + ni*16 + r15] = f2b(oc[ni][rg]*inv[rg]);
    }
}

// ---------------------------------------------------------------- K4: spatial proj + residual (MFMA)
// R1: LDS-transpose epilogue with coalesced 16B stores (x2 and x2T).
__global__ __launch_bounds__(256) void k_proj_s_mfma(const bf16* __restrict__ AT,
        const bf16* __restrict__ Wb, const void* __restrict__ Bv,
        const void* __restrict__ xin, bf16* __restrict__ x2,
        bf16* __restrict__ x2T, int doT,
        const int* __restrict__ flag, int n0){
  const bool f32in = flag[0] != 0;
  const int o0 = blockIdx.x * 128;
  const int l0 = blockIdx.y * 64;
  const int nl = blockIdx.z;
  const int n = n0 + nl;
  const int b = n >> 4, t = n & 15;
  const int tid = threadIdx.x, lane = tid & 63;
  const int wm = (tid >> 6) & 1, wn = tid >> 7;
  const int r15 = lane & 15, quad = lane >> 4;
  __shared__ bf16 As[128*72];
  __shared__ bf16 Bs[64*72];
  v4f acc[4][2];
  #pragma unroll
  for (int i = 0; i < 4; ++i)
    #pragma unroll
    for (int j = 0; j < 2; ++j) acc[i][j] = (v4f){0.f,0.f,0.f,0.f};
  for (int kc = 0; kc < 512; kc += 64){
    __syncthreads();
    #pragma unroll
    for (int r = 0; r < 8; ++r){
      int e4 = (tid + 256*r)*4;
      int row = e4 >> 6, k = e4 & 63;
      stage4b(&Wb[(size_t)(o0+row)*512 + kc + k], &As[row*72 + k]);
    }
    #pragma unroll
    for (int r = 0; r < 4; ++r){
      int e4 = (tid + 256*r)*4;
      int row = e4 >> 6, k = e4 & 63;
      stage4b(&AT[(size_t)(nl*576 + l0 + row)*512 + kc + k], &Bs[row*72 + k]);
    }
    __syncthreads();
    #pragma unroll
    for (int ks = 0; ks < 2; ++ks){
      v8s a[4], b[2];
      #pragma unroll
      for (int mi = 0; mi < 4; ++mi)
        a[mi] = *(const v8s*)&As[(wm*64 + mi*16 + r15)*72 + ks*32 + quad*8];
      #pragma unroll
      for (int ni = 0; ni < 2; ++ni)
        b[ni] = *(const v8s*)&Bs[(wn*32 + ni*16 + r15)*72 + ks*32 + quad*8];
      #pragma unroll
      for (int mi = 0; mi < 4; ++mi)
        #pragma unroll
        for (int ni = 0; ni < 2; ++ni)
          acc[mi][ni] = __builtin_amdgcn_mfma_f32_16x16x32_bf16(a[mi], b[ni], acc[mi][ni], 0, 0, 0);
    }
  }
  // -------- epilogue: stage acc+bias into As as [o_rel][l_rel] (stride 72)
  __syncthreads();
  #pragma unroll
  for (int mi = 0; mi < 4; ++mi){
    int orel = wm*64 + mi*16 + quad*4;
    #pragma unroll
    for (int rg = 0; rg < 4; ++rg){
      float bia = ldin(Bv, o0 + orel + rg, f32in);
      #pragma unroll
      for (int ni = 0; ni < 2; ++ni)
        As[(orel + rg)*72 + wn*32 + ni*16 + r15] = f2b(acc[mi][ni][rg] + bia);
    }
  }
  __syncthreads();
  // phase 1: residual add + coalesced x2 write (+writeback for phase 2)
  const size_t xrow = ((size_t)(b*512 + o0)*16 + t)*576 + l0;
  for (int it = 0; it < 4; ++it){
    int idx = tid + it*256;             // 1024 chunks of 8 elems
    int o = idx >> 3, lc = (idx & 7)*8;
    union { bf16 h[8]; v8s v; } val;
    val.v = *(const v8s*)&As[o*72 + lc];
    size_t ga = xrow + (size_t)o*9216 + lc;
    if (f32in){
      const float* xp = (const float*)xin + ga;
      float4 f0 = *(const float4*)xp;
      float4 f1 = *(const float4*)(xp + 4);
      val.h[0] = f2b(b2f(val.h[0]) + f0.x);
      val.h[1] = f2b(b2f(val.h[1]) + f0.y);
      val.h[2] = f2b(b2f(val.h[2]) + f0.z);
      val.h[3] = f2b(b2f(val.h[3]) + f0.w);
      val.h[4] = f2b(b2f(val.h[4]) + f1.x);
      val.h[5] = f2b(b2f(val.h[5]) + f1.y);
      val.h[6] = f2b(b2f(val.h[6]) + f1.z);
      val.h[7] = f2b(b2f(val.h[7]) + f1.w);
    } else {
      union { bf16 h[8]; v8s v; } xv;
      xv.v = *(const v8s*)((const bf16*)xin + ga);
      #pragma unroll
      for (int j = 0; j < 8; ++j) val.h[j] = f2b(b2f(val.h[j]) + b2f(xv.h[j]));
    }
    *(v8s*)&x2[ga] = val.v;
    if (doT) *(v8s*)&As[o*72 + lc] = val.v;
  }
  if (doT){
    __syncthreads();
    // phase 2: x2T [m][t][c]: per chunk, 8 consecutive o at fixed l
    const size_t tbase = ((size_t)b*576 + l0)*8192 + (size_t)t*512 + o0;
    for (int it = 0; it < 4; ++it){
      int l = (tid & 15) + it*16;
      int ocg = (tid >> 4)*8;
      union { bf16 h[8]; v8s v; } val;
      #pragma unroll
      for (int j = 0; j < 8; ++j) val.h[j] = As[(ocg + j)*72 + l];
      *(v8s*)&x2T[tbase + (size_t)l*8192 + ocg] = val.v;
    }
  }
}

// ---------------------------------------------------------------- K5a: temporal groupnorm (scattered x2) -> xnT [m][t][c]
__global__ __launch_bounds__(256) void k_gn_t(const bf16* __restrict__ x2,
        const void* __restrict__ gw, const void* __restrict__ gb,
        bf16* __restrict__ xnT, const int* __restrict__ flag, int m0){
  const bool f32in = flag[0] != 0;
  const int ml = blockIdx.x;
  const int m = m0 + ml;
  const int b = m / 576, l = m - b*576;
  const int tid = threadIdx.x;
  __shared__ float xs[8192];
  __shared__ float mg[32], rg[32];
  for (int i = tid; i < 8192; i += 256){
    int t = i >> 9, c = i & 511;
    xs[i] = b2f(x2[((b*512 + c)*16 + t)*576 + l]);
  }
  __syncthreads();
  {
    int g = tid >> 3, ii = tid & 7;
    float s = 0.f, q = 0.f;
    for (int idx = ii; idx < 256; idx += 8){
      int t = idx >> 4, cg = idx & 15;
      float v = xs[t*512 + g*16 + cg]; s += v; q += v*v;
    }
    #pragma unroll
    for (int off = 1; off < 8; off <<= 1){ s += __shfl_xor(s, off, 64); q += __shfl_xor(q, off, 64); }
    if (ii == 0){
      float mean = s*(1.f/256.f);
      float var  = q*(1.f/256.f) - mean*mean;
      mg[g] = mean; rg[g] = rsqrtf(fmaxf(var, 0.f) + 1e-5f);
    }
  }
  __syncthreads();
  for (int i = tid; i < 8192; i += 256){
    int c = i & 511, g = c >> 4;
    xnT[(size_t)ml*8192 + i] = f2b((xs[i] - mg[g])*rg[g]*ldin(gw, c, f32in) + ldin(gb, c, f32in));
  }
}

// ---------------------------------------------------------------- K5b: temporal groupnorm (coalesced x2T)
__global__ __launch_bounds__(256) void k_gn_t2(const bf16* __restrict__ x2T,
        const void* __restrict__ gw, const void* __restrict__ gb,
        bf16* __restrict__ xnT, const int* __restrict__ flag, int m0){
  const bool f32in = flag[0] != 0;
  const int ml = blockIdx.x;
  const int m = m0 + ml;
  const int tid = threadIdx.x;
  __shared__ float xs[8192];
  __shared__ float mg[32], rg[32];
  for (int i = tid; i < 8192; i += 256)
    xs[i] = b2f(x2T[(size_t)m*8192 + i]);     // [t][c] order, fully coalesced
  __syncthreads();
  {
    int g = tid >> 3, ii = tid & 7;
    float s = 0.f, q = 0.f;
    for (int idx = ii; idx < 256; idx += 8){
      int t = idx >> 4, cg = idx & 15;
      float v = xs[t*512 + g*16 + cg]; s += v; q += v*v;
    }
    #pragma unroll
    for (int off = 1; off < 8; off <<= 1){ s += __shfl_xor(s, off, 64); q += __shfl_xor(q, off, 64); }
    if (ii == 0){
      float mean = s*(1.f/256.f);
      float var  = q*(1.f/256.f) - mean*mean;
      mg[g] = mean; rg[g] = rsqrtf(fmaxf(var, 0.f) + 1e-5f);
    }
  }
  __syncthreads();
  for (int i = tid; i < 8192; i += 256){
    int c = i & 511, g = c >> 4;
    xnT[(size_t)ml*8192 + i] = f2b((xs[i] - mg[g])*rg[g]*ldin(gw, c, f32in) + ldin(gb, c, f32in));
  }
}

// ---------------------------------------------------------------- K7: temporal attention -> attT [m][t][c]
// R8: vectorized staging. R13: softmax->PV barrier removed (intra-wave dep:
// ps row t is written and read by lanes [16t,16t+16) — same wave64).
__global__ __launch_bounds__(256) void k_attn_t(const bf16* __restrict__ qkv,
        const void* __restrict__ tbk, const void* __restrict__ tbv,
        bf16* __restrict__ attT, const int* __restrict__ flag){
  const bool f32in = flag[0] != 0;
  const int head = blockIdx.x;
  const int ml = blockIdx.y;
  const int tid = threadIdx.x;
  __shared__ float qsT[16*68], ksT[16*68], vsT[16*68];  // [t][c], stride 68 (16B-aligned rows)
  __shared__ float tks[33*68], tvs[33*68];              // [d][c]
  __shared__ float ps[16*17];
  const int base = (ml*1536 + head*64)*16;
  // ---- qkv staging: 3 arrays x 128 v8s-chunks (chunk = 8 consecutive t, one c)
  for (int j = tid; j < 384; j += 256){
    int arr = j >> 7, cj = j & 127;
    int c = cj >> 1, t0 = (cj & 1)*8;
    union { bf16 h[8]; v8s v; } u;
    u.v = *(const v8s*)(qkv + base + arr*8192 + c*16 + t0);
    float* dst = (arr == 0) ? qsT : (arr == 1) ? ksT : vsT;
    #pragma unroll
    for (int e = 0; e < 8; ++e) dst[(t0 + e)*68 + c] = b2f(u.h[e]);
  }
  // ---- table staging: 33x64 each; contiguous-in-c chunks -> float4 LDS writes
  if (f32in){
    for (int j = tid; j < 1056; j += 256){
      int tb = (j >= 528) ? 1 : 0;
      int cj = j - tb*528;
      int d = cj >> 4, c = (cj & 15)*4;
      float4 v = *(const float4*)((const float*)(tb ? tbv : tbk) + d*64 + c);
      *(float4*)&((tb ? tvs : tks)[d*68 + c]) = v;
    }
  } else {
    for (int j = tid; j < 528; j += 256){
      int tb = (j >= 264) ? 1 : 0;
      int cj = j - tb*264;
      int d = cj >> 3, c = (cj & 7)*8;
      union { bf16 h[8]; v8s v; } u;
      u.v = *(const v8s*)((const bf16*)(tb ? tbv : tbk) + d*64 + c);
      float* dst = (tb ? tvs : tks) + d*68 + c;
      float4 f0 = {b2f(u.h[0]), b2f(u.h[1]), b2f(u.h[2]), b2f(u.h[3])};
      float4 f1 = {b2f(u.h[4]), b2f(u.h[5]), b2f(u.h[6]), b2f(u.h[7])};
      *(float4*)dst = f0;
      *(float4*)(dst + 4) = f1;
    }
  }
  __syncthreads();
  {
    const int t = tid >> 4, s = tid & 15;
    const float4* qt = (const float4*)&qsT[t*68];
    const float4* kr = (const float4*)&ksT[s*68];
    const float4* q2 = (const float4*)&qsT[s*68];
    const float4* tr = (const float4*)&tks[(t - s + 16)*68];
    float qk = 0.f, rp = 0.f;
    #pragma unroll
    for (int c4 = 0; c4 < 16; ++c4){
      float4 a = qt[c4], b = kr[c4];
      qk += a.x*b.x + a.y*b.y + a.z*b.z + a.w*b.w;
      float4 a2 = q2[c4], tb = tr[c4];
      rp += a2.x*tb.x + a2.y*tb.y + a2.z*tb.z + a2.w*tb.w;
    }
    float logit = 0.125f*qk + 0.35355339059327373f*rp;
    if (s > t) logit = -1e8f;
    float mx = logit;
    #pragma unroll
    for (int off = 8; off; off >>= 1) mx = fmaxf(mx, __shfl_xor(mx, off, 16));
    float e = __expf(logit - mx);
    float tot = e;
    #pragma unroll
    for (int off = 8; off; off >>= 1) tot += __shfl_xor(tot, off, 16);
    ps[t*17 + s] = e / tot;
  }
  // no barrier: ps row t written/read within the same wave (lanes 16t..16t+15)
  {
    const int c4 = tid & 15, t = tid >> 4;
    float4 acc = {0.f,0.f,0.f,0.f};
    #pragma unroll
    for (int s = 0; s < 16; ++s){
      float p = ps[t*17 + s];
      float4 v4 = *(const float4*)&vsT[s*68 + c4*4];
      float4 t4 = *(const float4*)&tvs[(s - t + 16)*68 + c4*4];
      acc.x += p*(v4.x + t4.x); acc.y += p*(v4.y + t4.y);
      acc.z += p*(v4.z + t4.z); acc.w += p*(v4.w + t4.w);
    }
    union { bf16 h[4]; ushort4 u; } o;
    o.h[0] = f2b(acc.x); o.h[1] = f2b(acc.y); o.h[2] = f2b(acc.z); o.h[3] = f2b(acc.w);
    *(ushort4*)&attT[(size_t)ml*8192 + t*512 + head*64 + c4*4] = o.u;
  }
}

// ---------------------------------------------------------------- K8: temporal proj + residual -> out (MFMA)
// R12: LDS-staged epilogue (R1 pattern): Cs[t][o][l] in As, then 8-elem chunks
// with v8s x2 loads + contiguous 16/32B stores.
__global__ __launch_bounds__(256) void k_proj_t_mfma(const bf16* __restrict__ AT,
        const bf16* __restrict__ Wb, const void* __restrict__ Bv,
        const bf16* __restrict__ x2, void* __restrict__ out,
        const int* __restrict__ flag, int m0){
  const bool f32in = flag[0] != 0;
  const int o0 = blockIdx.x * 128;
  const int tp = blockIdx.y;            // t-pair
  const int mg0 = blockIdx.z * 32;      // m base (32 | 576)
  const int tid = threadIdx.x, lane = tid & 63;
  const int wm = (tid >> 6) & 1, wn = tid >> 7;
  const int r15 = lane & 15, quad = lane >> 4;
  __shared__ bf16 As[128*72];           // W staging; Cs[2][128][36] after loop (9216 elems)
  __shared__ bf16 Bs[64*72];
  v4f acc[4][2];
  #pragma unroll
  for (int i = 0; i < 4; ++i)
    #pragma unroll
    for (int j = 0; j < 2; ++j) acc[i][j] = (v4f){0.f,0.f,0.f,0.f};
  for (int kc = 0; kc < 512; kc += 64){
    __syncthreads();
    #pragma unroll
    for (int r = 0; r < 8; ++r){
      int e4 = (tid + 256*r)*4;
      int row = e4 >> 6, k = e4 & 63;
      stage4b(&Wb[(size_t)(o0+row)*512 + kc + k], &As[row*72 + k]);
    }
    #pragma unroll
    for (int r = 0; r < 4; ++r){
      int e4 = (tid + 256*r)*4;
      int row = e4 >> 6, k = e4 & 63;
      stage4b(&AT[(size_t)(mg0 + (row & 31))*8192 + (tp*2 + (row >> 5))*512 + kc + k],
              &Bs[row*72 + k]);
    }
    __syncthreads();
    #pragma unroll
    for (int ks = 0; ks < 2; ++ks){
      v8s a[4], b[2];
      #pragma unroll
      for (int mi = 0; mi < 4; ++mi)
        a[mi] = *(const v8s*)&As[(wm*64 + mi*16 + r15)*72 + ks*32 + quad*8];
      #pragma unroll
      for (int ni = 0; ni < 2; ++ni)
        b[ni] = *(const v8s*)&Bs[(wn*32 + ni*16 + r15)*72 + ks*32 + quad*8];
      #pragma unroll
      for (int mi = 0; mi < 4; ++mi)
        #pragma unroll
        for (int ni = 0; ni < 2; ++ni)
          acc[mi][ni] = __builtin_amdgcn_mfma_f32_16x16x32_bf16(a[mi], b[ni], acc[mi][ni], 0, 0, 0);
    }
  }
  // ---- R12 epilogue: stage acc+bias as Cs[t_loc][o_rel][l_loc] (stride 36)
  __syncthreads();
  #pragma unroll
  for (int mi = 0; mi < 4; ++mi){
    int orel = wm*64 + mi*16 + quad*4;
    #pragma unroll
    for (int rg = 0; rg < 4; ++rg){
      float bia = ldin(Bv, o0 + orel + rg, f32in);
      #pragma unroll
      for (int ni = 0; ni < 2; ++ni)
        As[(wn*128 + orel + rg)*36 + ni*16 + r15] = f2b(acc[mi][ni][rg] + bia);
    }
  }
  __syncthreads();
  // store: 8192 elems in 1024 chunks of 8 consecutive l
  const int mb = m0 + mg0;
  const int bb = mb / 576;
  const int l0b = mb - bb*576;          // multiple of 32 (576%32==0)
  for (int it = 0; it < 4; ++it){
    int idx = tid + it*256;             // [0,1024)
    int l8 = (idx & 3)*8;
    int ot = idx >> 2;                  // [0,256)
    int orel = ot & 127, tl = ot >> 7;
    union { bf16 h[8]; v8s v; } cv;
    cv.v = *(const v8s*)&As[(tl*128 + orel)*36 + l8];
    size_t addr = ((size_t)(bb*512 + o0 + orel)*16 + tp*2 + tl)*576 + l0b + l8;
    union { bf16 h[8]; v8s v; } xv;
    xv.v = *(const v8s*)&x2[addr];
    if (f32in){
      float* op = (float*)out + addr;
      float4 f0, f1;
      f0.x = b2f(cv.h[0]) + b2f(xv.h[0]);
      f0.y = b2f(cv.h[1]) + b2f(xv.h[1]);
      f0.z = b2f(cv.h[2]) + b2f(xv.h[2]);
      f0.w = b2f(cv.h[3]) + b2f(xv.h[3]);
      f1.x = b2f(cv.h[4]) + b2f(xv.h[4]);
      f1.y = b2f(cv.h[5]) + b2f(xv.h[5]);
      f1.z = b2f(cv.h[6]) + b2f(xv.h[6]);
      f1.w = b2f(cv.h[7]) + b2f(xv.h[7]);
      *(float4*)op = f0;
      *(float4*)(op + 4) = f1;
    } else {
      union { bf16 h[8]; v8s v; } ov;
      #pragma unroll
      for (int j = 0; j < 8; ++j) ov.h[j] = f2b(b2f(cv.h[j]) + b2f(xv.h[j]));
      *(v8s*)((bf16*)out + addr) = ov.v;
    }
  }
}

// ----------------------------------------------------------------
extern "C" void kernel_launch(void* const* d_in, const int* in_sizes, int n_in,
                              void* d_out, int out_size, void* d_ws, size_t ws_size,
                              hipStream_t stream){
  const void* x   = d_in[0];
  const void* nsw = d_in[1];
  const void* nsb = d_in[2];
  const void* qsw = d_in[3];
  const void* qsb = d_in[4];
  const void* psw = d_in[5];
  const void* psb = d_in[6];
  const void* ntw = d_in[7];
  const void* ntb = d_in[8];
  const void* qtw = d_in[9];
  const void* qtb = d_in[10];
  const void* ptw = d_in[11];
  const void* ptb = d_in[12];
  const void* rpk = d_in[13];
  const void* rpv = d_in[14];

  // Chunking and x2T gate from ws_size (constant across calls -> graph-safe).
  const size_t S_full = (size_t)32*294912;
  const size_t need_full = 256 + (S_full*5 + 9437184)*2;
  const size_t need_T    = 256 + (S_full*5 + (size_t)2*9437184)*2;  // +18.9 MB for x2T
  const int NCH = (ws_size >= need_full) ? 32 : 8;
  const int MCH = (NCH == 32) ? 1152 : 288;
  const size_t S = (size_t)NCH*294912;
  const int useT = (NCH == 32 && ws_size >= need_T) ? 1 : 0;

  int*  flag = (int*)d_ws;
  bf16* A  = (bf16*)((char*)d_ws + 256);   // S: xnT_s / xnT_t
  bf16* A2 = A  + S;                        // S: attT_s / attT_t (+ transient W copy)
  bf16* Bq = A2 + S;                        // 3S: qkv (+ transient W copies)
  bf16* Cx = Bq + 3*S;                      // 9,437,184: x2 residual
  bf16* Cx2 = Cx + 9437184;                 // 9,437,184: x2T [m][t][c] (if useT)
  const size_t kOff = S, vOff = 2*S;
  bf16* Wcv  = A2;
  bf16* Wcv2 = Bq;

  k_detect<<<1, 64, 0, stream>>>(x, flag);

  for (int n0 = 0; n0 < 32; n0 += NCH){
    k_gn_s       <<<dim3(32, NCH),   256, 0, stream>>>(x, nsw, nsb, A, flag, n0);
    k_cvtw       <<<dim3(768),       256, 0, stream>>>(qsw, Wcv, 196608, flag);
    k_gemm_qkv   <<<dim3(NCH*54),    256, 0, stream>>>(A, Wcv, qsb, Bq, flag, kOff, vOff, 0);
    k_attn_s_mfma<<<dim3(72*NCH),    256, 0, stream>>>(Bq, A2, kOff, vOff);
    // proj_s weight pre-convert into Bq (qkv dead after attn_s)
    k_cvtw       <<<dim3(256),       256, 0, stream>>>(psw, Bq, 65536, flag);
    k_proj_s_mfma<<<dim3(4, 9, NCH), 256, 0, stream>>>(A2, Bq, psb, x, Cx, Cx2, useT, flag, n0);
  }
  for (int m0 = 0; m0 < 1152; m0 += MCH){
    if (useT) k_gn_t2<<<dim3(MCH),   256, 0, stream>>>(Cx2, ntw, ntb, A, flag, m0);
    else      k_gn_t <<<dim3(MCH),   256, 0, stream>>>(Cx,  ntw, ntb, A, flag, m0);
    k_cvtw       <<<dim3(768),       256, 0, stream>>>(qtw, Wcv, 196608, flag);
    k_gemm_qkv   <<<dim3((MCH/2)*3), 256, 0, stream>>>(A, Wcv, qtb, Bq, flag, 0, 0, 1);
    k_attn_t     <<<dim3(8, MCH),    256, 0, stream>>>(Bq, rpk, rpv, A2, flag);
    k_cvtw       <<<dim3(256),       256, 0, stream>>>(ptw, Wcv2, 65536, flag);
    k_proj_t_mfma<<<dim3(4, 8, MCH/32), 256, 0, stream>>>(A2, Wcv2, ptb, Cx, d_out, flag, m0);
  }
}

// Round 16
// 424.307 us; speedup vs baseline: 1.2068x; 1.0126x over previous
//
#include <hip/hip_runtime.h>
#include <hip/hip_bf16.h>

typedef __hip_bfloat16 bf16;
typedef __attribute__((ext_vector_type(8))) short v8s;
typedef __attribute__((ext_vector_type(4))) float v4f;

__device__ __forceinline__ float b2f(bf16 v){ return __bfloat162float(v); }
__device__ __forceinline__ bf16  f2b(float v){ return __float2bfloat16(v); }

// Inputs may be bf16 OR f32 — runtime-detected flag (1 => f32). Output dtype follows.
__device__ __forceinline__ float ldin(const void* p, int i, bool f32in){
  return f32in ? ((const float*)p)[i] : b2f(((const bf16*)p)[i]);
}

// stage 4 consecutive source elems (f32-or-bf16) into dst as bf16 (8B write)
__device__ __forceinline__ void stage4(const void* src, size_t off, bool f32in, bf16* dst){
  union { bf16 h[4]; ushort4 u; } tmp;
  if (f32in){
    float4 f = *(const float4*)((const float*)src + off);
    tmp.h[0] = f2b(f.x); tmp.h[1] = f2b(f.y); tmp.h[2] = f2b(f.z); tmp.h[3] = f2b(f.w);
  } else {
    tmp.u = *(const ushort4*)((const ushort*)src + off);
  }
  *(ushort4*)dst = tmp.u;
}
__device__ __forceinline__ void stage4b(const bf16* src, bf16* dst){
  *(ushort4*)dst = *(const ushort4*)src;
}

// async global->LDS, 16B per lane. LDS dest must be wave-uniform base (HW adds lane*16).
__device__ __forceinline__ void async_cp16(const bf16* g, bf16* l){
  __builtin_amdgcn_global_load_lds(
      (const __attribute__((address_space(1))) unsigned int*)g,
      (__attribute__((address_space(3))) unsigned int*)l, 16, 0, 0);
}

// Problem: B=2, C=512, T=16, H=W=24, heads=8, ch=64
// ws: flag | A (S) | A2 (S) | Bq (3S) | Cx 9,437,184 | [Cx2 9,437,184 if room]
// R1: proj_s epilogue request-bound -> LDS-transpose epilogue (WIN, -58us).
// R2: qkv GEMMs -> unified 128x128 global_load_lds GEMM.
// R3: XOR-swizzle via pre-swizzled global source + swizzled ds_read (conflict=0).
// R4: attn_s setprio bundle FAILED; R6 conditional max-reduce + ones-MFMA WIN (-19us).
// R8: attn_t staging vectorized (WIN, -24us).
// R9: gemm_qkv LDS-staged C-tile epilogue + 16B stores (WIN, -10us).
// R12: gn_s vectorized + proj_t LDS epilogue (WIN, -29us).
// R13: attn_s dbuf 1-barrier NEUTRAL (VALU 53->64 but occupancy 35->27, wash);
//      attn_t softmax->PV barrier removed (kept).
// R14: attn_s revert to single-buffer/2-barrier (occupancy back to 5 blk/CU) +
//      pre-scale Q by SC once (kills 16 muls/iter/thread; MFMA output pre-scaled).
// R15: broker timeout, no measurement — resubmitted unchanged.

// ---------------------------------------------------------------- detect input dtype
__global__ void k_detect(const void* x, int* flag){
  int tid = threadIdx.x;
  const bf16* p = (const bf16*)x;
  int cnt = 0;
  for (int i = tid; i < 512; i += 64){
    float v = b2f(p[i]);
    if (!(fabsf(v) <= 64.f)) cnt++;
  }
  #pragma unroll
  for (int off = 32; off; off >>= 1) cnt += __shfl_down(cnt, off, 64);
  if (tid == 0) flag[0] = (cnt > 16) ? 1 : 0;
}

// ---------------------------------------------------------------- weight convert -> bf16 scratch
__global__ __launch_bounds__(256) void k_cvtw(const void* __restrict__ W,
        bf16* __restrict__ out, int n4, const int* __restrict__ flag){
  const bool f32in = flag[0] != 0;
  int i = blockIdx.x*256 + threadIdx.x;
  if (i < n4) stage4(W, (size_t)i*4, f32in, out + (size_t)i*4);
}

// ---------------------------------------------------------------- K1: spatial groupnorm -> xnT [l][c]
// R12: vectorized loads, xs[cg][577] (float4 LDS writes conflict-free),
// gw/gb preload, v8s output stores.
__global__ __launch_bounds__(256) void k_gn_s(const void* __restrict__ x,
        const void* __restrict__ gw, const void* __restrict__ gb,
        bf16* __restrict__ xnT, const int* __restrict__ flag, int n0){
  const bool f32in = flag[0] != 0;
  const int g = blockIdx.x;
  const int nl = blockIdx.y;
  const int n = n0 + nl;
  const int b = n >> 4, t = n & 15;
  const int tid = threadIdx.x;
  __shared__ float xs[16*577];     // [cg][l] padded
  __shared__ float red[4][2];
  __shared__ float stats[2];
  __shared__ float sgw[16], sgb[16];
  if (tid < 16){
    sgw[tid] = ldin(gw, g*16 + tid, f32in);
    sgb[tid] = ldin(gb, g*16 + tid, f32in);
  }
  float s = 0.f, q = 0.f;
  #pragma unroll
  for (int p = 0; p < 9; ++p){
    int j = tid + p*256;                 // 2304 chunks of 4 along l
    int cg = j / 144, lc = (j - cg*144)*4;
    int c = g*16 + cg;
    size_t base = ((size_t)(b*512 + c)*16 + t)*576 + lc;
    float4 f;
    if (f32in){
      f = *(const float4*)((const float*)x + base);
    } else {
      union { bf16 h[4]; ushort4 u; } uu;
      uu.u = *(const ushort4*)((const bf16*)x + base);
      f.x = b2f(uu.h[0]); f.y = b2f(uu.h[1]); f.z = b2f(uu.h[2]); f.w = b2f(uu.h[3]);
    }
    *(float4*)&xs[cg*577 + lc] = f;
    s += f.x + f.y + f.z + f.w;
    q += f.x*f.x + f.y*f.y + f.z*f.z + f.w*f.w;
  }
  #pragma unroll
  for (int off = 32; off; off >>= 1){ s += __shfl_down(s, off, 64); q += __shfl_down(q, off, 64); }
  int wid = tid >> 6;
  if ((tid & 63) == 0){ red[wid][0] = s; red[wid][1] = q; }
  __syncthreads();
  if (tid == 0){
    float S = red[0][0]+red[1][0]+red[2][0]+red[3][0];
    float Q = red[0][1]+red[1][1]+red[2][1]+red[3][1];
    float mean = S * (1.f/9216.f);
    float var  = Q * (1.f/9216.f) - mean*mean;
    stats[0] = mean; stats[1] = rsqrtf(fmaxf(var, 0.f) + 1e-5f);
  }
  __syncthreads();
  float mean = stats[0], rstd = stats[1];
  // output: 1152 chunks of 8 consecutive c at fixed l -> 16B stores
  for (int j = tid; j < 1152; j += 256){
    int l = j >> 1, c8 = (j & 1)*8;
    union { bf16 h[8]; v8s v; } o;
    #pragma unroll
    for (int e = 0; e < 8; ++e){
      int cg = c8 + e;
      o.h[e] = f2b((xs[cg*577 + l] - mean)*rstd*sgw[cg] + sgb[cg]);
    }
    *(v8s*)&xnT[(size_t)(nl*576 + l)*512 + g*16 + c8] = o.v;
  }
}

// ---------------------------------------------------------------- K2/K6: unified qkv GEMM
// Xf: flat [R][512] bf16. Wb: [1536][512] bf16. 128x128 tile, BK=64,
// global_load_lds staging into linear LDS; slot^=(row&7) XOR swizzle via
// pre-swizzled global source + swizzled ds_read (T2 / rule #21).
// R9: LDS-staged C-tile epilogue with 16B contiguous stores.
// mode 0: spatial (Q/K [l][512] + V [c][576] per nl); mode 1: temporal [m][o][t].
__global__ __launch_bounds__(256) void k_gemm_qkv(const bf16* __restrict__ Xf,
        const bf16* __restrict__ Wb, const void* __restrict__ Bv,
        bf16* __restrict__ Y, const int* __restrict__ flag,
        size_t kOff, size_t vOff, int mode){
  const bool f32in = flag[0] != 0;
  const int nwg = gridDim.x;
  const int bid = blockIdx.x;
  const int g = (bid & 7)*(nwg >> 3) + (bid >> 3);   // chunked XCD swizzle (nwg%8==0)
  const int mt = g / 12, nt = g - mt*12;
  const int r0 = mt*128, o0 = nt*128;
  const int tid = threadIdx.x, lane = tid & 63, w = tid >> 6;
  const int wm = w & 1, wn = w >> 1;
  const int r15 = lane & 15, quad = lane >> 4;
  const int rsw = r15 & 7;                 // read-side swizzle key (row&7 == r15&7)
  __shared__ bf16 LB[16384];               // As=LB[0..8191], Bs=LB[8192..]; C-tile after loop
  bf16* As = LB;
  bf16* Bs = LB + 8192;
  v4f acc[4][4];
  #pragma unroll
  for (int i = 0; i < 4; ++i)
    #pragma unroll
    for (int j = 0; j < 4; ++j) acc[i][j] = (v4f){0.f,0.f,0.f,0.f};
  for (int kc = 0; kc < 512; kc += 64){
    __syncthreads();
    #pragma unroll
    for (int r = 0; r < 4; ++r){
      int d = (tid + 256*r)*8;             // linear LDS elem offset this lane fills
      int row = d >> 6;
      int slot = (d >> 3) & 7;             // 16B slot within the 128B row
      int col = ((slot ^ (row & 7)) * 8);  // inverse-swizzled source column
      async_cp16(&Xf[(size_t)(r0 + row)*512 + kc + col], As + r*2048 + w*512);
      async_cp16(&Wb[(size_t)(o0 + row)*512 + kc + col], Bs + r*2048 + w*512);
    }
    __syncthreads();                        // compiler drains vmcnt(0) before barrier
    #pragma unroll
    for (int ks = 0; ks < 2; ++ks){
      v8s a[4], b[4];
      #pragma unroll
      for (int mi = 0; mi < 4; ++mi)
        a[mi] = *(const v8s*)&As[(wm*64 + mi*16 + r15)*64 + (((ks*4 + quad) ^ rsw)*8)];
      #pragma unroll
      for (int ni = 0; ni < 4; ++ni)
        b[ni] = *(const v8s*)&Bs[(wn*64 + ni*16 + r15)*64 + (((ks*4 + quad) ^ rsw)*8)];
      #pragma unroll
      for (int mi = 0; mi < 4; ++mi)
        #pragma unroll
        for (int ni = 0; ni < 4; ++ni)
          acc[mi][ni] = __builtin_amdgcn_mfma_f32_16x16x32_bf16(a[mi], b[ni], acc[mi][ni], 0, 0, 0);
    }
  }
  // ---- R9 epilogue: stage acc+bias into LB as [r=128][c=128], then 16B stores
  __syncthreads();
  #pragma unroll
  for (int ni = 0; ni < 4; ++ni){
    int crel = wn*64 + ni*16 + r15;
    float bia = ldin(Bv, o0 + crel, f32in);
    #pragma unroll
    for (int mi = 0; mi < 4; ++mi){
      int rb = wm*64 + mi*16 + quad*4;
      #pragma unroll
      for (int rg = 0; rg < 4; ++rg)
        LB[(rb + rg)*128 + crel] = f2b(acc[mi][ni][rg] + bia);
    }
  }
  __syncthreads();
  if (mode == 0){
    const int seg = o0 >> 9, ob = o0 & 511;
    const size_t segb = (seg==0) ? 0 : (seg==1) ? kOff : vOff;
    if (seg < 2){
      // Q/K [l][512]: chunk = 8 consecutive oseg at fixed row
      for (int i = tid; i < 2048; i += 256){
        int r = i >> 4, c8 = (i & 15)*8;
        v8s v = *(const v8s*)&LB[r*128 + c8];
        int rr = r0 + r;
        int nl = rr / 576, l = rr - nl*576;
        *(v8s*)&Y[segb + (size_t)nl*294912 + (size_t)l*512 + ob + c8] = v;
      }
    } else {
      // V [c][576]: chunk = 8 consecutive rows (l) at fixed col; lanes c-major
      for (int i = tid; i < 2048; i += 256){
        int c = i & 127, rb = (i >> 7)*8;   // rows rb..rb+7 (576%8==0 -> no nl split)
        union { bf16 h[8]; v8s v; } u;
        #pragma unroll
        for (int e = 0; e < 8; ++e) u.h[e] = LB[(rb + e)*128 + c];
        int rr = r0 + rb;
        int nl = rr / 576, l = rr - nl*576;
        *(v8s*)&Y[segb + (size_t)nl*294912 + (size_t)(ob + c)*576 + l] = u.v;
      }
    }
  } else {
    // temporal [m][o][t]: chunk = 8 consecutive t at fixed (m, o); lanes c-major
    const int m0b = r0 >> 4;
    for (int i = tid; i < 2048; i += 256){
      int c = i & 127, rh = i >> 7;
      int mloc = rh >> 1, t0 = (rh & 1)*8;
      union { bf16 h[8]; v8s v; } u;
      #pragma unroll
      for (int e = 0; e < 8; ++e) u.h[e] = LB[(mloc*16 + t0 + e)*128 + c];
      *(v8s*)&Y[((size_t)(m0b + mloc)*1536 + o0 + c)*16 + t0] = u.v;
    }
  }
}

// ---------------------------------------------------------------- K3: spatial attention (flash MFMA) -> attT [l][c]
// R6: conditional max-reduce + ones-MFMA row-sum. R14: single-buffer/2-barrier
// (occupancy) + Q pre-scaled by SC (MFMA output pre-scaled, no per-iter muls).
__global__ __launch_bounds__(256, 4) void k_attn_s_mfma(const bf16* __restrict__ qkv,
        bf16* __restrict__ attT, size_t kOff, size_t vOff){
  const int bid = blockIdx.x;
  const int xcd = bid & 7, slot = bid >> 3;
  const int nl = xcd + 8*(slot/72);
  const int idx = slot - 72*(slot/72);
  const int head = idx/9, t0 = idx - 9*head;
  const int tid = threadIdx.x, lane = tid & 63, w = tid >> 6;
  const int r15 = lane & 15, quad = lane >> 4;
  __shared__ bf16 Ks[64*72];
  __shared__ bf16 Vs[64*72];
  __shared__ bf16 Ps[4][16*72];
  const bf16* QT = qkv + (size_t)nl*294912;
  const bf16* KT = qkv + kOff + (size_t)nl*294912;
  const bf16* Vp = qkv + vOff + (size_t)nl*294912;
  const int c0 = head*64;
  const float SC = 0.180336880f;            // 0.125 * log2(e): exp2 domain
  v8s aq0, aq1;
  {
    const bf16* qrow = QT + (size_t)(t0*64 + w*16 + r15)*512 + c0;
    union { bf16 h[8]; v8s v; } u0, u1;
    u0.v = *(const v8s*)(qrow + quad*8);
    u1.v = *(const v8s*)(qrow + 32 + quad*8);
    #pragma unroll
    for (int j = 0; j < 8; ++j){            // pre-scale Q by SC once
      u0.h[j] = f2b(b2f(u0.h[j])*SC);
      u1.h[j] = f2b(b2f(u1.h[j])*SC);
    }
    aq0 = u0.v; aq1 = u1.v;
  }
  // ones B-fragment for row-sum MFMA
  v8s bones;
  {
    union { bf16 h[8]; v8s v; } ob;
    #pragma unroll
    for (int j = 0; j < 8; ++j) ob.h[j] = f2b(1.f);
    bones = ob.v;
  }
  // staging geometry (reg prefetch)
  int srow[4], scol[4];
  #pragma unroll
  for (int r = 0; r < 4; ++r){
    int e4 = (tid + 256*r)*4;
    srow[r] = e4 >> 6; scol[r] = e4 & 63;
  }
  ushort4 kreg[4], vreg[4];
  #pragma unroll
  for (int r = 0; r < 4; ++r){
    kreg[r] = *(const ushort4*)&KT[(size_t)srow[r]*512 + c0 + scol[r]];
    vreg[r] = *(const ushort4*)&Vp[(size_t)(c0 + srow[r])*576 + scol[r]];
  }
  v4f oc[4];
  v4f oc2 = (v4f){0.f,0.f,0.f,0.f};         // row-sum accumulator (l_run)
  #pragma unroll
  for (int ni = 0; ni < 4; ++ni) oc[ni] = (v4f){0.f,0.f,0.f,0.f};
  float m_run[4] = {-1e30f,-1e30f,-1e30f,-1e30f};
  for (int sc = 0; sc < 9; ++sc){
    __syncthreads();
    #pragma unroll
    for (int r = 0; r < 4; ++r){
      *(ushort4*)&Ks[srow[r]*72 + scol[r]] = kreg[r];
      *(ushort4*)&Vs[srow[r]*72 + scol[r]] = vreg[r];
    }
    __syncthreads();
    if (sc < 8){                            // prefetch next tile under compute
      #pragma unroll
      for (int r = 0; r < 4; ++r){
        kreg[r] = *(const ushort4*)&KT[(size_t)((sc+1)*64 + srow[r])*512 + c0 + scol[r]];
        vreg[r] = *(const ushort4*)&Vp[(size_t)(c0 + srow[r])*576 + (sc+1)*64 + scol[r]];
      }
    }
    v4f sa[4];
    #pragma unroll
    for (int sj = 0; sj < 4; ++sj) sa[sj] = (v4f){0.f,0.f,0.f,0.f};
    #pragma unroll
    for (int sj = 0; sj < 4; ++sj){
      v8s b0 = *(const v8s*)&Ks[(sj*16 + r15)*72 + quad*8];
      v8s b1 = *(const v8s*)&Ks[(sj*16 + r15)*72 + 32 + quad*8];
      sa[sj] = __builtin_amdgcn_mfma_f32_16x16x32_bf16(aq0, b0, sa[sj], 0, 0, 0);
      sa[sj] = __builtin_amdgcn_mfma_f32_16x16x32_bf16(aq1, b1, sa[sj], 0, 0, 0);
    }
    // per-lane partial max per row-group (sa already in exp2 domain)
    float cmx[4] = {-1e30f,-1e30f,-1e30f,-1e30f};
    #pragma unroll
    for (int sj = 0; sj < 4; ++sj)
      #pragma unroll
      for (int rg = 0; rg < 4; ++rg)
        cmx[rg] = fmaxf(cmx[rg], sa[sj][rg]);
    // defer-max: if no lane's PARTIAL exceeds m+8, true rowmax <= m+8 -> P <= 2^8, skip reduce
    float grow = fmaxf(fmaxf(cmx[0]-m_run[0], cmx[1]-m_run[1]),
                       fmaxf(cmx[2]-m_run[2], cmx[3]-m_run[3]));
    if (__any(grow > 8.f)){
      #pragma unroll
      for (int off = 1; off < 16; off <<= 1)
        #pragma unroll
        for (int rg = 0; rg < 4; ++rg) cmx[rg] = fmaxf(cmx[rg], __shfl_xor(cmx[rg], off, 64));
      #pragma unroll
      for (int rg = 0; rg < 4; ++rg){
        float mnew = fmaxf(m_run[rg], cmx[rg]);
        float al = exp2f(m_run[rg] - mnew);
        m_run[rg] = mnew;
        oc2[rg] *= al;
        #pragma unroll
        for (int ni = 0; ni < 4; ++ni) oc[ni][rg] *= al;
      }
    }
    #pragma unroll
    for (int sj = 0; sj < 4; ++sj)
      #pragma unroll
      for (int rg = 0; rg < 4; ++rg)
        Ps[w][(quad*4 + rg)*72 + sj*16 + r15] = f2b(exp2f(sa[sj][rg] - m_run[rg]));
    #pragma unroll
    for (int ks = 0; ks < 2; ++ks){
      v8s a = *(const v8s*)&Ps[w][r15*72 + ks*32 + quad*8];
      #pragma unroll
      for (int ni = 0; ni < 4; ++ni){
        v8s b = *(const v8s*)&Vs[(ni*16 + r15)*72 + ks*32 + quad*8];
        oc[ni] = __builtin_amdgcn_mfma_f32_16x16x32_bf16(a, b, oc[ni], 0, 0, 0);
      }
      oc2 = __builtin_amdgcn_mfma_f32_16x16x32_bf16(a, bones, oc2, 0, 0, 0);  // row-sum
    }
  }
  float inv[4];
  #pragma unroll
  for (int rg = 0; rg < 4; ++rg) inv[rg] = 1.f / oc2[rg];
  #pragma unroll
  for (int ni = 0; ni < 4; ++ni)
    #pragma unroll
    for (int rg = 0; rg < 4; ++rg){
      int t = t0*64 + w*16 + quad*4 + rg;
      attT[(size_t)(nl*576 + t)*512 + c0 + ni*16 + r15] = f2b(oc[ni][rg]*inv[rg]);
    }
}

// ---------------------------------------------------------------- K4: spatial proj + residual (MFMA)
// R1: LDS-transpose epilogue with coalesced 16B stores (x2 and x2T).
__global__ __launch_bounds__(256) void k_proj_s_mfma(const bf16* __restrict__ AT,
        const bf16* __restrict__ Wb, const void* __restrict__ Bv,
        const void* __restrict__ xin, bf16* __restrict__ x2,
        bf16* __restrict__ x2T, int doT,
        const int* __restrict__ flag, int n0){
  const bool f32in = flag[0] != 0;
  const int o0 = blockIdx.x * 128;
  const int l0 = blockIdx.y * 64;
  const int nl = blockIdx.z;
  const int n = n0 + nl;
  const int b = n >> 4, t = n & 15;
  const int tid = threadIdx.x, lane = tid & 63;
  const int wm = (tid >> 6) & 1, wn = tid >> 7;
  const int r15 = lane & 15, quad = lane >> 4;
  __shared__ bf16 As[128*72];
  __shared__ bf16 Bs[64*72];
  v4f acc[4][2];
  #pragma unroll
  for (int i = 0; i < 4; ++i)
    #pragma unroll
    for (int j = 0; j < 2; ++j) acc[i][j] = (v4f){0.f,0.f,0.f,0.f};
  for (int kc = 0; kc < 512; kc += 64){
    __syncthreads();
    #pragma unroll
    for (int r = 0; r < 8; ++r){
      int e4 = (tid + 256*r)*4;
      int row = e4 >> 6, k = e4 & 63;
      stage4b(&Wb[(size_t)(o0+row)*512 + kc + k], &As[row*72 + k]);
    }
    #pragma unroll
    for (int r = 0; r < 4; ++r){
      int e4 = (tid + 256*r)*4;
      int row = e4 >> 6, k = e4 & 63;
      stage4b(&AT[(size_t)(nl*576 + l0 + row)*512 + kc + k], &Bs[row*72 + k]);
    }
    __syncthreads();
    #pragma unroll
    for (int ks = 0; ks < 2; ++ks){
      v8s a[4], b[2];
      #pragma unroll
      for (int mi = 0; mi < 4; ++mi)
        a[mi] = *(const v8s*)&As[(wm*64 + mi*16 + r15)*72 + ks*32 + quad*8];
      #pragma unroll
      for (int ni = 0; ni < 2; ++ni)
        b[ni] = *(const v8s*)&Bs[(wn*32 + ni*16 + r15)*72 + ks*32 + quad*8];
      #pragma unroll
      for (int mi = 0; mi < 4; ++mi)
        #pragma unroll
        for (int ni = 0; ni < 2; ++ni)
          acc[mi][ni] = __builtin_amdgcn_mfma_f32_16x16x32_bf16(a[mi], b[ni], acc[mi][ni], 0, 0, 0);
    }
  }
  // -------- epilogue: stage acc+bias into As as [o_rel][l_rel] (stride 72)
  __syncthreads();
  #pragma unroll
  for (int mi = 0; mi < 4; ++mi){
    int orel = wm*64 + mi*16 + quad*4;
    #pragma unroll
    for (int rg = 0; rg < 4; ++rg){
      float bia = ldin(Bv, o0 + orel + rg, f32in);
      #pragma unroll
      for (int ni = 0; ni < 2; ++ni)
        As[(orel + rg)*72 + wn*32 + ni*16 + r15] = f2b(acc[mi][ni][rg] + bia);
    }
  }
  __syncthreads();
  // phase 1: residual add + coalesced x2 write (+writeback for phase 2)
  const size_t xrow = ((size_t)(b*512 + o0)*16 + t)*576 + l0;
  for (int it = 0; it < 4; ++it){
    int idx = tid + it*256;             // 1024 chunks of 8 elems
    int o = idx >> 3, lc = (idx & 7)*8;
    union { bf16 h[8]; v8s v; } val;
    val.v = *(const v8s*)&As[o*72 + lc];
    size_t ga = xrow + (size_t)o*9216 + lc;
    if (f32in){
      const float* xp = (const float*)xin + ga;
      float4 f0 = *(const float4*)xp;
      float4 f1 = *(const float4*)(xp + 4);
      val.h[0] = f2b(b2f(val.h[0]) + f0.x);
      val.h[1] = f2b(b2f(val.h[1]) + f0.y);
      val.h[2] = f2b(b2f(val.h[2]) + f0.z);
      val.h[3] = f2b(b2f(val.h[3]) + f0.w);
      val.h[4] = f2b(b2f(val.h[4]) + f1.x);
      val.h[5] = f2b(b2f(val.h[5]) + f1.y);
      val.h[6] = f2b(b2f(val.h[6]) + f1.z);
      val.h[7] = f2b(b2f(val.h[7]) + f1.w);
    } else {
      union { bf16 h[8]; v8s v; } xv;
      xv.v = *(const v8s*)((const bf16*)xin + ga);
      #pragma unroll
      for (int j = 0; j < 8; ++j) val.h[j] = f2b(b2f(val.h[j]) + b2f(xv.h[j]));
    }
    *(v8s*)&x2[ga] = val.v;
    if (doT) *(v8s*)&As[o*72 + lc] = val.v;
  }
  if (doT){
    __syncthreads();
    // phase 2: x2T [m][t][c]: per chunk, 8 consecutive o at fixed l
    const size_t tbase = ((size_t)b*576 + l0)*8192 + (size_t)t*512 + o0;
    for (int it = 0; it < 4; ++it){
      int l = (tid & 15) + it*16;
      int ocg = (tid >> 4)*8;
      union { bf16 h[8]; v8s v; } val;
      #pragma unroll
      for (int j = 0; j < 8; ++j) val.h[j] = As[(ocg + j)*72 + l];
      *(v8s*)&x2T[tbase + (size_t)l*8192 + ocg] = val.v;
    }
  }
}

// ---------------------------------------------------------------- K5a: temporal groupnorm (scattered x2) -> xnT [m][t][c]
__global__ __launch_bounds__(256) void k_gn_t(const bf16* __restrict__ x2,
        const void* __restrict__ gw, const void* __restrict__ gb,
        bf16* __restrict__ xnT, const int* __restrict__ flag, int m0){
  const bool f32in = flag[0] != 0;
  const int ml = blockIdx.x;
  const int m = m0 + ml;
  const int b = m / 576, l = m - b*576;
  const int tid = threadIdx.x;
  __shared__ float xs[8192];
  __shared__ float mg[32], rg[32];
  for (int i = tid; i < 8192; i += 256){
    int t = i >> 9, c = i & 511;
    xs[i] = b2f(x2[((b*512 + c)*16 + t)*576 + l]);
  }
  __syncthreads();
  {
    int g = tid >> 3, ii = tid & 7;
    float s = 0.f, q = 0.f;
    for (int idx = ii; idx < 256; idx += 8){
      int t = idx >> 4, cg = idx & 15;
      float v = xs[t*512 + g*16 + cg]; s += v; q += v*v;
    }
    #pragma unroll
    for (int off = 1; off < 8; off <<= 1){ s += __shfl_xor(s, off, 64); q += __shfl_xor(q, off, 64); }
    if (ii == 0){
      float mean = s*(1.f/256.f);
      float var  = q*(1.f/256.f) - mean*mean;
      mg[g] = mean; rg[g] = rsqrtf(fmaxf(var, 0.f) + 1e-5f);
    }
  }
  __syncthreads();
  for (int i = tid; i < 8192; i += 256){
    int c = i & 511, g = c >> 4;
    xnT[(size_t)ml*8192 + i] = f2b((xs[i] - mg[g])*rg[g]*ldin(gw, c, f32in) + ldin(gb, c, f32in));
  }
}

// ---------------------------------------------------------------- K5b: temporal groupnorm (coalesced x2T)
__global__ __launch_bounds__(256) void k_gn_t2(const bf16* __restrict__ x2T,
        const void* __restrict__ gw, const void* __restrict__ gb,
        bf16* __restrict__ xnT, const int* __restrict__ flag, int m0){
  const bool f32in = flag[0] != 0;
  const int ml = blockIdx.x;
  const int m = m0 + ml;
  const int tid = threadIdx.x;
  __shared__ float xs[8192];
  __shared__ float mg[32], rg[32];
  for (int i = tid; i < 8192; i += 256)
    xs[i] = b2f(x2T[(size_t)m*8192 + i]);     // [t][c] order, fully coalesced
  __syncthreads();
  {
    int g = tid >> 3, ii = tid & 7;
    float s = 0.f, q = 0.f;
    for (int idx = ii; idx < 256; idx += 8){
      int t = idx >> 4, cg = idx & 15;
      float v = xs[t*512 + g*16 + cg]; s += v; q += v*v;
    }
    #pragma unroll
    for (int off = 1; off < 8; off <<= 1){ s += __shfl_xor(s, off, 64); q += __shfl_xor(q, off, 64); }
    if (ii == 0){
      float mean = s*(1.f/256.f);
      float var  = q*(1.f/256.f) - mean*mean;
      mg[g] = mean; rg[g] = rsqrtf(fmaxf(var, 0.f) + 1e-5f);
    }
  }
  __syncthreads();
  for (int i = tid; i < 8192; i += 256){
    int c = i & 511, g = c >> 4;
    xnT[(size_t)ml*8192 + i] = f2b((xs[i] - mg[g])*rg[g]*ldin(gw, c, f32in) + ldin(gb, c, f32in));
  }
}

// ---------------------------------------------------------------- K7: temporal attention -> attT [m][t][c]
// R8: vectorized staging. R13: softmax->PV barrier removed (intra-wave dep:
// ps row t is written and read by lanes [16t,16t+16) — same wave64).
__global__ __launch_bounds__(256) void k_attn_t(const bf16* __restrict__ qkv,
        const void* __restrict__ tbk, const void* __restrict__ tbv,
        bf16* __restrict__ attT, const int* __restrict__ flag){
  const bool f32in = flag[0] != 0;
  const int head = blockIdx.x;
  const int ml = blockIdx.y;
  const int tid = threadIdx.x;
  __shared__ float qsT[16*68], ksT[16*68], vsT[16*68];  // [t][c], stride 68 (16B-aligned rows)
  __shared__ float tks[33*68], tvs[33*68];              // [d][c]
  __shared__ float ps[16*17];
  const int base = (ml*1536 + head*64)*16;
  // ---- qkv staging: 3 arrays x 128 v8s-chunks (chunk = 8 consecutive t, one c)
  for (int j = tid; j < 384; j += 256){
    int arr = j >> 7, cj = j & 127;
    int c = cj >> 1, t0 = (cj & 1)*8;
    union { bf16 h[8]; v8s v; } u;
    u.v = *(const v8s*)(qkv + base + arr*8192 + c*16 + t0);
    float* dst = (arr == 0) ? qsT : (arr == 1) ? ksT : vsT;
    #pragma unroll
    for (int e = 0; e < 8; ++e) dst[(t0 + e)*68 + c] = b2f(u.h[e]);
  }
  // ---- table staging: 33x64 each; contiguous-in-c chunks -> float4 LDS writes
  if (f32in){
    for (int j = tid; j < 1056; j += 256){
      int tb = (j >= 528) ? 1 : 0;
      int cj = j - tb*528;
      int d = cj >> 4, c = (cj & 15)*4;
      float4 v = *(const float4*)((const float*)(tb ? tbv : tbk) + d*64 + c);
      *(float4*)&((tb ? tvs : tks)[d*68 + c]) = v;
    }
  } else {
    for (int j = tid; j < 528; j += 256){
      int tb = (j >= 264) ? 1 : 0;
      int cj = j - tb*264;
      int d = cj >> 3, c = (cj & 7)*8;
      union { bf16 h[8]; v8s v; } u;
      u.v = *(const v8s*)((const bf16*)(tb ? tbv : tbk) + d*64 + c);
      float* dst = (tb ? tvs : tks) + d*68 + c;
      float4 f0 = {b2f(u.h[0]), b2f(u.h[1]), b2f(u.h[2]), b2f(u.h[3])};
      float4 f1 = {b2f(u.h[4]), b2f(u.h[5]), b2f(u.h[6]), b2f(u.h[7])};
      *(float4*)dst = f0;
      *(float4*)(dst + 4) = f1;
    }
  }
  __syncthreads();
  {
    const int t = tid >> 4, s = tid & 15;
    const float4* qt = (const float4*)&qsT[t*68];
    const float4* kr = (const float4*)&ksT[s*68];
    const float4* q2 = (const float4*)&qsT[s*68];
    const float4* tr = (const float4*)&tks[(t - s + 16)*68];
    float qk = 0.f, rp = 0.f;
    #pragma unroll
    for (int c4 = 0; c4 < 16; ++c4){
      float4 a = qt[c4], b = kr[c4];
      qk += a.x*b.x + a.y*b.y + a.z*b.z + a.w*b.w;
      float4 a2 = q2[c4], tb = tr[c4];
      rp += a2.x*tb.x + a2.y*tb.y + a2.z*tb.z + a2.w*tb.w;
    }
    float logit = 0.125f*qk + 0.35355339059327373f*rp;
    if (s > t) logit = -1e8f;
    float mx = logit;
    #pragma unroll
    for (int off = 8; off; off >>= 1) mx = fmaxf(mx, __shfl_xor(mx, off, 16));
    float e = __expf(logit - mx);
    float tot = e;
    #pragma unroll
    for (int off = 8; off; off >>= 1) tot += __shfl_xor(tot, off, 16);
    ps[t*17 + s] = e / tot;
  }
  // no barrier: ps row t written/read within the same wave (lanes 16t..16t+15)
  {
    const int c4 = tid & 15, t = tid >> 4;
    float4 acc = {0.f,0.f,0.f,0.f};
    #pragma unroll
    for (int s = 0; s < 16; ++s){
      float p = ps[t*17 + s];
      float4 v4 = *(const float4*)&vsT[s*68 + c4*4];
      float4 t4 = *(const float4*)&tvs[(s - t + 16)*68 + c4*4];
      acc.x += p*(v4.x + t4.x); acc.y += p*(v4.y + t4.y);
      acc.z += p*(v4.z + t4.z); acc.w += p*(v4.w + t4.w);
    }
    union { bf16 h[4]; ushort4 u; } o;
    o.h[0] = f2b(acc.x); o.h[1] = f2b(acc.y); o.h[2] = f2b(acc.z); o.h[3] = f2b(acc.w);
    *(ushort4*)&attT[(size_t)ml*8192 + t*512 + head*64 + c4*4] = o.u;
  }
}

// ---------------------------------------------------------------- K8: temporal proj + residual -> out (MFMA)
// R12: LDS-staged epilogue (R1 pattern): Cs[t][o][l] in As, then 8-elem chunks
// with v8s x2 loads + contiguous 16/32B stores.
__global__ __launch_bounds__(256) void k_proj_t_mfma(const bf16* __restrict__ AT,
        const bf16* __restrict__ Wb, const void* __restrict__ Bv,
        const bf16* __restrict__ x2, void* __restrict__ out,
        const int* __restrict__ flag, int m0){
  const bool f32in = flag[0] != 0;
  const int o0 = blockIdx.x * 128;
  const int tp = blockIdx.y;            // t-pair
  const int mg0 = blockIdx.z * 32;      // m base (32 | 576)
  const int tid = threadIdx.x, lane = tid & 63;
  const int wm = (tid >> 6) & 1, wn = tid >> 7;
  const int r15 = lane & 15, quad = lane >> 4;
  __shared__ bf16 As[128*72];           // W staging; Cs[2][128][36] after loop (9216 elems)
  __shared__ bf16 Bs[64*72];
  v4f acc[4][2];
  #pragma unroll
  for (int i = 0; i < 4; ++i)
    #pragma unroll
    for (int j = 0; j < 2; ++j) acc[i][j] = (v4f){0.f,0.f,0.f,0.f};
  for (int kc = 0; kc < 512; kc += 64){
    __syncthreads();
    #pragma unroll
    for (int r = 0; r < 8; ++r){
      int e4 = (tid + 256*r)*4;
      int row = e4 >> 6, k = e4 & 63;
      stage4b(&Wb[(size_t)(o0+row)*512 + kc + k], &As[row*72 + k]);
    }
    #pragma unroll
    for (int r = 0; r < 4; ++r){
      int e4 = (tid + 256*r)*4;
      int row = e4 >> 6, k = e4 & 63;
      stage4b(&AT[(size_t)(mg0 + (row & 31))*8192 + (tp*2 + (row >> 5))*512 + kc + k],
              &Bs[row*72 + k]);
    }
    __syncthreads();
    #pragma unroll
    for (int ks = 0; ks < 2; ++ks){
      v8s a[4], b[2];
      #pragma unroll
      for (int mi = 0; mi < 4; ++mi)
        a[mi] = *(const v8s*)&As[(wm*64 + mi*16 + r15)*72 + ks*32 + quad*8];
      #pragma unroll
      for (int ni = 0; ni < 2; ++ni)
        b[ni] = *(const v8s*)&Bs[(wn*32 + ni*16 + r15)*72 + ks*32 + quad*8];
      #pragma unroll
      for (int mi = 0; mi < 4; ++mi)
        #pragma unroll
        for (int ni = 0; ni < 2; ++ni)
          acc[mi][ni] = __builtin_amdgcn_mfma_f32_16x16x32_bf16(a[mi], b[ni], acc[mi][ni], 0, 0, 0);
    }
  }
  // ---- R12 epilogue: stage acc+bias as Cs[t_loc][o_rel][l_loc] (stride 36)
  __syncthreads();
  #pragma unroll
  for (int mi = 0; mi < 4; ++mi){
    int orel = wm*64 + mi*16 + quad*4;
    #pragma unroll
    for (int rg = 0; rg < 4; ++rg){
      float bia = ldin(Bv, o0 + orel + rg, f32in);
      #pragma unroll
      for (int ni = 0; ni < 2; ++ni)
        As[(wn*128 + orel + rg)*36 + ni*16 + r15] = f2b(acc[mi][ni][rg] + bia);
    }
  }
  __syncthreads();
  // store: 8192 elems in 1024 chunks of 8 consecutive l
  const int mb = m0 + mg0;
  const int bb = mb / 576;
  const int l0b = mb - bb*576;          // multiple of 32 (576%32==0)
  for (int it = 0; it < 4; ++it){
    int idx = tid + it*256;             // [0,1024)
    int l8 = (idx & 3)*8;
    int ot = idx >> 2;                  // [0,256)
    int orel = ot & 127, tl = ot >> 7;
    union { bf16 h[8]; v8s v; } cv;
    cv.v = *(const v8s*)&As[(tl*128 + orel)*36 + l8];
    size_t addr = ((size_t)(bb*512 + o0 + orel)*16 + tp*2 + tl)*576 + l0b + l8;
    union { bf16 h[8]; v8s v; } xv;
    xv.v = *(const v8s*)&x2[addr];
    if (f32in){
      float* op = (float*)out + addr;
      float4 f0, f1;
      f0.x = b2f(cv.h[0]) + b2f(xv.h[0]);
      f0.y = b2f(cv.h[1]) + b2f(xv.h[1]);
      f0.z = b2f(cv.h[2]) + b2f(xv.h[2]);
      f0.w = b2f(cv.h[3]) + b2f(xv.h[3]);
      f1.x = b2f(cv.h[4]) + b2f(xv.h[4]);
      f1.y = b2f(cv.h[5]) + b2f(xv.h[5]);
      f1.z = b2f(cv.h[6]) + b2f(xv.h[6]);
      f1.w = b2f(cv.h[7]) + b2f(xv.h[7]);
      *(float4*)op = f0;
      *(float4*)(op + 4) = f1;
    } else {
      union { bf16 h[8]; v8s v; } ov;
      #pragma unroll
      for (int j = 0; j < 8; ++j) ov.h[j] = f2b(b2f(cv.h[j]) + b2f(xv.h[j]));
      *(v8s*)((bf16*)out + addr) = ov.v;
    }
  }
}

// ----------------------------------------------------------------
extern "C" void kernel_launch(void* const* d_in, const int* in_sizes, int n_in,
                              void* d_out, int out_size, void* d_ws, size_t ws_size,
                              hipStream_t stream){
  const void* x   = d_in[0];
  const void* nsw = d_in[1];
  const void* nsb = d_in[2];
  const void* qsw = d_in[3];
  const void* qsb = d_in[4];
  const void* psw = d_in[5];
  const void* psb = d_in[6];
  const void* ntw = d_in[7];
  const void* ntb = d_in[8];
  const void* qtw = d_in[9];
  const void* qtb = d_in[10];
  const void* ptw = d_in[11];
  const void* ptb = d_in[12];
  const void* rpk = d_in[13];
  const void* rpv = d_in[14];

  // Chunking and x2T gate from ws_size (constant across calls -> graph-safe).
  const size_t S_full = (size_t)32*294912;
  const size_t need_full = 256 + (S_full*5 + 9437184)*2;
  const size_t need_T    = 256 + (S_full*5 + (size_t)2*9437184)*2;  // +18.9 MB for x2T
  const int NCH = (ws_size >= need_full) ? 32 : 8;
  const int MCH = (NCH == 32) ? 1152 : 288;
  const size_t S = (size_t)NCH*294912;
  const int useT = (NCH == 32 && ws_size >= need_T) ? 1 : 0;

  int*  flag = (int*)d_ws;
  bf16* A  = (bf16*)((char*)d_ws + 256);   // S: xnT_s / xnT_t
  bf16* A2 = A  + S;                        // S: attT_s / attT_t (+ transient W copy)
  bf16* Bq = A2 + S;                        // 3S: qkv (+ transient W copies)
  bf16* Cx = Bq + 3*S;                      // 9,437,184: x2 residual
  bf16* Cx2 = Cx + 9437184;                 // 9,437,184: x2T [m][t][c] (if useT)
  const size_t kOff = S, vOff = 2*S;
  bf16* Wcv  = A2;
  bf16* Wcv2 = Bq;

  k_detect<<<1, 64, 0, stream>>>(x, flag);

  for (int n0 = 0; n0 < 32; n0 += NCH){
    k_gn_s       <<<dim3(32, NCH),   256, 0, stream>>>(x, nsw, nsb, A, flag, n0);
    k_cvtw       <<<dim3(768),       256, 0, stream>>>(qsw, Wcv, 196608, flag);
    k_gemm_qkv   <<<dim3(NCH*54),    256, 0, stream>>>(A, Wcv, qsb, Bq, flag, kOff, vOff, 0);
    k_attn_s_mfma<<<dim3(72*NCH),    256, 0, stream>>>(Bq, A2, kOff, vOff);
    // proj_s weight pre-convert into Bq (qkv dead after attn_s)
    k_cvtw       <<<dim3(256),       256, 0, stream>>>(psw, Bq, 65536, flag);
    k_proj_s_mfma<<<dim3(4, 9, NCH), 256, 0, stream>>>(A2, Bq, psb, x, Cx, Cx2, useT, flag, n0);
  }
  for (int m0 = 0; m0 < 1152; m0 += MCH){
    if (useT) k_gn_t2<<<dim3(MCH),   256, 0, stream>>>(Cx2, ntw, ntb, A, flag, m0);
    else      k_gn_t <<<dim3(MCH),   256, 0, stream>>>(Cx,  ntw, ntb, A, flag, m0);
    k_cvtw       <<<dim3(768),       256, 0, stream>>>(qtw, Wcv, 196608, flag);
    k_gemm_qkv   <<<dim3((MCH/2)*3), 256, 0, stream>>>(A, Wcv, qtb, Bq, flag, 0, 0, 1);
    k_attn_t     <<<dim3(8, MCH),    256, 0, stream>>>(Bq, rpk, rpv, A2, flag);
    k_cvtw       <<<dim3(256),       256, 0, stream>>>(ptw, Wcv2, 65536, flag);
    k_proj_t_mfma<<<dim3(4, 8, MCH/32), 256, 0, stream>>>(A2, Wcv2, ptb, Cx, d_out, flag, m0);
  }
}